// Round 2
// baseline (1789.932 us; speedup 1.0000x reference)
//
#include <hip/hip_runtime.h>

#define BB 16
#define CC 128
#define NN 2048
#define MM2 2052
#define MM 1024

constexpr float RSQRT_C = 0.08838834764831845f; // 1/sqrt(128)

// ---- workspace layout (element offsets, everything 4 bytes) ----
constexpr size_t OFF_Q     = 0;                                  // BB*NN*CC
constexpr size_t OFF_K     = OFF_Q     + (size_t)BB*NN*CC;       // BB*CC*MM2
constexpr size_t OFF_V     = OFF_K     + (size_t)BB*CC*MM2;      // BB*CC*MM2
constexpr size_t OFF_RMAX  = OFF_V     + (size_t)BB*CC*MM2;      // BB*NN
constexpr size_t OFF_RSUM  = OFF_RMAX  + (size_t)BB*NN;          // BB*NN
constexpr size_t OFF_EBINS = OFF_RSUM  + (size_t)BB*NN;          // BB*NN*4
constexpr size_t OFF_SCORE = OFF_EBINS + (size_t)BB*NN*4;        // BB*NN
constexpr size_t OFF_BINOF = OFF_SCORE + (size_t)BB*NN;          // BB*NN (int)
constexpr size_t OFF_KBINS = OFF_BINOF + (size_t)BB*NN;          // BB*4  (int)
constexpr size_t OFF_FLAGS = OFF_KBINS + (size_t)BB*4;           // BB*NN (int)
constexpr size_t OFF_IDXL  = OFF_FLAGS + (size_t)BB*NN;          // BB*MM (int)

// ---------------------------------------------------------------
// K1a: Q[b][n][o] = sum_c Wq[o][c] * x[b][c][n], scaled by 1/sqrt(C)
// ---------------------------------------------------------------
__global__ __launch_bounds__(256) void proj_q_kernel(
    const float* __restrict__ x, const float* __restrict__ Wq, float* __restrict__ Q)
{
  __shared__ float xs[128][132];  // [c][n]
  __shared__ float ws[128][132];  // [c][o]
  const int t  = threadIdx.x;
  const int b  = blockIdx.x >> 4;
  const int n0 = (blockIdx.x & 15) * 128;

  for (int i = t; i < 128*128; i += 256) {
    int c = i >> 7, n = i & 127;
    xs[c][n] = x[((size_t)(b*CC)+c)*NN + n0 + n];
  }
  for (int i = t; i < 128*128; i += 256) {
    int o = i >> 7, c = i & 127;
    ws[c][o] = Wq[o*CC + c];
  }
  __syncthreads();

  const int tn = (t & 15) * 8;
  const int to = (t >> 4) * 8;
  float acc[8][8];
  #pragma unroll
  for (int i=0;i<8;i++) {
    #pragma unroll
    for (int j=0;j<8;j++) acc[i][j]=0.f;
  }

  for (int c = 0; c < 128; ++c) {
    float xv[8], wv[8];
    #pragma unroll
    for (int i=0;i<8;i++) xv[i] = xs[c][tn+i];
    #pragma unroll
    for (int j=0;j<8;j++) wv[j] = ws[c][to+j];
    #pragma unroll
    for (int i=0;i<8;i++) {
      #pragma unroll
      for (int j=0;j<8;j++) acc[i][j] = fmaf(xv[i], wv[j], acc[i][j]);
    }
  }
  for (int i=0;i<8;i++)
    for (int j=0;j<8;j++)
      Q[((size_t)(b*NN)+n0+tn+i)*CC + to + j] = acc[i][j] * RSQRT_C;
}

// ---------------------------------------------------------------
// K1b: K/V[b][o][m] = sum_c W[o][c] * x_tok[b][c][m], m in [0,2052)
// ---------------------------------------------------------------
__global__ __launch_bounds__(256) void proj_kv_kernel(
    const float* __restrict__ x, const float* __restrict__ Wk, const float* __restrict__ Wv,
    const float* __restrict__ bt, float* __restrict__ K, float* __restrict__ V)
{
  __shared__ float xs[128][132];  // [c][m]
  __shared__ float ws[128][132];  // [c][o]
  const int t  = threadIdx.x;
  const int b  = blockIdx.x & 15;
  const int m0 = (blockIdx.x >> 4) * 128;

  for (int i = t; i < 128*128; i += 256) {
    int c = i >> 7, m = i & 127; int gm = m0 + m;
    float v = 0.f;
    if (gm < NN) v = x[((size_t)(b*CC)+c)*NN + gm];
    else if (gm < MM2) v = bt[c*4 + (gm - NN)];
    xs[c][m] = v;
  }
  const int tm = (t & 15) * 8;
  const int to = (t >> 4) * 8;

  for (int pass = 0; pass < 2; ++pass) {
    const float* W = pass ? Wv : Wk;
    float* O = pass ? V : K;
    __syncthreads();
    for (int i = t; i < 128*128; i += 256) {
      int o = i >> 7, c = i & 127;
      ws[c][o] = W[o*CC + c];
    }
    __syncthreads();
    float acc[8][8];
    #pragma unroll
    for (int i=0;i<8;i++) {
      #pragma unroll
      for (int j=0;j<8;j++) acc[i][j]=0.f;
    }
    for (int c = 0; c < 128; ++c) {
      float xv[8], wv[8];
      #pragma unroll
      for (int i=0;i<8;i++) xv[i] = xs[c][tm+i];
      #pragma unroll
      for (int j=0;j<8;j++) wv[j] = ws[c][to+j];
      #pragma unroll
      for (int i=0;i<8;i++) {
        #pragma unroll
        for (int j=0;j<8;j++) acc[i][j] = fmaf(xv[i], wv[j], acc[i][j]);
      }
    }
    for (int j=0;j<8;j++) {
      for (int i=0;i<8;i++) {
        int gm = m0 + tm + i;
        if (gm < MM2) O[((size_t)(b*CC)+to+j)*MM2 + gm] = acc[i][j];
      }
    }
  }
}

// ---------------------------------------------------------------
// K2a: per-row online softmax stats (rowmax, rowsum) + bin-column energies
// block: 64 query rows, streams 33 tiles of 64 keys
// ---------------------------------------------------------------
__global__ __launch_bounds__(256) void stats_kernel(
    const float* __restrict__ Q, const float* __restrict__ K,
    float* __restrict__ rowmax, float* __restrict__ rowsum, float* __restrict__ ebins)
{
  __shared__ float qs[64][129];   // [r][c]
  __shared__ float ks[128][68];   // [c][m]
  const int t  = threadIdx.x;
  const int b  = blockIdx.x & 15;
  const int n0 = (blockIdx.x >> 4) * 64;

  for (int i = t; i < 64*128; i += 256) {
    int r = i >> 7, c = i & 127;
    qs[r][c] = Q[((size_t)(b*NN)+n0+r)*CC + c];
  }
  const int tk = t & 15;        // keys tk*4..
  const int tr4 = (t >> 4) * 4; // rows tr4..tr4+3
  float runmx[4], runsum[4];
  #pragma unroll
  for (int i=0;i<4;i++){ runmx[i] = -INFINITY; runsum[i] = 0.f; }

  for (int kt = 0; kt < 33; ++kt) {
    const int m0 = kt * 64;
    __syncthreads();
    for (int i = t; i < 128*64; i += 256) {
      int c = i >> 6, m = i & 63; int gm = m0 + m;
      ks[c][m] = (gm < MM2) ? K[((size_t)(b*CC)+c)*MM2 + gm] : 0.f;
    }
    __syncthreads();

    float e[4][4];
    #pragma unroll
    for (int i=0;i<4;i++){
      #pragma unroll
      for (int j=0;j<4;j++) e[i][j]=0.f;
    }
    for (int c = 0; c < 128; ++c) {
      const float4 kv = *(const float4*)&ks[c][tk*4];
      float qv[4];
      #pragma unroll
      for (int i=0;i<4;i++) qv[i] = qs[tr4+i][c];
      #pragma unroll
      for (int i=0;i<4;i++) {
        e[i][0] = fmaf(qv[i], kv.x, e[i][0]);
        e[i][1] = fmaf(qv[i], kv.y, e[i][1]);
        e[i][2] = fmaf(qv[i], kv.z, e[i][2]);
        e[i][3] = fmaf(qv[i], kv.w, e[i][3]);
      }
    }

    if (kt == 32) {
      if (tk == 0) { // keys 2048..2051 = bin columns (pre-softmax energies)
        #pragma unroll
        for (int i=0;i<4;i++) {
          #pragma unroll
          for (int j=0;j<4;j++)
            ebins[((size_t)(b*NN)+n0+tr4+i)*4 + j] = e[i][j];
        }
      }
      #pragma unroll
      for (int j=0;j<4;j++) {
        if (m0 + tk*4 + j >= MM2) {
          #pragma unroll
          for (int i=0;i<4;i++) e[i][j] = -INFINITY;
        }
      }
    }

    #pragma unroll
    for (int i=0;i<4;i++) {
      float tmx = fmaxf(fmaxf(e[i][0], e[i][1]), fmaxf(e[i][2], e[i][3]));
      #pragma unroll
      for (int off=1; off<16; off<<=1) tmx = fmaxf(tmx, __shfl_xor(tmx, off));
      float nm = fmaxf(runmx[i], tmx);
      float ps = expf(e[i][0]-nm)+expf(e[i][1]-nm)+expf(e[i][2]-nm)+expf(e[i][3]-nm);
      #pragma unroll
      for (int off=1; off<16; off<<=1) ps += __shfl_xor(ps, off);
      runsum[i] = runsum[i] * expf(runmx[i] - nm) + ps;
      runmx[i] = nm;
    }
  }
  if (tk == 0) {
    #pragma unroll
    for (int i=0;i<4;i++) {
      rowmax[(size_t)b*NN + n0 + tr4 + i] = runmx[i];
      rowsum[(size_t)b*NN + n0 + tr4 + i] = runsum[i];
    }
  }
}

// ---------------------------------------------------------------
// K2b: score[b][m] = sum_n exp(e[n][m]-rowmax[n])/rowsum[n]  (m<2048)
// block owns 64 keys, streams 32 tiles of 64 query rows
// ---------------------------------------------------------------
__global__ __launch_bounds__(256) void score_kernel(
    const float* __restrict__ Q, const float* __restrict__ K,
    const float* __restrict__ rowmax, const float* __restrict__ rowsum,
    float* __restrict__ score)
{
  __shared__ float ks[128][68];
  __shared__ float qs[64][129];
  __shared__ float mxs[64], irs[64];
  __shared__ float red[16][64];
  const int t  = threadIdx.x;
  const int b  = blockIdx.x & 15;
  const int m0 = (blockIdx.x >> 4) * 64;

  for (int i = t; i < 128*64; i += 256) {
    int c = i >> 6, m = i & 63;
    ks[c][m] = K[((size_t)(b*CC)+c)*MM2 + m0 + m];
  }
  const int tk = t & 15;
  const int tr4 = (t >> 4) * 4;
  float sacc[4] = {0.f,0.f,0.f,0.f};

  for (int rt = 0; rt < 32; ++rt) {
    const int n0 = rt * 64;
    __syncthreads();
    for (int i = t; i < 64*128; i += 256) {
      int r = i >> 7, c = i & 127;
      qs[r][c] = Q[((size_t)(b*NN)+n0+r)*CC + c];
    }
    if (t < 64) {
      mxs[t] = rowmax[(size_t)b*NN + n0 + t];
      irs[t] = 1.0f / rowsum[(size_t)b*NN + n0 + t];
    }
    __syncthreads();

    float e[4][4];
    #pragma unroll
    for (int i=0;i<4;i++){
      #pragma unroll
      for (int j=0;j<4;j++) e[i][j]=0.f;
    }
    for (int c = 0; c < 128; ++c) {
      const float4 kv = *(const float4*)&ks[c][tk*4];
      float qv[4];
      #pragma unroll
      for (int i=0;i<4;i++) qv[i] = qs[tr4+i][c];
      #pragma unroll
      for (int i=0;i<4;i++) {
        e[i][0] = fmaf(qv[i], kv.x, e[i][0]);
        e[i][1] = fmaf(qv[i], kv.y, e[i][1]);
        e[i][2] = fmaf(qv[i], kv.z, e[i][2]);
        e[i][3] = fmaf(qv[i], kv.w, e[i][3]);
      }
    }
    #pragma unroll
    for (int i=0;i<4;i++) {
      float mx = mxs[tr4+i], al = irs[tr4+i];
      #pragma unroll
      for (int j=0;j<4;j++) sacc[j] += expf(e[i][j] - mx) * al;
    }
  }
  __syncthreads();
  #pragma unroll
  for (int j=0;j<4;j++) red[t>>4][tk*4+j] = sacc[j];
  __syncthreads();
  if (t < 64) {
    float s = 0.f;
    for (int g = 0; g < 16; ++g) s += red[g][t];
    score[(size_t)b*NN + m0 + t] = s;
  }
}

// ---------------------------------------------------------------
// K3a: bin assignment + budget allocation (one block per batch)
// ---------------------------------------------------------------
__global__ __launch_bounds__(256) void bin_kernel(
    const float* __restrict__ score, const float* __restrict__ ebins,
    int* __restrict__ binof, int* __restrict__ kbins)
{
  const int b = blockIdx.x, t = threadIdx.x;
  float wsm[4] = {0.f,0.f,0.f,0.f};
  int   cnt[4] = {0,0,0,0};
  for (int n = t; n < NN; n += 256) {
    float s = score[(size_t)b*NN + n];
    int j = (s >= 1.2f) ? 0 : (s >= 1.0f) ? 1 : (s >= 0.8f) ? 2 : 3;
    binof[(size_t)b*NN + n] = j;
    wsm[j] += ebins[((size_t)b*NN + n)*4 + j];
    cnt[j] += 1;
  }
  #pragma unroll
  for (int j=0;j<4;j++){
    for (int off=1; off<64; off<<=1){
      wsm[j] += __shfl_xor(wsm[j], off);
      cnt[j] += __shfl_xor(cnt[j], off);
    }
  }
  __shared__ float wred[4][4];
  __shared__ int   cred[4][4];
  int wave = t >> 6, lane = t & 63;
  if (lane == 0) for (int j=0;j<4;j++){ wred[wave][j]=wsm[j]; cred[wave][j]=cnt[j]; }
  __syncthreads();
  if (t == 0) {
    float wsum[4]; int cs[4];
    for (int j=0;j<4;j++){
      wsum[j]=wred[0][j]+wred[1][j]+wred[2][j]+wred[3][j];
      cs[j]=cred[0][j]+cred[1][j]+cred[2][j]+cred[3][j];
    }
    float bw[4]; float sbw = 0.f;
    for (int j=0;j<4;j++){
      float wp = wsum[j] / ((float)cs[j] + 1e-8f);
      bw[j] = fmaxf(wp, 0.f); sbw += bw[j];
    }
    float den = fmaxf(sbw, 1e-8f);
    int k0[4]; int sk0 = 0;
    for (int j=0;j<4;j++){
      float p = bw[j] / den;
      int kk = (int)floorf(p * 1024.0f);
      if (kk > cs[j]) kk = cs[j];
      k0[j]=kk; sk0 += kk;
    }
    int deficit = 1024 - sk0;
    int cum = 0;
    for (int j=0;j<4;j++){
      int cap = cs[j] - k0[j];
      int ex = deficit - cum; if (ex < 0) ex = 0; if (ex > cap) ex = cap;
      kbins[b*4+j] = k0[j] + ex;
      cum += cap;
    }
  }
}

// ---------------------------------------------------------------
// K3b: per-(batch,bin) top-k by (score desc, index asc) -> selection flags
// bitonic sort of 2048 composite keys in LDS
// ---------------------------------------------------------------
__global__ __launch_bounds__(256) void topk_kernel(
    const float* __restrict__ score, const int* __restrict__ binof,
    const int* __restrict__ kbins, int* __restrict__ flags)
{
  __shared__ unsigned long long arr[2048];
  const int t = threadIdx.x;
  const int b = blockIdx.x >> 2;
  const int j = blockIdx.x & 3;
  for (int n = t; n < NN; n += 256) {
    unsigned long long comp = 0ull;
    if (binof[(size_t)b*NN+n] == j) {
      unsigned int bits = __float_as_uint(score[(size_t)b*NN+n]);
      bits = (bits & 0x80000000u) ? ~bits : (bits | 0x80000000u);
      comp = ((unsigned long long)bits << 32) |
             (unsigned long long)(0xFFFFFFFFu - (unsigned)n);
    }
    arr[n] = ~comp;   // ascending sort puts best first, non-members last
  }
  __syncthreads();
  for (int ksz = 2; ksz <= 2048; ksz <<= 1) {
    for (int jsz = ksz >> 1; jsz > 0; jsz >>= 1) {
      for (int i = t; i < 2048; i += 256) {
        int ixj = i ^ jsz;
        if (ixj > i) {
          unsigned long long a = arr[i], bv = arr[ixj];
          bool up = ((i & ksz) == 0);
          if ((a > bv) == up) { arr[i] = bv; arr[ixj] = a; }
        }
      }
      __syncthreads();
    }
  }
  const int kb = kbins[b*4+j];
  for (int i = t; i < kb; i += 256) {
    unsigned long long comp = ~arr[i];
    int n = (int)(0xFFFFFFFFu - (unsigned)(comp & 0xFFFFFFFFull));
    flags[(size_t)b*NN + n] = 1;
  }
}

// ---------------------------------------------------------------
// K3c: prefix-scan of flags -> ascending selected index list + index output
// ---------------------------------------------------------------
__global__ __launch_bounds__(256) void scan_kernel(
    const int* __restrict__ flags, int* __restrict__ idxl, float* __restrict__ outIdx)
{
  __shared__ int tsum[256];
  const int b = blockIdx.x, t = threadIdx.x;
  int f[8]; int c8 = 0;
  const int base = t * 8;
  #pragma unroll
  for (int i=0;i<8;i++){ f[i] = flags[(size_t)b*NN + base + i]; c8 += f[i]; }
  tsum[t] = c8;
  __syncthreads();
  for (int off=1; off<256; off<<=1) {
    int v = (t >= off) ? tsum[t-off] : 0;
    __syncthreads();
    tsum[t] += v;
    __syncthreads();
  }
  int pos = tsum[t] - c8;
  #pragma unroll
  for (int i=0;i<8;i++){
    if (f[i] && pos < MM) {
      idxl[(size_t)b*MM + pos] = base + i;
      outIdx[(size_t)b*MM + pos] = (float)(base + i);
      pos++;
    }
  }
}

// ---------------------------------------------------------------
// K4: gather selected query rows, recompute their attention rows,
// out0[b][c][m] = sum_k attn[idx_m][k] * V[c][k]
// ---------------------------------------------------------------
__global__ __launch_bounds__(256) void out_kernel(
    const float* __restrict__ Q, const float* __restrict__ K, const float* __restrict__ V,
    const float* __restrict__ rowmax, const float* __restrict__ rowsum,
    const int* __restrict__ idxl, float* __restrict__ out0)
{
  __shared__ float qs[64][129];
  __shared__ float ks[128][36];
  __shared__ float vs[128][33];
  __shared__ float ps[64][36];
  __shared__ float mxs[64], irs[64];
  __shared__ int rowid[64];
  const int t  = threadIdx.x;
  const int b  = blockIdx.x & 15;
  const int m0 = (blockIdx.x >> 4) * 64;

  if (t < 64) {
    int n = idxl[(size_t)b*MM + m0 + t];
    rowid[t] = n;
    mxs[t] = rowmax[(size_t)b*NN + n];
    irs[t] = 1.0f / rowsum[(size_t)b*NN + n];
  }
  __syncthreads();
  for (int i = t; i < 64*128; i += 256) {
    int r = i >> 7, c = i & 127;
    qs[r][c] = Q[((size_t)(b*NN)+rowid[r])*CC + c];
  }

  float acc[4][8];
  #pragma unroll
  for (int i=0;i<4;i++){
    #pragma unroll
    for (int jj=0;jj<8;jj++) acc[i][jj]=0.f;
  }

  const int tk8 = t & 7;        // e-phase: keys tk8*4..
  const int tq2 = (t >> 3) * 2; // e-phase: rows tq2, tq2+1
  const int tr4 = (t >> 4) * 4; // PV: rows tr4..
  const int tc8 = (t & 15) * 8; // PV: cols tc8..

  for (int kt = 0; kt < 65; ++kt) {
    const int k0g = kt * 32;
    __syncthreads();
    for (int i = t; i < 128*32; i += 256) {
      int c = i >> 5, m = i & 31; int gm = k0g + m;
      float kvv = 0.f, vvv = 0.f;
      if (gm < MM2) {
        kvv = K[((size_t)(b*CC)+c)*MM2 + gm];
        vvv = V[((size_t)(b*CC)+c)*MM2 + gm];
      }
      ks[c][m] = kvv; vs[c][m] = vvv;
    }
    __syncthreads();

    float e[2][4];
    #pragma unroll
    for (int i=0;i<2;i++){
      #pragma unroll
      for (int jj=0;jj<4;jj++) e[i][jj]=0.f;
    }
    for (int c = 0; c < 128; ++c) {
      const float4 kv = *(const float4*)&ks[c][tk8*4];
      float q0 = qs[tq2+0][c], q1 = qs[tq2+1][c];
      e[0][0] = fmaf(q0, kv.x, e[0][0]); e[0][1] = fmaf(q0, kv.y, e[0][1]);
      e[0][2] = fmaf(q0, kv.z, e[0][2]); e[0][3] = fmaf(q0, kv.w, e[0][3]);
      e[1][0] = fmaf(q1, kv.x, e[1][0]); e[1][1] = fmaf(q1, kv.y, e[1][1]);
      e[1][2] = fmaf(q1, kv.z, e[1][2]); e[1][3] = fmaf(q1, kv.w, e[1][3]);
    }
    #pragma unroll
    for (int i=0;i<2;i++) {
      int r = tq2 + i;
      float mx = mxs[r], al = irs[r];
      #pragma unroll
      for (int jj=0;jj<4;jj++) {
        int gm = k0g + tk8*4 + jj;
        ps[r][tk8*4+jj] = (gm < MM2) ? expf(e[i][jj] - mx) * al : 0.f;
      }
    }
    __syncthreads();

    for (int k = 0; k < 32; ++k) {
      float pv[4];
      #pragma unroll
      for (int i=0;i<4;i++) pv[i] = ps[tr4+i][k];
      #pragma unroll
      for (int jj=0;jj<8;jj++) {
        float vv = vs[tc8+jj][k];
        #pragma unroll
        for (int i=0;i<4;i++) acc[i][jj] = fmaf(pv[i], vv, acc[i][jj]);
      }
    }
  }

  for (int i=0;i<4;i++) {
    int m = m0 + tr4 + i;
    for (int jj=0;jj<8;jj++) {
      int c = tc8 + jj;
      out0[((size_t)(b*CC)+c)*MM + m] = acc[i][jj];
    }
  }
}

// ---------------------------------------------------------------
extern "C" void kernel_launch(void* const* d_in, const int* in_sizes, int n_in,
                              void* d_out, int out_size, void* d_ws, size_t ws_size,
                              hipStream_t stream) {
  const float* x  = (const float*)d_in[0];
  const float* Wq = (const float*)d_in[1];
  const float* Wk = (const float*)d_in[2];
  const float* Wv = (const float*)d_in[3];
  const float* bt = (const float*)d_in[4];
  float* out = (float*)d_out;
  float* wsf = (float*)d_ws;

  float* Q      = wsf + OFF_Q;
  float* Kmat   = wsf + OFF_K;
  float* Vmat   = wsf + OFF_V;
  float* rmax   = wsf + OFF_RMAX;
  float* rsum   = wsf + OFF_RSUM;
  float* ebins  = wsf + OFF_EBINS;
  float* score  = wsf + OFF_SCORE;
  int*   binof  = (int*)(wsf + OFF_BINOF);
  int*   kbins  = (int*)(wsf + OFF_KBINS);
  int*   flags  = (int*)(wsf + OFF_FLAGS);
  int*   idxl   = (int*)(wsf + OFF_IDXL);

  float* out0   = out;                        // (B,C,M)
  float* outIdx = out + (size_t)BB*CC*MM;     // (B,1,M) as float

  (void)hipMemsetAsync(flags, 0, (size_t)BB*NN*sizeof(int), stream);

  hipLaunchKernelGGL(proj_q_kernel,  dim3(256), dim3(256), 0, stream, x, Wq, Q);
  hipLaunchKernelGGL(proj_kv_kernel, dim3(272), dim3(256), 0, stream, x, Wk, Wv, bt, Kmat, Vmat);
  hipLaunchKernelGGL(stats_kernel,   dim3(512), dim3(256), 0, stream, Q, Kmat, rmax, rsum, ebins);
  hipLaunchKernelGGL(score_kernel,   dim3(512), dim3(256), 0, stream, Q, Kmat, rmax, rsum, score);
  hipLaunchKernelGGL(bin_kernel,     dim3(16),  dim3(256), 0, stream, score, ebins, binof, kbins);
  hipLaunchKernelGGL(topk_kernel,    dim3(64),  dim3(256), 0, stream, score, binof, kbins, flags);
  hipLaunchKernelGGL(scan_kernel,    dim3(16),  dim3(256), 0, stream, flags, idxl, outIdx);
  hipLaunchKernelGGL(out_kernel,     dim3(256), dim3(256), 0, stream, Q, Kmat, Vmat, rmax, rsum, idxl, out0);
}

// Round 3
// 693.230 us; speedup vs baseline: 2.5820x; 2.5820x over previous
//
#include <hip/hip_runtime.h>

#define BB 16
#define CC 128
#define NN 2048
#define MM2 2052
#define VST 2056   // padded V row stride (16B-aligned rows)
#define MM 1024

constexpr float RSQRT_C = 0.08838834764831845f; // 1/sqrt(128)

typedef unsigned short u16;
typedef __attribute__((ext_vector_type(8))) short bf16x8;
typedef __attribute__((ext_vector_type(4))) float f32x4;

__device__ inline u16 f2b_rn(float f) {
  unsigned u = __float_as_uint(f);
  unsigned r = u + 0x7fffu + ((u >> 16) & 1u);
  return (u16)(r >> 16);
}
__device__ inline float b2f(u16 h) { return __uint_as_float(((unsigned)h) << 16); }

__device__ inline void store8(u16* dst, const u16 h[8]) {
  uint4 v;
  v.x = (unsigned)h[0] | ((unsigned)h[1] << 16);
  v.y = (unsigned)h[2] | ((unsigned)h[3] << 16);
  v.z = (unsigned)h[4] | ((unsigned)h[5] << 16);
  v.w = (unsigned)h[6] | ((unsigned)h[7] << 16);
  *(uint4*)dst = v;
}

// ---- workspace layout (byte offsets) ----
constexpr size_t SZ_Q  = (size_t)BB*NN*CC*2;          // 8388608
constexpr size_t SZ_K  = (size_t)BB*MM2*CC*2;         // 8404992
constexpr size_t SZ_V  = (size_t)BB*CC*VST*2;         // 8421376
constexpr size_t oQH = 0;
constexpr size_t oQL = oQH + SZ_Q;
constexpr size_t oKH = oQL + SZ_Q;
constexpr size_t oKL = oKH + SZ_K;
constexpr size_t oVH = oKL + SZ_K;
constexpr size_t oVL = oVH + SZ_V;
constexpr size_t oRMAX = oVL + SZ_V;                  // BB*NN f32
constexpr size_t oRSUM = oRMAX + (size_t)BB*NN*4;
constexpr size_t oEB   = oRSUM + (size_t)BB*NN*4;     // BB*NN*4 f32
constexpr size_t oSCORE= oEB   + (size_t)BB*NN*16;
constexpr size_t oBIN  = oSCORE+ (size_t)BB*NN*4;     // int
constexpr size_t oKB   = oBIN  + (size_t)BB*NN*4;     // BB*4 int
constexpr size_t oFL   = oKB   + 256;                 // BB*NN int
constexpr size_t oIDX  = oFL   + (size_t)BB*NN*4;     // BB*MM int

// ---------------------------------------------------------------
// proj_q: Q[b][n][c] = (Wq x)/sqrt(C), emitted as bf16 hi/lo
// ---------------------------------------------------------------
__global__ __launch_bounds__(256) void proj_q_kernel(
    const float* __restrict__ x, const float* __restrict__ Wq,
    u16* __restrict__ QH, u16* __restrict__ QL)
{
  __shared__ float xs[128][132];
  __shared__ float ws[128][132];
  const int t  = threadIdx.x;
  const int b  = blockIdx.x >> 4;
  const int n0 = (blockIdx.x & 15) * 128;

  for (int i = t; i < 128*128; i += 256) {
    int c = i >> 7, n = i & 127;
    xs[c][n] = x[((size_t)(b*CC)+c)*NN + n0 + n];
  }
  for (int i = t; i < 128*128; i += 256) {
    int o = i >> 7, c = i & 127;
    ws[c][o] = Wq[o*CC + c];
  }
  __syncthreads();

  const int tn = (t & 15) * 8;
  const int to = (t >> 4) * 8;
  float acc[8][8];
  #pragma unroll
  for (int i=0;i<8;i++) {
    #pragma unroll
    for (int j=0;j<8;j++) acc[i][j]=0.f;
  }
  for (int c = 0; c < 128; ++c) {
    float xv[8], wv[8];
    #pragma unroll
    for (int i=0;i<8;i++) xv[i] = xs[c][tn+i];
    #pragma unroll
    for (int j=0;j<8;j++) wv[j] = ws[c][to+j];
    #pragma unroll
    for (int i=0;i<8;i++) {
      #pragma unroll
      for (int j=0;j<8;j++) acc[i][j] = fmaf(xv[i], wv[j], acc[i][j]);
    }
  }
  for (int i=0;i<8;i++) {
    u16 hs[8], ls[8];
    #pragma unroll
    for (int j=0;j<8;j++) {
      float v = acc[i][j] * RSQRT_C;
      u16 hb = f2b_rn(v);
      hs[j] = hb; ls[j] = f2b_rn(v - b2f(hb));
    }
    size_t idx = ((size_t)b*NN + n0+tn+i)*CC + to;
    store8(QH + idx, hs); store8(QL + idx, ls);
  }
}

// ---------------------------------------------------------------
// proj_kv: K[b][m][c] hi/lo, V[b][c][m] hi/lo (V rows padded to 2056)
// ---------------------------------------------------------------
__global__ __launch_bounds__(256) void proj_kv_kernel(
    const float* __restrict__ x, const float* __restrict__ Wk, const float* __restrict__ Wv,
    const float* __restrict__ bt,
    u16* __restrict__ KH, u16* __restrict__ KL, u16* __restrict__ VH, u16* __restrict__ VL)
{
  __shared__ float xs[128][132];
  __shared__ float ws[128][132];
  const int t  = threadIdx.x;
  const int b  = blockIdx.x & 15;
  const int m0 = (blockIdx.x >> 4) * 128;

  for (int i = t; i < 128*128; i += 256) {
    int c = i >> 7, m = i & 127; int gm = m0 + m;
    float v = 0.f;
    if (gm < NN) v = x[((size_t)(b*CC)+c)*NN + gm];
    else if (gm < MM2) v = bt[c*4 + (gm - NN)];
    xs[c][m] = v;
  }
  const int tm = (t & 15) * 8;
  const int to = (t >> 4) * 8;

  for (int pass = 0; pass < 2; ++pass) {
    const float* W = pass ? Wv : Wk;
    __syncthreads();
    for (int i = t; i < 128*128; i += 256) {
      int o = i >> 7, c = i & 127;
      ws[c][o] = W[o*CC + c];
    }
    __syncthreads();
    float acc[8][8];
    #pragma unroll
    for (int i=0;i<8;i++) {
      #pragma unroll
      for (int j=0;j<8;j++) acc[i][j]=0.f;
    }
    for (int c = 0; c < 128; ++c) {
      float xv[8], wv[8];
      #pragma unroll
      for (int i=0;i<8;i++) xv[i] = xs[c][tm+i];
      #pragma unroll
      for (int j=0;j<8;j++) wv[j] = ws[c][to+j];
      #pragma unroll
      for (int i=0;i<8;i++) {
        #pragma unroll
        for (int j=0;j<8;j++) acc[i][j] = fmaf(xv[i], wv[j], acc[i][j]);
      }
    }
    if (pass == 0) {
      // K: [b][m][c] rows, c-contiguous
      for (int i=0;i<8;i++) {
        int gm = m0 + tm + i;
        if (gm >= MM2) continue;
        u16 hs[8], ls[8];
        #pragma unroll
        for (int j=0;j<8;j++) {
          float v = acc[i][j];
          u16 hb = f2b_rn(v);
          hs[j] = hb; ls[j] = f2b_rn(v - b2f(hb));
        }
        size_t idx = ((size_t)b*MM2 + gm)*CC + to;
        store8(KH + idx, hs); store8(KL + idx, ls);
      }
    } else {
      // V: [b][c][m] rows (stride VST), m-contiguous; zero the pad
      if (m0 + tm + 8 <= VST) {
        for (int j=0;j<8;j++) {
          int c = to + j;
          u16 hs[8], ls[8];
          #pragma unroll
          for (int i=0;i<8;i++) {
            int gm = m0 + tm + i;
            float v = (gm < MM2) ? acc[i][j] : 0.f;
            u16 hb = f2b_rn(v);
            hs[i] = hb; ls[i] = f2b_rn(v - b2f(hb));
          }
          size_t idx = ((size_t)b*CC + c)*VST + m0 + tm;
          store8(VH + idx, hs); store8(VL + idx, ls);
        }
      }
    }
  }
}

// ---------------------------------------------------------------
// Pass A: rowmax/rowsum over all 2052 cols + bin energies.
// grid 512 = 16b x 32 ntiles(64 rows); wave owns 16 rows, Q frags in regs.
// ---------------------------------------------------------------
__global__ __launch_bounds__(256) void statsA_kernel(
    const u16* __restrict__ QH, const u16* __restrict__ QL,
    const u16* __restrict__ KH, const u16* __restrict__ KL,
    float* __restrict__ rowmax, float* __restrict__ rowsum, float* __restrict__ ebins)
{
  __shared__ u16 kh[64*128], kl[64*128];
  const int t = threadIdx.x;
  const int b = blockIdx.x >> 5;
  const int n0 = (blockIdx.x & 31) * 64;
  const int wv = t >> 6, lane = t & 63;
  const int l15 = lane & 15, lhi = lane >> 4;
  const int nw = n0 + wv*16;

  bf16x8 qh[4], ql[4];
  {
    const size_t rb = ((size_t)b*NN + nw + l15)*CC + lhi*8;
    #pragma unroll
    for (int it=0; it<4; ++it) {
      qh[it] = *(const bf16x8*)(QH + rb + it*32);
      ql[it] = *(const bf16x8*)(QL + rb + it*32);
    }
  }
  float runmx[4], runsum[4];
  #pragma unroll
  for (int r=0;r<4;++r){ runmx[r] = -INFINITY; runsum[r] = 0.f; }

  for (int kt = 0; kt < 33; ++kt) {
    const int m0 = kt*64;
    __syncthreads();
    {
      const int row0 = t >> 4, chunk = t & 15;
      #pragma unroll
      for (int ii=0; ii<4; ++ii) {
        int r = row0 + ii*16; int gm = m0 + r;
        int dst = r*256 + ((chunk*16) ^ ((r&7)<<4));
        uint4 vh = make_uint4(0,0,0,0), vl = make_uint4(0,0,0,0);
        if (gm < MM2) {
          size_t g = ((size_t)b*MM2 + gm)*CC + chunk*8;
          vh = *(const uint4*)(KH + g);
          vl = *(const uint4*)(KL + g);
        }
        *(uint4*)((char*)kh + dst) = vh;
        *(uint4*)((char*)kl + dst) = vl;
      }
    }
    __syncthreads();
    const int mcEnd = (kt == 32) ? 1 : 4;
    for (int mc = 0; mc < mcEnd; ++mc) {
      f32x4 acc = {0.f,0.f,0.f,0.f};
      const int mrow = mc*16 + l15;
      #pragma unroll
      for (int it=0; it<4; ++it) {
        int byt = mrow*256 + ((it*64 + lhi*16) ^ ((mrow&7)<<4));
        bf16x8 bh = *(const bf16x8*)((const char*)kh + byt);
        bf16x8 bl = *(const bf16x8*)((const char*)kl + byt);
        acc = __builtin_amdgcn_mfma_f32_16x16x32_bf16(qh[it], bh, acc, 0,0,0);
        acc = __builtin_amdgcn_mfma_f32_16x16x32_bf16(qh[it], bl, acc, 0,0,0);
        acc = __builtin_amdgcn_mfma_f32_16x16x32_bf16(ql[it], bh, acc, 0,0,0);
      }
      const int m = m0 + mrow;
      if (kt == 32 && l15 < 4) {
        #pragma unroll
        for (int r=0;r<4;++r)
          ebins[((size_t)b*NN + nw + lhi*4 + r)*4 + l15] = acc[r];
      }
      #pragma unroll
      for (int r=0;r<4;++r) {
        float v = (m < MM2) ? acc[r] : -INFINITY;
        float tmx = v;
        tmx = fmaxf(tmx, __shfl_xor(tmx, 1));
        tmx = fmaxf(tmx, __shfl_xor(tmx, 2));
        tmx = fmaxf(tmx, __shfl_xor(tmx, 4));
        tmx = fmaxf(tmx, __shfl_xor(tmx, 8));
        float nm = fmaxf(runmx[r], tmx);
        float ps = expf(v - nm);
        ps += __shfl_xor(ps, 1);
        ps += __shfl_xor(ps, 2);
        ps += __shfl_xor(ps, 4);
        ps += __shfl_xor(ps, 8);
        runsum[r] = runsum[r] * expf(runmx[r] - nm) + ps;
        runmx[r] = nm;
      }
    }
  }
  if (l15 == 0) {
    #pragma unroll
    for (int r=0;r<4;++r) {
      rowmax[(size_t)b*NN + nw + lhi*4 + r] = runmx[r];
      rowsum[(size_t)b*NN + nw + lhi*4 + r] = runsum[r];
    }
  }
}

// ---------------------------------------------------------------
// Pass B: score[b][m] = sum_n exp(e[n][m]-mx[n])/rowsum[n], m<2048.
// grid 512 = 16b x 32 mtiles(64 cols); K frags in regs; Q streamed via LDS.
// ---------------------------------------------------------------
__global__ __launch_bounds__(256) void scoreB_kernel(
    const u16* __restrict__ QH, const u16* __restrict__ QL,
    const u16* __restrict__ KH, const u16* __restrict__ KL,
    const float* __restrict__ rowmax, const float* __restrict__ rowsum,
    float* __restrict__ score)
{
  __shared__ u16 qsh[64*128], qsl[64*128];
  __shared__ float smx[64], sirs[64];
  const int t = threadIdx.x;
  const int b = blockIdx.x >> 5;
  const int m0 = (blockIdx.x & 31) * 64;
  const int wv = t >> 6, lane = t & 63;
  const int l15 = lane & 15, lhi = lane >> 4;
  const int mcol = m0 + wv*16 + l15;

  bf16x8 kbh[4], kbl[4];
  {
    const size_t rb = ((size_t)b*MM2 + mcol)*CC + lhi*8;
    #pragma unroll
    for (int it=0; it<4; ++it) {
      kbh[it] = *(const bf16x8*)(KH + rb + it*32);
      kbl[it] = *(const bf16x8*)(KL + rb + it*32);
    }
  }
  float sacc = 0.f;

  for (int nt = 0; nt < 32; ++nt) {
    const int n0 = nt*64;
    __syncthreads();
    {
      const int row0 = t >> 4, chunk = t & 15;
      #pragma unroll
      for (int ii=0; ii<4; ++ii) {
        int r = row0 + ii*16;
        int dst = r*256 + ((chunk*16) ^ ((r&7)<<4));
        size_t g = ((size_t)b*NN + n0 + r)*CC + chunk*8;
        *(uint4*)((char*)qsh + dst) = *(const uint4*)(QH + g);
        *(uint4*)((char*)qsl + dst) = *(const uint4*)(QL + g);
      }
      if (t < 64) {
        smx[t]  = rowmax[(size_t)b*NN + n0 + t];
        sirs[t] = 1.0f / rowsum[(size_t)b*NN + n0 + t];
      }
    }
    __syncthreads();
    for (int sub = 0; sub < 4; ++sub) {
      f32x4 acc = {0.f,0.f,0.f,0.f};
      const int arow = sub*16 + l15;
      #pragma unroll
      for (int it=0; it<4; ++it) {
        int byt = arow*256 + ((it*64 + lhi*16) ^ ((arow&7)<<4));
        bf16x8 ah = *(const bf16x8*)((const char*)qsh + byt);
        bf16x8 al = *(const bf16x8*)((const char*)qsl + byt);
        acc = __builtin_amdgcn_mfma_f32_16x16x32_bf16(ah, kbh[it], acc, 0,0,0);
        acc = __builtin_amdgcn_mfma_f32_16x16x32_bf16(ah, kbl[it], acc, 0,0,0);
        acc = __builtin_amdgcn_mfma_f32_16x16x32_bf16(al, kbh[it], acc, 0,0,0);
      }
      #pragma unroll
      for (int r=0;r<4;++r) {
        int nl = sub*16 + lhi*4 + r;
        sacc += expf(acc[r] - smx[nl]) * sirs[nl];
      }
    }
  }
  sacc += __shfl_xor(sacc, 16);
  sacc += __shfl_xor(sacc, 32);
  if (lhi == 0) score[(size_t)b*NN + mcol] = sacc;
}

// ---------------------------------------------------------------
// K3a: bin assignment + budget allocation (one block per batch)
// ---------------------------------------------------------------
__global__ __launch_bounds__(256) void bin_kernel(
    const float* __restrict__ score, const float* __restrict__ ebins,
    int* __restrict__ binof, int* __restrict__ kbins)
{
  const int b = blockIdx.x, t = threadIdx.x;
  float wsm[4] = {0.f,0.f,0.f,0.f};
  int   cnt[4] = {0,0,0,0};
  for (int n = t; n < NN; n += 256) {
    float s = score[(size_t)b*NN + n];
    int j = (s >= 1.2f) ? 0 : (s >= 1.0f) ? 1 : (s >= 0.8f) ? 2 : 3;
    binof[(size_t)b*NN + n] = j;
    wsm[j] += ebins[((size_t)b*NN + n)*4 + j];
    cnt[j] += 1;
  }
  #pragma unroll
  for (int j=0;j<4;j++){
    for (int off=1; off<64; off<<=1){
      wsm[j] += __shfl_xor(wsm[j], off);
      cnt[j] += __shfl_xor(cnt[j], off);
    }
  }
  __shared__ float wred[4][4];
  __shared__ int   cred[4][4];
  int wave = t >> 6, lane = t & 63;
  if (lane == 0) for (int j=0;j<4;j++){ wred[wave][j]=wsm[j]; cred[wave][j]=cnt[j]; }
  __syncthreads();
  if (t == 0) {
    float wsum[4]; int cs[4];
    for (int j=0;j<4;j++){
      wsum[j]=wred[0][j]+wred[1][j]+wred[2][j]+wred[3][j];
      cs[j]=cred[0][j]+cred[1][j]+cred[2][j]+cred[3][j];
    }
    float bw[4]; float sbw = 0.f;
    for (int j=0;j<4;j++){
      float wp = wsum[j] / ((float)cs[j] + 1e-8f);
      bw[j] = fmaxf(wp, 0.f); sbw += bw[j];
    }
    float den = fmaxf(sbw, 1e-8f);
    int k0[4]; int sk0 = 0;
    for (int j=0;j<4;j++){
      float p = bw[j] / den;
      int kk = (int)floorf(p * 1024.0f);
      if (kk > cs[j]) kk = cs[j];
      k0[j]=kk; sk0 += kk;
    }
    int deficit = 1024 - sk0;
    int cum = 0;
    for (int j=0;j<4;j++){
      int cap = cs[j] - k0[j];
      int ex = deficit - cum; if (ex < 0) ex = 0; if (ex > cap) ex = cap;
      kbins[b*4+j] = k0[j] + ex;
      cum += cap;
    }
  }
}

// ---------------------------------------------------------------
// K3b: per-(batch,bin) top-k by (score desc, index asc) -> flags
// ---------------------------------------------------------------
__global__ __launch_bounds__(256) void topk_kernel(
    const float* __restrict__ score, const int* __restrict__ binof,
    const int* __restrict__ kbins, int* __restrict__ flags)
{
  __shared__ unsigned long long arr[2048];
  const int t = threadIdx.x;
  const int b = blockIdx.x >> 2;
  const int j = blockIdx.x & 3;
  for (int n = t; n < NN; n += 256) {
    unsigned long long comp = 0ull;
    if (binof[(size_t)b*NN+n] == j) {
      unsigned int bits = __float_as_uint(score[(size_t)b*NN+n]);
      bits = (bits & 0x80000000u) ? ~bits : (bits | 0x80000000u);
      comp = ((unsigned long long)bits << 32) |
             (unsigned long long)(0xFFFFFFFFu - (unsigned)n);
    }
    arr[n] = ~comp;
  }
  __syncthreads();
  for (int ksz = 2; ksz <= 2048; ksz <<= 1) {
    for (int jsz = ksz >> 1; jsz > 0; jsz >>= 1) {
      for (int i = t; i < 2048; i += 256) {
        int ixj = i ^ jsz;
        if (ixj > i) {
          unsigned long long a = arr[i], bv = arr[ixj];
          bool up = ((i & ksz) == 0);
          if ((a > bv) == up) { arr[i] = bv; arr[ixj] = a; }
        }
      }
      __syncthreads();
    }
  }
  const int kb = kbins[b*4+j];
  for (int i = t; i < kb; i += 256) {
    unsigned long long comp = ~arr[i];
    int n = (int)(0xFFFFFFFFu - (unsigned)(comp & 0xFFFFFFFFull));
    flags[(size_t)b*NN + n] = 1;
  }
}

// ---------------------------------------------------------------
// K3c: prefix-scan of flags -> selected index list + index output
// ---------------------------------------------------------------
__global__ __launch_bounds__(256) void scan_kernel(
    const int* __restrict__ flags, int* __restrict__ idxl, float* __restrict__ outIdx)
{
  __shared__ int tsum[256];
  const int b = blockIdx.x, t = threadIdx.x;
  int f[8]; int c8 = 0;
  const int base = t * 8;
  #pragma unroll
  for (int i=0;i<8;i++){ f[i] = flags[(size_t)b*NN + base + i]; c8 += f[i]; }
  tsum[t] = c8;
  __syncthreads();
  for (int off=1; off<256; off<<=1) {
    int v = (t >= off) ? tsum[t-off] : 0;
    __syncthreads();
    tsum[t] += v;
    __syncthreads();
  }
  int pos = tsum[t] - c8;
  #pragma unroll
  for (int i=0;i<8;i++){
    if (f[i] && pos < MM) {
      idxl[(size_t)b*MM + pos] = base + i;
      outIdx[(size_t)b*MM + pos] = (float)(base + i);
      pos++;
    }
  }
}

// ---------------------------------------------------------------
// Pass C: selected rows -> recompute e (bf16x3 MFMA), P, PV (MFMA).
// grid 256 = 16b x 16 seltiles(64 rows); wave owns 16 rows.
// ---------------------------------------------------------------
__global__ __launch_bounds__(256) void outC_kernel(
    const u16* __restrict__ QH, const u16* __restrict__ QL,
    const u16* __restrict__ KH, const u16* __restrict__ KL,
    const u16* __restrict__ VH, const u16* __restrict__ VL,
    const float* __restrict__ rowmax, const float* __restrict__ rowsum,
    const int* __restrict__ idxl, float* __restrict__ out0)
{
  __shared__ u16 kh[64*128], kl[64*128];
  __shared__ u16 vsh[128*64], vsl[128*64];
  __shared__ u16 ph[4][16][72];
  __shared__ float smx[64], sirs[64];
  __shared__ int rid[64];
  const int t = threadIdx.x;
  const int b = blockIdx.x >> 4;
  const int s0 = (blockIdx.x & 15) * 64;
  const int wv = t >> 6, lane = t & 63;
  const int l15 = lane & 15, lhi = lane >> 4;

  if (t < 64) {
    int n = idxl[(size_t)b*MM + s0 + t];
    rid[t] = n;
    smx[t] = rowmax[(size_t)b*NN + n];
    sirs[t] = 1.0f / rowsum[(size_t)b*NN + n];
  }
  __syncthreads();

  bf16x8 qh[4], ql[4];
  {
    int nq = rid[wv*16 + l15];
    const size_t rb = ((size_t)b*NN + nq)*CC + lhi*8;
    #pragma unroll
    for (int it=0; it<4; ++it) {
      qh[it] = *(const bf16x8*)(QH + rb + it*32);
      ql[it] = *(const bf16x8*)(QL + rb + it*32);
    }
  }
  f32x4 oacc[8];
  #pragma unroll
  for (int ct=0; ct<8; ++ct) oacc[ct] = (f32x4){0.f,0.f,0.f,0.f};

  for (int kt = 0; kt < 33; ++kt) {
    const int m0 = kt*64;
    __syncthreads();
    {
      // stage K tile [64 m][128 c]
      const int row0 = t >> 4, chunk = t & 15;
      #pragma unroll
      for (int ii=0; ii<4; ++ii) {
        int r = row0 + ii*16; int gm = m0 + r;
        int dst = r*256 + ((chunk*16) ^ ((r&7)<<4));
        uint4 vh4 = make_uint4(0,0,0,0), vl4 = make_uint4(0,0,0,0);
        if (gm < MM2) {
          size_t g = ((size_t)b*MM2 + gm)*CC + chunk*8;
          vh4 = *(const uint4*)(KH + g);
          vl4 = *(const uint4*)(KL + g);
        }
        *(uint4*)((char*)kh + dst) = vh4;
        *(uint4*)((char*)kl + dst) = vl4;
      }
      // stage V tile [128 c][64 m]
      const int c0 = t >> 3, mch = t & 7;
      #pragma unroll
      for (int ii=0; ii<4; ++ii) {
        int c = c0 + ii*32;
        int gm = m0 + mch*8;
        int dst = c*128 + ((mch*16) ^ ((c&7)<<4));
        uint4 vh4 = make_uint4(0,0,0,0), vl4 = make_uint4(0,0,0,0);
        if (gm < VST) {
          size_t g = ((size_t)b*CC + c)*VST + gm;
          vh4 = *(const uint4*)(VH + g);
          vl4 = *(const uint4*)(VL + g);
        }
        *(uint4*)((char*)vsh + dst) = vh4;
        *(uint4*)((char*)vsl + dst) = vl4;
      }
    }
    __syncthreads();

    // QK^T + softmax -> P (per-wave private LDS region)
    for (int mc = 0; mc < 4; ++mc) {
      f32x4 acc = {0.f,0.f,0.f,0.f};
      const int mrow = mc*16 + l15;
      #pragma unroll
      for (int it=0; it<4; ++it) {
        int byt = mrow*256 + ((it*64 + lhi*16) ^ ((mrow&7)<<4));
        bf16x8 bh = *(const bf16x8*)((const char*)kh + byt);
        bf16x8 bl = *(const bf16x8*)((const char*)kl + byt);
        acc = __builtin_amdgcn_mfma_f32_16x16x32_bf16(qh[it], bh, acc, 0,0,0);
        acc = __builtin_amdgcn_mfma_f32_16x16x32_bf16(qh[it], bl, acc, 0,0,0);
        acc = __builtin_amdgcn_mfma_f32_16x16x32_bf16(ql[it], bh, acc, 0,0,0);
      }
      const int m = m0 + mrow;
      #pragma unroll
      for (int r=0;r<4;++r) {
        int rl = lhi*4 + r;
        float p = 0.f;
        if (m < MM2) p = expf(acc[r] - smx[wv*16+rl]) * sirs[wv*16+rl];
        ph[wv][rl][mc*16 + l15] = f2b_rn(p);
      }
    }
    // PV (same-wave LDS ordering is in-order; no block barrier needed)
    #pragma unroll
    for (int ki=0; ki<2; ++ki) {
      int pb = l15*144 + ki*64 + lhi*16;
      bf16x8 pa = *(const bf16x8*)((const char*)&ph[wv][0][0] + pb);
      #pragma unroll
      for (int ct=0; ct<8; ++ct) {
        int c = ct*16 + l15;
        int byt = c*128 + ((ki*64 + lhi*16) ^ ((c&7)<<4));
        bf16x8 vb = *(const bf16x8*)((const char*)vsh + byt);
        bf16x8 vbl = *(const bf16x8*)((const char*)vsl + byt);
        oacc[ct] = __builtin_amdgcn_mfma_f32_16x16x32_bf16(pa, vb, oacc[ct], 0,0,0);
        oacc[ct] = __builtin_amdgcn_mfma_f32_16x16x32_bf16(pa, vbl, oacc[ct], 0,0,0);
      }
    }
  }
  #pragma unroll
  for (int ct=0; ct<8; ++ct) {
    #pragma unroll
    for (int r=0;r<4;++r) {
      out0[((size_t)b*CC + ct*16 + l15)*MM + s0 + wv*16 + lhi*4 + r] = oacc[ct][r];
    }
  }
}

// ---------------------------------------------------------------
extern "C" void kernel_launch(void* const* d_in, const int* in_sizes, int n_in,
                              void* d_out, int out_size, void* d_ws, size_t ws_size,
                              hipStream_t stream) {
  const float* x  = (const float*)d_in[0];
  const float* Wq = (const float*)d_in[1];
  const float* Wk = (const float*)d_in[2];
  const float* Wv = (const float*)d_in[3];
  const float* bt = (const float*)d_in[4];
  float* out = (float*)d_out;
  char* ws = (char*)d_ws;

  u16* QH = (u16*)(ws + oQH);
  u16* QL = (u16*)(ws + oQL);
  u16* KH = (u16*)(ws + oKH);
  u16* KL = (u16*)(ws + oKL);
  u16* VH = (u16*)(ws + oVH);
  u16* VL = (u16*)(ws + oVL);
  float* rmax  = (float*)(ws + oRMAX);
  float* rsum  = (float*)(ws + oRSUM);
  float* ebins = (float*)(ws + oEB);
  float* score = (float*)(ws + oSCORE);
  int* binof = (int*)(ws + oBIN);
  int* kbins = (int*)(ws + oKB);
  int* flags = (int*)(ws + oFL);
  int* idxl  = (int*)(ws + oIDX);

  float* out0   = out;                        // (B,C,M)
  float* outIdx = out + (size_t)BB*CC*MM;     // (B,1,M) as float

  (void)hipMemsetAsync(flags, 0, (size_t)BB*NN*sizeof(int), stream);

  hipLaunchKernelGGL(proj_q_kernel,  dim3(256), dim3(256), 0, stream, x, Wq, QH, QL);
  hipLaunchKernelGGL(proj_kv_kernel, dim3(272), dim3(256), 0, stream, x, Wk, Wv, bt, KH, KL, VH, VL);
  hipLaunchKernelGGL(statsA_kernel,  dim3(512), dim3(256), 0, stream, QH, QL, KH, KL, rmax, rsum, ebins);
  hipLaunchKernelGGL(scoreB_kernel,  dim3(512), dim3(256), 0, stream, QH, QL, KH, KL, rmax, rsum, score);
  hipLaunchKernelGGL(bin_kernel,     dim3(16),  dim3(256), 0, stream, score, ebins, binof, kbins);
  hipLaunchKernelGGL(topk_kernel,    dim3(64),  dim3(256), 0, stream, score, binof, kbins, flags);
  hipLaunchKernelGGL(scan_kernel,    dim3(16),  dim3(256), 0, stream, flags, idxl, outIdx);
  hipLaunchKernelGGL(outC_kernel,    dim3(256), dim3(256), 0, stream, QH, QL, KH, KL, VH, VL, rmax, rsum, idxl, out0);
}

// Round 4
// 554.072 us; speedup vs baseline: 3.2305x; 1.2512x over previous
//
#include <hip/hip_runtime.h>

#define BB 16
#define CC 128
#define NN 2048
#define MM2 2052
#define VST 2056   // padded V row stride (16B-aligned rows)
#define MM 1024

constexpr float RSQRT_C = 0.08838834764831845f; // 1/sqrt(128)

typedef unsigned short u16;
typedef __attribute__((ext_vector_type(8))) short bf16x8;
typedef __attribute__((ext_vector_type(4))) float f32x4;

__device__ inline u16 f2b_rn(float f) {
  unsigned u = __float_as_uint(f);
  unsigned r = u + 0x7fffu + ((u >> 16) & 1u);
  return (u16)(r >> 16);
}
__device__ inline float b2f(u16 h) { return __uint_as_float(((unsigned)h) << 16); }

__device__ inline void store8(u16* dst, const u16 h[8]) {
  uint4 v;
  v.x = (unsigned)h[0] | ((unsigned)h[1] << 16);
  v.y = (unsigned)h[2] | ((unsigned)h[3] << 16);
  v.z = (unsigned)h[4] | ((unsigned)h[5] << 16);
  v.w = (unsigned)h[6] | ((unsigned)h[7] << 16);
  *(uint4*)dst = v;
}

// ---- workspace layout (byte offsets) ----
constexpr size_t SZ_Q  = (size_t)BB*NN*CC*2;
constexpr size_t SZ_K  = (size_t)BB*MM2*CC*2;
constexpr size_t SZ_V  = (size_t)BB*CC*VST*2;
constexpr size_t oQH = 0;
constexpr size_t oQL = oQH + SZ_Q;
constexpr size_t oKH = oQL + SZ_Q;
constexpr size_t oKL = oKH + SZ_K;
constexpr size_t oVH = oKL + SZ_K;
constexpr size_t oVL = oVH + SZ_V;
constexpr size_t oRSUM = oVL + SZ_V;                  // BB*NN f32
constexpr size_t oEB   = oRSUM + (size_t)BB*NN*4;     // BB*NN*4 f32
constexpr size_t oSCORE= oEB   + (size_t)BB*NN*16;
constexpr size_t oBIN  = oSCORE+ (size_t)BB*NN*4;     // int
constexpr size_t oKB   = oBIN  + (size_t)BB*NN*4;     // BB*4 int
constexpr size_t oFL   = oKB   + 256;                 // BB*NN int
constexpr size_t oIDX  = oFL   + (size_t)BB*NN*4;     // BB*MM int

// ---------------------------------------------------------------
// proj_q: Q[b][n][c] = (Wq x)/sqrt(C), emitted as bf16 hi/lo
// ---------------------------------------------------------------
__global__ __launch_bounds__(256) void proj_q_kernel(
    const float* __restrict__ x, const float* __restrict__ Wq,
    u16* __restrict__ QH, u16* __restrict__ QL)
{
  __shared__ float xs[128][132];
  __shared__ float ws[128][132];
  const int t  = threadIdx.x;
  const int b  = blockIdx.x >> 4;
  const int n0 = (blockIdx.x & 15) * 128;

  for (int i = t; i < 128*128; i += 256) {
    int c = i >> 7, n = i & 127;
    xs[c][n] = x[((size_t)(b*CC)+c)*NN + n0 + n];
  }
  for (int i = t; i < 128*128; i += 256) {
    int o = i >> 7, c = i & 127;
    ws[c][o] = Wq[o*CC + c];
  }
  __syncthreads();

  const int tn = (t & 15) * 8;
  const int to = (t >> 4) * 8;
  float acc[8][8];
  #pragma unroll
  for (int i=0;i<8;i++) {
    #pragma unroll
    for (int j=0;j<8;j++) acc[i][j]=0.f;
  }
  for (int c = 0; c < 128; ++c) {
    float xv[8], wv[8];
    #pragma unroll
    for (int i=0;i<8;i++) xv[i] = xs[c][tn+i];
    #pragma unroll
    for (int j=0;j<8;j++) wv[j] = ws[c][to+j];
    #pragma unroll
    for (int i=0;i<8;i++) {
      #pragma unroll
      for (int j=0;j<8;j++) acc[i][j] = fmaf(xv[i], wv[j], acc[i][j]);
    }
  }
  for (int i=0;i<8;i++) {
    u16 hs[8], ls[8];
    #pragma unroll
    for (int j=0;j<8;j++) {
      float v = acc[i][j] * RSQRT_C;
      u16 hb = f2b_rn(v);
      hs[j] = hb; ls[j] = f2b_rn(v - b2f(hb));
    }
    size_t idx = ((size_t)b*NN + n0+tn+i)*CC + to;
    store8(QH + idx, hs); store8(QL + idx, ls);
  }
}

// ---------------------------------------------------------------
// proj_kv: K[b][m][c] hi/lo, V[b][c][m] hi/lo (V rows padded to 2056)
// ---------------------------------------------------------------
__global__ __launch_bounds__(256) void proj_kv_kernel(
    const float* __restrict__ x, const float* __restrict__ Wk, const float* __restrict__ Wv,
    const float* __restrict__ bt,
    u16* __restrict__ KH, u16* __restrict__ KL, u16* __restrict__ VH, u16* __restrict__ VL)
{
  __shared__ float xs[128][132];
  __shared__ float ws[128][132];
  const int t  = threadIdx.x;
  const int b  = blockIdx.x & 15;
  const int m0 = (blockIdx.x >> 4) * 128;

  for (int i = t; i < 128*128; i += 256) {
    int c = i >> 7, m = i & 127; int gm = m0 + m;
    float v = 0.f;
    if (gm < NN) v = x[((size_t)(b*CC)+c)*NN + gm];
    else if (gm < MM2) v = bt[c*4 + (gm - NN)];
    xs[c][m] = v;
  }
  const int tm = (t & 15) * 8;
  const int to = (t >> 4) * 8;

  for (int pass = 0; pass < 2; ++pass) {
    const float* W = pass ? Wv : Wk;
    __syncthreads();
    for (int i = t; i < 128*128; i += 256) {
      int o = i >> 7, c = i & 127;
      ws[c][o] = W[o*CC + c];
    }
    __syncthreads();
    float acc[8][8];
    #pragma unroll
    for (int i=0;i<8;i++) {
      #pragma unroll
      for (int j=0;j<8;j++) acc[i][j]=0.f;
    }
    for (int c = 0; c < 128; ++c) {
      float xv[8], wv[8];
      #pragma unroll
      for (int i=0;i<8;i++) xv[i] = xs[c][tm+i];
      #pragma unroll
      for (int j=0;j<8;j++) wv[j] = ws[c][to+j];
      #pragma unroll
      for (int i=0;i<8;i++) {
        #pragma unroll
        for (int j=0;j<8;j++) acc[i][j] = fmaf(xv[i], wv[j], acc[i][j]);
      }
    }
    if (pass == 0) {
      for (int i=0;i<8;i++) {
        int gm = m0 + tm + i;
        if (gm >= MM2) continue;
        u16 hs[8], ls[8];
        #pragma unroll
        for (int j=0;j<8;j++) {
          float v = acc[i][j];
          u16 hb = f2b_rn(v);
          hs[j] = hb; ls[j] = f2b_rn(v - b2f(hb));
        }
        size_t idx = ((size_t)b*MM2 + gm)*CC + to;
        store8(KH + idx, hs); store8(KL + idx, ls);
      }
    } else {
      if (m0 + tm + 8 <= VST) {
        for (int j=0;j<8;j++) {
          int c = to + j;
          u16 hs[8], ls[8];
          #pragma unroll
          for (int i=0;i<8;i++) {
            int gm = m0 + tm + i;
            float v = (gm < MM2) ? acc[i][j] : 0.f;
            u16 hb = f2b_rn(v);
            hs[i] = hb; ls[i] = f2b_rn(v - b2f(hb));
          }
          size_t idx = ((size_t)b*CC + c)*VST + m0 + tm;
          store8(VH + idx, hs); store8(VL + idx, ls);
        }
      }
    }
  }
}

// ---------------------------------------------------------------
// Pass A: rowsum of exp(e) over all 2052 cols + bin energies.
// NO max subtraction (e bounded ~[-8,8]); per-lane accumulate, one
// shuffle-reduce at the end.
// ---------------------------------------------------------------
__global__ __launch_bounds__(256) void statsA_kernel(
    const u16* __restrict__ QH, const u16* __restrict__ QL,
    const u16* __restrict__ KH, const u16* __restrict__ KL,
    float* __restrict__ rowsum, float* __restrict__ ebins)
{
  __shared__ u16 kh[64*128], kl[64*128];
  const int t = threadIdx.x;
  const int b = blockIdx.x >> 5;
  const int n0 = (blockIdx.x & 31) * 64;
  const int wv = t >> 6, lane = t & 63;
  const int l15 = lane & 15, lhi = lane >> 4;
  const int nw = n0 + wv*16;

  bf16x8 qh[4], ql[4];
  {
    const size_t rb = ((size_t)b*NN + nw + l15)*CC + lhi*8;
    #pragma unroll
    for (int it=0; it<4; ++it) {
      qh[it] = *(const bf16x8*)(QH + rb + it*32);
      ql[it] = *(const bf16x8*)(QL + rb + it*32);
    }
  }
  float runsum[4] = {0.f, 0.f, 0.f, 0.f};

  for (int kt = 0; kt < 33; ++kt) {
    const int m0 = kt*64;
    __syncthreads();
    {
      const int row0 = t >> 4, chunk = t & 15;
      #pragma unroll
      for (int ii=0; ii<4; ++ii) {
        int r = row0 + ii*16; int gm = m0 + r;
        int dst = r*256 + ((chunk*16) ^ ((r&7)<<4));
        uint4 vh = make_uint4(0,0,0,0), vl = make_uint4(0,0,0,0);
        if (gm < MM2) {
          size_t g = ((size_t)b*MM2 + gm)*CC + chunk*8;
          vh = *(const uint4*)(KH + g);
          vl = *(const uint4*)(KL + g);
        }
        *(uint4*)((char*)kh + dst) = vh;
        *(uint4*)((char*)kl + dst) = vl;
      }
    }
    __syncthreads();
    const int mcEnd = (kt == 32) ? 1 : 4;
    for (int mc = 0; mc < mcEnd; ++mc) {
      f32x4 acc = {0.f,0.f,0.f,0.f};
      const int mrow = mc*16 + l15;
      #pragma unroll
      for (int it=0; it<4; ++it) {
        int byt = mrow*256 + ((it*64 + lhi*16) ^ ((mrow&7)<<4));
        bf16x8 bh = *(const bf16x8*)((const char*)kh + byt);
        bf16x8 bl = *(const bf16x8*)((const char*)kl + byt);
        acc = __builtin_amdgcn_mfma_f32_16x16x32_bf16(qh[it], bh, acc, 0,0,0);
        acc = __builtin_amdgcn_mfma_f32_16x16x32_bf16(qh[it], bl, acc, 0,0,0);
        acc = __builtin_amdgcn_mfma_f32_16x16x32_bf16(ql[it], bh, acc, 0,0,0);
      }
      const int m = m0 + mrow;
      if (kt == 32 && l15 < 4) {
        #pragma unroll
        for (int r=0;r<4;++r)
          ebins[((size_t)b*NN + nw + lhi*4 + r)*4 + l15] = acc[r];
      }
      const bool valid = (m < MM2);
      #pragma unroll
      for (int r=0;r<4;++r)
        runsum[r] += valid ? __expf(acc[r]) : 0.f;
    }
  }
  #pragma unroll
  for (int r=0;r<4;++r) {
    runsum[r] += __shfl_xor(runsum[r], 1);
    runsum[r] += __shfl_xor(runsum[r], 2);
    runsum[r] += __shfl_xor(runsum[r], 4);
    runsum[r] += __shfl_xor(runsum[r], 8);
  }
  if (l15 == 0) {
    #pragma unroll
    for (int r=0;r<4;++r)
      rowsum[(size_t)b*NN + nw + lhi*4 + r] = runsum[r];
  }
}

// ---------------------------------------------------------------
// Pass B: score[b][m] = sum_n exp(e[n][m])/rowsum[n], m<2048.
// ---------------------------------------------------------------
__global__ __launch_bounds__(256) void scoreB_kernel(
    const u16* __restrict__ QH, const u16* __restrict__ QL,
    const u16* __restrict__ KH, const u16* __restrict__ KL,
    const float* __restrict__ rowsum, float* __restrict__ score)
{
  __shared__ u16 qsh[64*128], qsl[64*128];
  __shared__ float sirs[64];
  const int t = threadIdx.x;
  const int b = blockIdx.x >> 5;
  const int m0 = (blockIdx.x & 31) * 64;
  const int wv = t >> 6, lane = t & 63;
  const int l15 = lane & 15, lhi = lane >> 4;
  const int mcol = m0 + wv*16 + l15;

  bf16x8 kbh[4], kbl[4];
  {
    const size_t rb = ((size_t)b*MM2 + mcol)*CC + lhi*8;
    #pragma unroll
    for (int it=0; it<4; ++it) {
      kbh[it] = *(const bf16x8*)(KH + rb + it*32);
      kbl[it] = *(const bf16x8*)(KL + rb + it*32);
    }
  }
  float sacc = 0.f;

  for (int nt = 0; nt < 32; ++nt) {
    const int n0 = nt*64;
    __syncthreads();
    {
      const int row0 = t >> 4, chunk = t & 15;
      #pragma unroll
      for (int ii=0; ii<4; ++ii) {
        int r = row0 + ii*16;
        int dst = r*256 + ((chunk*16) ^ ((r&7)<<4));
        size_t g = ((size_t)b*NN + n0 + r)*CC + chunk*8;
        *(uint4*)((char*)qsh + dst) = *(const uint4*)(QH + g);
        *(uint4*)((char*)qsl + dst) = *(const uint4*)(QL + g);
      }
      if (t < 64) sirs[t] = 1.0f / rowsum[(size_t)b*NN + n0 + t];
    }
    __syncthreads();
    for (int sub = 0; sub < 4; ++sub) {
      f32x4 acc = {0.f,0.f,0.f,0.f};
      const int arow = sub*16 + l15;
      #pragma unroll
      for (int it=0; it<4; ++it) {
        int byt = arow*256 + ((it*64 + lhi*16) ^ ((arow&7)<<4));
        bf16x8 ah = *(const bf16x8*)((const char*)qsh + byt);
        bf16x8 al = *(const bf16x8*)((const char*)qsl + byt);
        acc = __builtin_amdgcn_mfma_f32_16x16x32_bf16(ah, kbh[it], acc, 0,0,0);
        acc = __builtin_amdgcn_mfma_f32_16x16x32_bf16(ah, kbl[it], acc, 0,0,0);
        acc = __builtin_amdgcn_mfma_f32_16x16x32_bf16(al, kbh[it], acc, 0,0,0);
      }
      #pragma unroll
      for (int r=0;r<4;++r) {
        int nl = sub*16 + lhi*4 + r;
        sacc += __expf(acc[r]) * sirs[nl];
      }
    }
  }
  sacc += __shfl_xor(sacc, 16);
  sacc += __shfl_xor(sacc, 32);
  if (lhi == 0) score[(size_t)b*NN + mcol] = sacc;
}

// ---------------------------------------------------------------
// K3a: bin assignment + budget allocation (one block per batch)
// ---------------------------------------------------------------
__global__ __launch_bounds__(256) void bin_kernel(
    const float* __restrict__ score, const float* __restrict__ ebins,
    int* __restrict__ binof, int* __restrict__ kbins)
{
  const int b = blockIdx.x, t = threadIdx.x;
  float wsm[4] = {0.f,0.f,0.f,0.f};
  int   cnt[4] = {0,0,0,0};
  for (int n = t; n < NN; n += 256) {
    float s = score[(size_t)b*NN + n];
    int j = (s >= 1.2f) ? 0 : (s >= 1.0f) ? 1 : (s >= 0.8f) ? 2 : 3;
    binof[(size_t)b*NN + n] = j;
    wsm[j] += ebins[((size_t)b*NN + n)*4 + j];
    cnt[j] += 1;
  }
  #pragma unroll
  for (int j=0;j<4;j++){
    for (int off=1; off<64; off<<=1){
      wsm[j] += __shfl_xor(wsm[j], off);
      cnt[j] += __shfl_xor(cnt[j], off);
    }
  }
  __shared__ float wred[4][4];
  __shared__ int   cred[4][4];
  int wave = t >> 6, lane = t & 63;
  if (lane == 0) for (int j=0;j<4;j++){ wred[wave][j]=wsm[j]; cred[wave][j]=cnt[j]; }
  __syncthreads();
  if (t == 0) {
    float wsum[4]; int cs[4];
    for (int j=0;j<4;j++){
      wsum[j]=wred[0][j]+wred[1][j]+wred[2][j]+wred[3][j];
      cs[j]=cred[0][j]+cred[1][j]+cred[2][j]+cred[3][j];
    }
    float bw[4]; float sbw = 0.f;
    for (int j=0;j<4;j++){
      float wp = wsum[j] / ((float)cs[j] + 1e-8f);
      bw[j] = fmaxf(wp, 0.f); sbw += bw[j];
    }
    float den = fmaxf(sbw, 1e-8f);
    int k0[4]; int sk0 = 0;
    for (int j=0;j<4;j++){
      float p = bw[j] / den;
      int kk = (int)floorf(p * 1024.0f);
      if (kk > cs[j]) kk = cs[j];
      k0[j]=kk; sk0 += kk;
    }
    int deficit = 1024 - sk0;
    int cum = 0;
    for (int j=0;j<4;j++){
      int cap = cs[j] - k0[j];
      int ex = deficit - cum; if (ex < 0) ex = 0; if (ex > cap) ex = cap;
      kbins[b*4+j] = k0[j] + ex;
      cum += cap;
    }
  }
}

// ---------------------------------------------------------------
// K3b: per-(batch,bin) top-k by (score desc, index asc) -> flags
// ---------------------------------------------------------------
__global__ __launch_bounds__(256) void topk_kernel(
    const float* __restrict__ score, const int* __restrict__ binof,
    const int* __restrict__ kbins, int* __restrict__ flags)
{
  __shared__ unsigned long long arr[2048];
  const int t = threadIdx.x;
  const int b = blockIdx.x >> 2;
  const int j = blockIdx.x & 3;
  for (int n = t; n < NN; n += 256) {
    unsigned long long comp = 0ull;
    if (binof[(size_t)b*NN+n] == j) {
      unsigned int bits = __float_as_uint(score[(size_t)b*NN+n]);
      bits = (bits & 0x80000000u) ? ~bits : (bits | 0x80000000u);
      comp = ((unsigned long long)bits << 32) |
             (unsigned long long)(0xFFFFFFFFu - (unsigned)n);
    }
    arr[n] = ~comp;
  }
  __syncthreads();
  for (int ksz = 2; ksz <= 2048; ksz <<= 1) {
    for (int jsz = ksz >> 1; jsz > 0; jsz >>= 1) {
      for (int i = t; i < 2048; i += 256) {
        int ixj = i ^ jsz;
        if (ixj > i) {
          unsigned long long a = arr[i], bv = arr[ixj];
          bool up = ((i & ksz) == 0);
          if ((a > bv) == up) { arr[i] = bv; arr[ixj] = a; }
        }
      }
      __syncthreads();
    }
  }
  const int kb = kbins[b*4+j];
  for (int i = t; i < kb; i += 256) {
    unsigned long long comp = ~arr[i];
    int n = (int)(0xFFFFFFFFu - (unsigned)(comp & 0xFFFFFFFFull));
    flags[(size_t)b*NN + n] = 1;
  }
}

// ---------------------------------------------------------------
// K3c: prefix-scan of flags -> selected index list + index output
// ---------------------------------------------------------------
__global__ __launch_bounds__(256) void scan_kernel(
    const int* __restrict__ flags, int* __restrict__ idxl, float* __restrict__ outIdx)
{
  __shared__ int tsum[256];
  const int b = blockIdx.x, t = threadIdx.x;
  int f[8]; int c8 = 0;
  const int base = t * 8;
  #pragma unroll
  for (int i=0;i<8;i++){ f[i] = flags[(size_t)b*NN + base + i]; c8 += f[i]; }
  tsum[t] = c8;
  __syncthreads();
  for (int off=1; off<256; off<<=1) {
    int v = (t >= off) ? tsum[t-off] : 0;
    __syncthreads();
    tsum[t] += v;
    __syncthreads();
  }
  int pos = tsum[t] - c8;
  #pragma unroll
  for (int i=0;i<8;i++){
    if (f[i] && pos < MM) {
      idxl[(size_t)b*MM + pos] = base + i;
      outIdx[(size_t)b*MM + pos] = (float)(base + i);
      pos++;
    }
  }
}

// ---------------------------------------------------------------
// Pass C: selected rows -> recompute e (bf16x3 MFMA), P, PV (MFMA).
// ---------------------------------------------------------------
__global__ __launch_bounds__(256) void outC_kernel(
    const u16* __restrict__ QH, const u16* __restrict__ QL,
    const u16* __restrict__ KH, const u16* __restrict__ KL,
    const u16* __restrict__ VH, const u16* __restrict__ VL,
    const float* __restrict__ rowsum,
    const int* __restrict__ idxl, float* __restrict__ out0)
{
  __shared__ u16 kh[64*128], kl[64*128];
  __shared__ u16 vsh[128*64], vsl[128*64];
  __shared__ u16 ph[4][16][72];
  __shared__ float sirs[64];
  __shared__ int rid[64];
  const int t = threadIdx.x;
  const int b = blockIdx.x >> 4;
  const int s0 = (blockIdx.x & 15) * 64;
  const int wv = t >> 6, lane = t & 63;
  const int l15 = lane & 15, lhi = lane >> 4;

  if (t < 64) {
    int n = idxl[(size_t)b*MM + s0 + t];
    rid[t] = n;
    sirs[t] = 1.0f / rowsum[(size_t)b*NN + n];
  }
  __syncthreads();

  bf16x8 qh[4], ql[4];
  {
    int nq = rid[wv*16 + l15];
    const size_t rb = ((size_t)b*NN + nq)*CC + lhi*8;
    #pragma unroll
    for (int it=0; it<4; ++it) {
      qh[it] = *(const bf16x8*)(QH + rb + it*32);
      ql[it] = *(const bf16x8*)(QL + rb + it*32);
    }
  }
  f32x4 oacc[8];
  #pragma unroll
  for (int ct=0; ct<8; ++ct) oacc[ct] = (f32x4){0.f,0.f,0.f,0.f};

  for (int kt = 0; kt < 33; ++kt) {
    const int m0 = kt*64;
    __syncthreads();
    {
      const int row0 = t >> 4, chunk = t & 15;
      #pragma unroll
      for (int ii=0; ii<4; ++ii) {
        int r = row0 + ii*16; int gm = m0 + r;
        int dst = r*256 + ((chunk*16) ^ ((r&7)<<4));
        uint4 vh4 = make_uint4(0,0,0,0), vl4 = make_uint4(0,0,0,0);
        if (gm < MM2) {
          size_t g = ((size_t)b*MM2 + gm)*CC + chunk*8;
          vh4 = *(const uint4*)(KH + g);
          vl4 = *(const uint4*)(KL + g);
        }
        *(uint4*)((char*)kh + dst) = vh4;
        *(uint4*)((char*)kl + dst) = vl4;
      }
      const int c0 = t >> 3, mch = t & 7;
      #pragma unroll
      for (int ii=0; ii<4; ++ii) {
        int c = c0 + ii*32;
        int gm = m0 + mch*8;
        int dst = c*128 + ((mch*16) ^ ((c&7)<<4));
        uint4 vh4 = make_uint4(0,0,0,0), vl4 = make_uint4(0,0,0,0);
        if (gm < VST) {
          size_t g = ((size_t)b*CC + c)*VST + gm;
          vh4 = *(const uint4*)(VH + g);
          vl4 = *(const uint4*)(VL + g);
        }
        *(uint4*)((char*)vsh + dst) = vh4;
        *(uint4*)((char*)vsl + dst) = vl4;
      }
    }
    __syncthreads();

    for (int mc = 0; mc < 4; ++mc) {
      f32x4 acc = {0.f,0.f,0.f,0.f};
      const int mrow = mc*16 + l15;
      #pragma unroll
      for (int it=0; it<4; ++it) {
        int byt = mrow*256 + ((it*64 + lhi*16) ^ ((mrow&7)<<4));
        bf16x8 bh = *(const bf16x8*)((const char*)kh + byt);
        bf16x8 bl = *(const bf16x8*)((const char*)kl + byt);
        acc = __builtin_amdgcn_mfma_f32_16x16x32_bf16(qh[it], bh, acc, 0,0,0);
        acc = __builtin_amdgcn_mfma_f32_16x16x32_bf16(qh[it], bl, acc, 0,0,0);
        acc = __builtin_amdgcn_mfma_f32_16x16x32_bf16(ql[it], bh, acc, 0,0,0);
      }
      const int m = m0 + mrow;
      #pragma unroll
      for (int r=0;r<4;++r) {
        int rl = lhi*4 + r;
        float p = 0.f;
        if (m < MM2) p = __expf(acc[r]) * sirs[wv*16+rl];
        ph[wv][rl][mc*16 + l15] = f2b_rn(p);
      }
    }
    #pragma unroll
    for (int ki=0; ki<2; ++ki) {
      int pb = l15*144 + ki*64 + lhi*16;
      bf16x8 pa = *(const bf16x8*)((const char*)&ph[wv][0][0] + pb);
      #pragma unroll
      for (int ct=0; ct<8; ++ct) {
        int c = ct*16 + l15;
        int byt = c*128 + ((ki*64 + lhi*16) ^ ((c&7)<<4));
        bf16x8 vb = *(const bf16x8*)((const char*)vsh + byt);
        bf16x8 vbl = *(const bf16x8*)((const char*)vsl + byt);
        oacc[ct] = __builtin_amdgcn_mfma_f32_16x16x32_bf16(pa, vb, oacc[ct], 0,0,0);
        oacc[ct] = __builtin_amdgcn_mfma_f32_16x16x32_bf16(pa, vbl, oacc[ct], 0,0,0);
      }
    }
  }
  #pragma unroll
  for (int ct=0; ct<8; ++ct) {
    #pragma unroll
    for (int r=0;r<4;++r) {
      out0[((size_t)b*CC + ct*16 + l15)*MM + s0 + wv*16 + lhi*4 + r] = oacc[ct][r];
    }
  }
}

// ---------------------------------------------------------------
extern "C" void kernel_launch(void* const* d_in, const int* in_sizes, int n_in,
                              void* d_out, int out_size, void* d_ws, size_t ws_size,
                              hipStream_t stream) {
  const float* x  = (const float*)d_in[0];
  const float* Wq = (const float*)d_in[1];
  const float* Wk = (const float*)d_in[2];
  const float* Wv = (const float*)d_in[3];
  const float* bt = (const float*)d_in[4];
  float* out = (float*)d_out;
  char* ws = (char*)d_ws;

  u16* QH = (u16*)(ws + oQH);
  u16* QL = (u16*)(ws + oQL);
  u16* KH = (u16*)(ws + oKH);
  u16* KL = (u16*)(ws + oKL);
  u16* VH = (u16*)(ws + oVH);
  u16* VL = (u16*)(ws + oVL);
  float* rsum  = (float*)(ws + oRSUM);
  float* ebins = (float*)(ws + oEB);
  float* score = (float*)(ws + oSCORE);
  int* binof = (int*)(ws + oBIN);
  int* kbins = (int*)(ws + oKB);
  int* flags = (int*)(ws + oFL);
  int* idxl  = (int*)(ws + oIDX);

  float* out0   = out;                        // (B,C,M)
  float* outIdx = out + (size_t)BB*CC*MM;     // (B,1,M) as float

  (void)hipMemsetAsync(flags, 0, (size_t)BB*NN*sizeof(int), stream);

  hipLaunchKernelGGL(proj_q_kernel,  dim3(256), dim3(256), 0, stream, x, Wq, QH, QL);
  hipLaunchKernelGGL(proj_kv_kernel, dim3(272), dim3(256), 0, stream, x, Wk, Wv, bt, KH, KL, VH, VL);
  hipLaunchKernelGGL(statsA_kernel,  dim3(512), dim3(256), 0, stream, QH, QL, KH, KL, rsum, ebins);
  hipLaunchKernelGGL(scoreB_kernel,  dim3(512), dim3(256), 0, stream, QH, QL, KH, KL, rsum, score);
  hipLaunchKernelGGL(bin_kernel,     dim3(16),  dim3(256), 0, stream, score, ebins, binof, kbins);
  hipLaunchKernelGGL(topk_kernel,    dim3(64),  dim3(256), 0, stream, score, binof, kbins, flags);
  hipLaunchKernelGGL(scan_kernel,    dim3(16),  dim3(256), 0, stream, flags, idxl, outIdx);
  hipLaunchKernelGGL(outC_kernel,    dim3(256), dim3(256), 0, stream, QH, QL, KH, KL, VH, VL, rsum, idxl, out0);
}

// Round 5
// 499.856 us; speedup vs baseline: 3.5809x; 1.1085x over previous
//
#include <hip/hip_runtime.h>

#define BB 16
#define CC 128
#define NN 2048
#define MM2 2052
#define VST 2056   // padded V row stride (16B-aligned rows)
#define MM 1024

constexpr float RSQRT_C = 0.08838834764831845f; // 1/sqrt(128)

typedef unsigned short u16;
typedef __attribute__((ext_vector_type(8))) short bf16x8;
typedef __attribute__((ext_vector_type(4))) float f32x4;

__device__ inline u16 f2b_rn(float f) {
  unsigned u = __float_as_uint(f);
  unsigned r = u + 0x7fffu + ((u >> 16) & 1u);
  return (u16)(r >> 16);
}
__device__ inline float b2f(u16 h) { return __uint_as_float(((unsigned)h) << 16); }

__device__ inline void store8(u16* dst, const u16 h[8]) {
  uint4 v;
  v.x = (unsigned)h[0] | ((unsigned)h[1] << 16);
  v.y = (unsigned)h[2] | ((unsigned)h[3] << 16);
  v.z = (unsigned)h[4] | ((unsigned)h[5] << 16);
  v.w = (unsigned)h[6] | ((unsigned)h[7] << 16);
  *(uint4*)dst = v;
}

// ---- workspace layout (byte offsets) ----
constexpr size_t SZ_Q  = (size_t)BB*NN*CC*2;
constexpr size_t SZ_K  = (size_t)BB*MM2*CC*2;
constexpr size_t SZ_V  = (size_t)BB*CC*VST*2;
constexpr size_t oQH = 0;
constexpr size_t oQL = oQH + SZ_Q;
constexpr size_t oKH = oQL + SZ_Q;
constexpr size_t oKL = oKH + SZ_K;
constexpr size_t oVH = oKL + SZ_K;
constexpr size_t oVL = oVH + SZ_V;
constexpr size_t oRS0 = oVL + SZ_V;                    // BB*NN f32 (kt half 0)
constexpr size_t oRS1 = oRS0 + (size_t)BB*NN*4;        // BB*NN f32 (kt half 1)
constexpr size_t oEB  = oRS1 + (size_t)BB*NN*4;        // BB*NN*4 f32
constexpr size_t oSC0 = oEB  + (size_t)BB*NN*16;       // BB*NN f32 (nt half 0)
constexpr size_t oSC1 = oSC0 + (size_t)BB*NN*4;        // BB*NN f32 (nt half 1)
constexpr size_t oSCORE = oSC1 + (size_t)BB*NN*4;      // BB*NN f32 merged
constexpr size_t oBIN = oSCORE + (size_t)BB*NN*4;      // int
constexpr size_t oKB  = oBIN + (size_t)BB*NN*4;        // BB*4 int
constexpr size_t oFL  = oKB  + 256;                    // BB*NN int
constexpr size_t oIDX = oFL  + (size_t)BB*NN*4;        // BB*MM int

// ---------------------------------------------------------------
// proj_q: Q[b][n][c] = (Wq x)/sqrt(C), emitted as bf16 hi/lo
// ---------------------------------------------------------------
__global__ __launch_bounds__(256) void proj_q_kernel(
    const float* __restrict__ x, const float* __restrict__ Wq,
    u16* __restrict__ QH, u16* __restrict__ QL)
{
  __shared__ float xs[128][132];
  __shared__ float ws[128][132];
  const int t  = threadIdx.x;
  const int b  = blockIdx.x >> 4;
  const int n0 = (blockIdx.x & 15) * 128;

  for (int i = t; i < 128*128; i += 256) {
    int c = i >> 7, n = i & 127;
    xs[c][n] = x[((size_t)(b*CC)+c)*NN + n0 + n];
  }
  for (int i = t; i < 128*128; i += 256) {
    int o = i >> 7, c = i & 127;
    ws[c][o] = Wq[o*CC + c];
  }
  __syncthreads();

  const int tn = (t & 15) * 8;
  const int to = (t >> 4) * 8;
  float acc[8][8];
  #pragma unroll
  for (int i=0;i<8;i++) {
    #pragma unroll
    for (int j=0;j<8;j++) acc[i][j]=0.f;
  }
  for (int c = 0; c < 128; ++c) {
    float xv[8], wv[8];
    #pragma unroll
    for (int i=0;i<8;i++) xv[i] = xs[c][tn+i];
    #pragma unroll
    for (int j=0;j<8;j++) wv[j] = ws[c][to+j];
    #pragma unroll
    for (int i=0;i<8;i++) {
      #pragma unroll
      for (int j=0;j<8;j++) acc[i][j] = fmaf(xv[i], wv[j], acc[i][j]);
    }
  }
  for (int i=0;i<8;i++) {
    u16 hs[8], ls[8];
    #pragma unroll
    for (int j=0;j<8;j++) {
      float v = acc[i][j] * RSQRT_C;
      u16 hb = f2b_rn(v);
      hs[j] = hb; ls[j] = f2b_rn(v - b2f(hb));
    }
    size_t idx = ((size_t)b*NN + n0+tn+i)*CC + to;
    store8(QH + idx, hs); store8(QL + idx, ls);
  }
}

// ---------------------------------------------------------------
// proj_kv: K[b][m][c] hi/lo, V[b][c][m] hi/lo (V rows padded to 2056)
// ---------------------------------------------------------------
__global__ __launch_bounds__(256) void proj_kv_kernel(
    const float* __restrict__ x, const float* __restrict__ Wk, const float* __restrict__ Wv,
    const float* __restrict__ bt,
    u16* __restrict__ KH, u16* __restrict__ KL, u16* __restrict__ VH, u16* __restrict__ VL)
{
  __shared__ float xs[128][132];
  __shared__ float ws[128][132];
  const int t  = threadIdx.x;
  const int b  = blockIdx.x & 15;
  const int m0 = (blockIdx.x >> 4) * 128;

  for (int i = t; i < 128*128; i += 256) {
    int c = i >> 7, m = i & 127; int gm = m0 + m;
    float v = 0.f;
    if (gm < NN) v = x[((size_t)(b*CC)+c)*NN + gm];
    else if (gm < MM2) v = bt[c*4 + (gm - NN)];
    xs[c][m] = v;
  }
  const int tm = (t & 15) * 8;
  const int to = (t >> 4) * 8;

  for (int pass = 0; pass < 2; ++pass) {
    const float* W = pass ? Wv : Wk;
    __syncthreads();
    for (int i = t; i < 128*128; i += 256) {
      int o = i >> 7, c = i & 127;
      ws[c][o] = W[o*CC + c];
    }
    __syncthreads();
    float acc[8][8];
    #pragma unroll
    for (int i=0;i<8;i++) {
      #pragma unroll
      for (int j=0;j<8;j++) acc[i][j]=0.f;
    }
    for (int c = 0; c < 128; ++c) {
      float xv[8], wv[8];
      #pragma unroll
      for (int i=0;i<8;i++) xv[i] = xs[c][tm+i];
      #pragma unroll
      for (int j=0;j<8;j++) wv[j] = ws[c][to+j];
      #pragma unroll
      for (int i=0;i<8;i++) {
        #pragma unroll
        for (int j=0;j<8;j++) acc[i][j] = fmaf(xv[i], wv[j], acc[i][j]);
      }
    }
    if (pass == 0) {
      for (int i=0;i<8;i++) {
        int gm = m0 + tm + i;
        if (gm >= MM2) continue;
        u16 hs[8], ls[8];
        #pragma unroll
        for (int j=0;j<8;j++) {
          float v = acc[i][j];
          u16 hb = f2b_rn(v);
          hs[j] = hb; ls[j] = f2b_rn(v - b2f(hb));
        }
        size_t idx = ((size_t)b*MM2 + gm)*CC + to;
        store8(KH + idx, hs); store8(KL + idx, ls);
      }
    } else {
      if (m0 + tm + 8 <= VST) {
        for (int j=0;j<8;j++) {
          int c = to + j;
          u16 hs[8], ls[8];
          #pragma unroll
          for (int i=0;i<8;i++) {
            int gm = m0 + tm + i;
            float v = (gm < MM2) ? acc[i][j] : 0.f;
            u16 hb = f2b_rn(v);
            hs[i] = hb; ls[i] = f2b_rn(v - b2f(hb));
          }
          size_t idx = ((size_t)b*CC + c)*VST + m0 + tm;
          store8(VH + idx, hs); store8(VL + idx, ls);
        }
      }
    }
  }
}

// ---------------------------------------------------------------
// Pass A: partial rowsum of exp(e) + bin energies; kt-range split
// across 2 halves (grid = 1024). Half h writes rsumP + h*BB*NN.
// ---------------------------------------------------------------
__global__ __launch_bounds__(256) void statsA_kernel(
    const u16* __restrict__ QH, const u16* __restrict__ QL,
    const u16* __restrict__ KH, const u16* __restrict__ KL,
    float* __restrict__ rsumP, float* __restrict__ ebins)
{
  __shared__ u16 kh[64*128], kl[64*128];
  const int t = threadIdx.x;
  const int half = blockIdx.x & 1;
  const int rest = blockIdx.x >> 1;
  const int b = rest >> 5;
  const int n0 = (rest & 31) * 64;
  const int wv = t >> 6, lane = t & 63;
  const int l15 = lane & 15, lhi = lane >> 4;
  const int nw = n0 + wv*16;
  const int ktBeg = half ? 17 : 0;
  const int ktEnd = half ? 33 : 17;

  bf16x8 qh[4], ql[4];
  {
    const size_t rb = ((size_t)b*NN + nw + l15)*CC + lhi*8;
    #pragma unroll
    for (int it=0; it<4; ++it) {
      qh[it] = *(const bf16x8*)(QH + rb + it*32);
      ql[it] = *(const bf16x8*)(QL + rb + it*32);
    }
  }
  float runsum[4] = {0.f, 0.f, 0.f, 0.f};

  for (int kt = ktBeg; kt < ktEnd; ++kt) {
    const int m0 = kt*64;
    __syncthreads();
    {
      const int row0 = t >> 4, chunk = t & 15;
      #pragma unroll
      for (int ii=0; ii<4; ++ii) {
        int r = row0 + ii*16; int gm = m0 + r;
        int dst = r*256 + ((chunk*16) ^ ((r&7)<<4));
        uint4 vh = make_uint4(0,0,0,0), vl = make_uint4(0,0,0,0);
        if (gm < MM2) {
          size_t g = ((size_t)b*MM2 + gm)*CC + chunk*8;
          vh = *(const uint4*)(KH + g);
          vl = *(const uint4*)(KL + g);
        }
        *(uint4*)((char*)kh + dst) = vh;
        *(uint4*)((char*)kl + dst) = vl;
      }
    }
    __syncthreads();
    const int mcEnd = (kt == 32) ? 1 : 4;
    for (int mc = 0; mc < mcEnd; ++mc) {
      f32x4 acc = {0.f,0.f,0.f,0.f};
      const int mrow = mc*16 + l15;
      #pragma unroll
      for (int it=0; it<4; ++it) {
        int byt = mrow*256 + ((it*64 + lhi*16) ^ ((mrow&7)<<4));
        bf16x8 bh = *(const bf16x8*)((const char*)kh + byt);
        bf16x8 bl = *(const bf16x8*)((const char*)kl + byt);
        acc = __builtin_amdgcn_mfma_f32_16x16x32_bf16(qh[it], bh, acc, 0,0,0);
        acc = __builtin_amdgcn_mfma_f32_16x16x32_bf16(qh[it], bl, acc, 0,0,0);
        acc = __builtin_amdgcn_mfma_f32_16x16x32_bf16(ql[it], bh, acc, 0,0,0);
      }
      const int m = m0 + mrow;
      if (kt == 32 && l15 < 4) {
        #pragma unroll
        for (int r=0;r<4;++r)
          ebins[((size_t)b*NN + nw + lhi*4 + r)*4 + l15] = acc[r];
      }
      const bool valid = (m < MM2);
      #pragma unroll
      for (int r=0;r<4;++r)
        runsum[r] += valid ? __expf(acc[r]) : 0.f;
    }
  }
  #pragma unroll
  for (int r=0;r<4;++r) {
    runsum[r] += __shfl_xor(runsum[r], 1);
    runsum[r] += __shfl_xor(runsum[r], 2);
    runsum[r] += __shfl_xor(runsum[r], 4);
    runsum[r] += __shfl_xor(runsum[r], 8);
  }
  if (l15 == 0) {
    float* rs = rsumP + (size_t)half*BB*NN;
    #pragma unroll
    for (int r=0;r<4;++r)
      rs[(size_t)b*NN + nw + lhi*4 + r] = runsum[r];
  }
}

// ---------------------------------------------------------------
// Pass B: partial score over an nt half-range (grid = 1024).
// sirs merged deterministically from the two rowsum partials.
// ---------------------------------------------------------------
__global__ __launch_bounds__(256) void scoreB_kernel(
    const u16* __restrict__ QH, const u16* __restrict__ QL,
    const u16* __restrict__ KH, const u16* __restrict__ KL,
    const float* __restrict__ rsumP, float* __restrict__ scoreP)
{
  __shared__ u16 qsh[64*128], qsl[64*128];
  __shared__ float sirs[64];
  const int t = threadIdx.x;
  const int half = blockIdx.x & 1;
  const int rest = blockIdx.x >> 1;
  const int b = rest >> 5;
  const int m0 = (rest & 31) * 64;
  const int wv = t >> 6, lane = t & 63;
  const int l15 = lane & 15, lhi = lane >> 4;
  const int mcol = m0 + wv*16 + l15;
  const int ntBeg = half ? 16 : 0;
  const int ntEnd = half ? 32 : 16;

  bf16x8 kbh[4], kbl[4];
  {
    const size_t rb = ((size_t)b*MM2 + mcol)*CC + lhi*8;
    #pragma unroll
    for (int it=0; it<4; ++it) {
      kbh[it] = *(const bf16x8*)(KH + rb + it*32);
      kbl[it] = *(const bf16x8*)(KL + rb + it*32);
    }
  }
  float sacc = 0.f;

  for (int nt = ntBeg; nt < ntEnd; ++nt) {
    const int n0 = nt*64;
    __syncthreads();
    {
      const int row0 = t >> 4, chunk = t & 15;
      #pragma unroll
      for (int ii=0; ii<4; ++ii) {
        int r = row0 + ii*16;
        int dst = r*256 + ((chunk*16) ^ ((r&7)<<4));
        size_t g = ((size_t)b*NN + n0 + r)*CC + chunk*8;
        *(uint4*)((char*)qsh + dst) = *(const uint4*)(QH + g);
        *(uint4*)((char*)qsl + dst) = *(const uint4*)(QL + g);
      }
      if (t < 64) {
        size_t ri = (size_t)b*NN + n0 + t;
        sirs[t] = 1.0f / (rsumP[ri] + rsumP[(size_t)BB*NN + ri]);
      }
    }
    __syncthreads();
    for (int sub = 0; sub < 4; ++sub) {
      f32x4 acc = {0.f,0.f,0.f,0.f};
      const int arow = sub*16 + l15;
      #pragma unroll
      for (int it=0; it<4; ++it) {
        int byt = arow*256 + ((it*64 + lhi*16) ^ ((arow&7)<<4));
        bf16x8 ah = *(const bf16x8*)((const char*)qsh + byt);
        bf16x8 al = *(const bf16x8*)((const char*)qsl + byt);
        acc = __builtin_amdgcn_mfma_f32_16x16x32_bf16(ah, kbh[it], acc, 0,0,0);
        acc = __builtin_amdgcn_mfma_f32_16x16x32_bf16(ah, kbl[it], acc, 0,0,0);
        acc = __builtin_amdgcn_mfma_f32_16x16x32_bf16(al, kbh[it], acc, 0,0,0);
      }
      #pragma unroll
      for (int r=0;r<4;++r) {
        int nl = sub*16 + lhi*4 + r;
        sacc += __expf(acc[r]) * sirs[nl];
      }
    }
  }
  sacc += __shfl_xor(sacc, 16);
  sacc += __shfl_xor(sacc, 32);
  if (lhi == 0) scoreP[(size_t)half*BB*NN + (size_t)b*NN + mcol] = sacc;
}

// ---------------------------------------------------------------
// K3a: merge score halves, bin assignment + budget allocation
// ---------------------------------------------------------------
__global__ __launch_bounds__(256) void bin_kernel(
    const float* __restrict__ scoreP, const float* __restrict__ ebins,
    float* __restrict__ score, int* __restrict__ binof, int* __restrict__ kbins)
{
  const int b = blockIdx.x, t = threadIdx.x;
  float wsm[4] = {0.f,0.f,0.f,0.f};
  int   cnt[4] = {0,0,0,0};
  for (int n = t; n < NN; n += 256) {
    size_t si = (size_t)b*NN + n;
    float s = scoreP[si] + scoreP[(size_t)BB*NN + si];
    score[si] = s;
    int j = (s >= 1.2f) ? 0 : (s >= 1.0f) ? 1 : (s >= 0.8f) ? 2 : 3;
    binof[si] = j;
    wsm[j] += ebins[si*4 + j];
    cnt[j] += 1;
  }
  #pragma unroll
  for (int j=0;j<4;j++){
    for (int off=1; off<64; off<<=1){
      wsm[j] += __shfl_xor(wsm[j], off);
      cnt[j] += __shfl_xor(cnt[j], off);
    }
  }
  __shared__ float wred[4][4];
  __shared__ int   cred[4][4];
  int wave = t >> 6, lane = t & 63;
  if (lane == 0) for (int j=0;j<4;j++){ wred[wave][j]=wsm[j]; cred[wave][j]=cnt[j]; }
  __syncthreads();
  if (t == 0) {
    float wsum[4]; int cs[4];
    for (int j=0;j<4;j++){
      wsum[j]=wred[0][j]+wred[1][j]+wred[2][j]+wred[3][j];
      cs[j]=cred[0][j]+cred[1][j]+cred[2][j]+cred[3][j];
    }
    float bw[4]; float sbw = 0.f;
    for (int j=0;j<4;j++){
      float wp = wsum[j] / ((float)cs[j] + 1e-8f);
      bw[j] = fmaxf(wp, 0.f); sbw += bw[j];
    }
    float den = fmaxf(sbw, 1e-8f);
    int k0[4]; int sk0 = 0;
    for (int j=0;j<4;j++){
      float p = bw[j] / den;
      int kk = (int)floorf(p * 1024.0f);
      if (kk > cs[j]) kk = cs[j];
      k0[j]=kk; sk0 += kk;
    }
    int deficit = 1024 - sk0;
    int cum = 0;
    for (int j=0;j<4;j++){
      int cap = cs[j] - k0[j];
      int ex = deficit - cum; if (ex < 0) ex = 0; if (ex > cap) ex = cap;
      kbins[b*4+j] = k0[j] + ex;
      cum += cap;
    }
  }
}

// ---------------------------------------------------------------
// K3b: per-(batch,bin) top-k by (score desc, index asc) -> flags
// ---------------------------------------------------------------
__global__ __launch_bounds__(256) void topk_kernel(
    const float* __restrict__ score, const int* __restrict__ binof,
    const int* __restrict__ kbins, int* __restrict__ flags)
{
  __shared__ unsigned long long arr[2048];
  const int t = threadIdx.x;
  const int b = blockIdx.x >> 2;
  const int j = blockIdx.x & 3;
  for (int n = t; n < NN; n += 256) {
    unsigned long long comp = 0ull;
    if (binof[(size_t)b*NN+n] == j) {
      unsigned int bits = __float_as_uint(score[(size_t)b*NN+n]);
      bits = (bits & 0x80000000u) ? ~bits : (bits | 0x80000000u);
      comp = ((unsigned long long)bits << 32) |
             (unsigned long long)(0xFFFFFFFFu - (unsigned)n);
    }
    arr[n] = ~comp;
  }
  __syncthreads();
  for (int ksz = 2; ksz <= 2048; ksz <<= 1) {
    for (int jsz = ksz >> 1; jsz > 0; jsz >>= 1) {
      for (int i = t; i < 2048; i += 256) {
        int ixj = i ^ jsz;
        if (ixj > i) {
          unsigned long long a = arr[i], bv = arr[ixj];
          bool up = ((i & ksz) == 0);
          if ((a > bv) == up) { arr[i] = bv; arr[ixj] = a; }
        }
      }
      __syncthreads();
    }
  }
  const int kb = kbins[b*4+j];
  for (int i = t; i < kb; i += 256) {
    unsigned long long comp = ~arr[i];
    int n = (int)(0xFFFFFFFFu - (unsigned)(comp & 0xFFFFFFFFull));
    flags[(size_t)b*NN + n] = 1;
  }
}

// ---------------------------------------------------------------
// K3c: prefix-scan of flags -> selected index list + index output
// ---------------------------------------------------------------
__global__ __launch_bounds__(256) void scan_kernel(
    const int* __restrict__ flags, int* __restrict__ idxl, float* __restrict__ outIdx)
{
  __shared__ int tsum[256];
  const int b = blockIdx.x, t = threadIdx.x;
  int f[8]; int c8 = 0;
  const int base = t * 8;
  #pragma unroll
  for (int i=0;i<8;i++){ f[i] = flags[(size_t)b*NN + base + i]; c8 += f[i]; }
  tsum[t] = c8;
  __syncthreads();
  for (int off=1; off<256; off<<=1) {
    int v = (t >= off) ? tsum[t-off] : 0;
    __syncthreads();
    tsum[t] += v;
    __syncthreads();
  }
  int pos = tsum[t] - c8;
  #pragma unroll
  for (int i=0;i<8;i++){
    if (f[i] && pos < MM) {
      idxl[(size_t)b*MM + pos] = base + i;
      outIdx[(size_t)b*MM + pos] = (float)(base + i);
      pos++;
    }
  }
}

// ---------------------------------------------------------------
// Pass C: selected rows -> e (bf16x3 MFMA), P, PV (MFMA); kt half-split
// (grid = 512); partial sums atomically added into zeroed out0.
// ---------------------------------------------------------------
__global__ __launch_bounds__(256) void outC_kernel(
    const u16* __restrict__ QH, const u16* __restrict__ QL,
    const u16* __restrict__ KH, const u16* __restrict__ KL,
    const u16* __restrict__ VH, const u16* __restrict__ VL,
    const float* __restrict__ rsumP,
    const int* __restrict__ idxl, float* __restrict__ out0)
{
  __shared__ u16 kh[64*128], kl[64*128];
  __shared__ u16 vsh[128*64], vsl[128*64];
  __shared__ u16 ph[4][16][72];
  __shared__ float sirs[64];
  __shared__ int rid[64];
  const int t = threadIdx.x;
  const int half = blockIdx.x & 1;
  const int rest = blockIdx.x >> 1;
  const int b = rest >> 4;
  const int s0 = (rest & 15) * 64;
  const int wv = t >> 6, lane = t & 63;
  const int l15 = lane & 15, lhi = lane >> 4;
  const int ktBeg = half ? 17 : 0;
  const int ktEnd = half ? 33 : 17;

  if (t < 64) {
    int n = idxl[(size_t)b*MM + s0 + t];
    rid[t] = n;
    size_t ri = (size_t)b*NN + n;
    sirs[t] = 1.0f / (rsumP[ri] + rsumP[(size_t)BB*NN + ri]);
  }
  __syncthreads();

  bf16x8 qh[4], ql[4];
  {
    int nq = rid[wv*16 + l15];
    const size_t rb = ((size_t)b*NN + nq)*CC + lhi*8;
    #pragma unroll
    for (int it=0; it<4; ++it) {
      qh[it] = *(const bf16x8*)(QH + rb + it*32);
      ql[it] = *(const bf16x8*)(QL + rb + it*32);
    }
  }
  f32x4 oacc[8];
  #pragma unroll
  for (int ct=0; ct<8; ++ct) oacc[ct] = (f32x4){0.f,0.f,0.f,0.f};

  for (int kt = ktBeg; kt < ktEnd; ++kt) {
    const int m0 = kt*64;
    __syncthreads();
    {
      const int row0 = t >> 4, chunk = t & 15;
      #pragma unroll
      for (int ii=0; ii<4; ++ii) {
        int r = row0 + ii*16; int gm = m0 + r;
        int dst = r*256 + ((chunk*16) ^ ((r&7)<<4));
        uint4 vh4 = make_uint4(0,0,0,0), vl4 = make_uint4(0,0,0,0);
        if (gm < MM2) {
          size_t g = ((size_t)b*MM2 + gm)*CC + chunk*8;
          vh4 = *(const uint4*)(KH + g);
          vl4 = *(const uint4*)(KL + g);
        }
        *(uint4*)((char*)kh + dst) = vh4;
        *(uint4*)((char*)kl + dst) = vl4;
      }
      const int c0 = t >> 3, mch = t & 7;
      #pragma unroll
      for (int ii=0; ii<4; ++ii) {
        int c = c0 + ii*32;
        int gm = m0 + mch*8;
        int dst = c*128 + ((mch*16) ^ ((c&7)<<4));
        uint4 vh4 = make_uint4(0,0,0,0), vl4 = make_uint4(0,0,0,0);
        if (gm < VST) {
          size_t g = ((size_t)b*CC + c)*VST + gm;
          vh4 = *(const uint4*)(VH + g);
          vl4 = *(const uint4*)(VL + g);
        }
        *(uint4*)((char*)vsh + dst) = vh4;
        *(uint4*)((char*)vsl + dst) = vl4;
      }
    }
    __syncthreads();

    for (int mc = 0; mc < 4; ++mc) {
      f32x4 acc = {0.f,0.f,0.f,0.f};
      const int mrow = mc*16 + l15;
      #pragma unroll
      for (int it=0; it<4; ++it) {
        int byt = mrow*256 + ((it*64 + lhi*16) ^ ((mrow&7)<<4));
        bf16x8 bh = *(const bf16x8*)((const char*)kh + byt);
        bf16x8 bl = *(const bf16x8*)((const char*)kl + byt);
        acc = __builtin_amdgcn_mfma_f32_16x16x32_bf16(qh[it], bh, acc, 0,0,0);
        acc = __builtin_amdgcn_mfma_f32_16x16x32_bf16(qh[it], bl, acc, 0,0,0);
        acc = __builtin_amdgcn_mfma_f32_16x16x32_bf16(ql[it], bh, acc, 0,0,0);
      }
      const int m = m0 + mrow;
      #pragma unroll
      for (int r=0;r<4;++r) {
        int rl = lhi*4 + r;
        float p = 0.f;
        if (m < MM2) p = __expf(acc[r]) * sirs[wv*16+rl];
        ph[wv][rl][mc*16 + l15] = f2b_rn(p);
      }
    }
    #pragma unroll
    for (int ki=0; ki<2; ++ki) {
      int pb = l15*144 + ki*64 + lhi*16;
      bf16x8 pa = *(const bf16x8*)((const char*)&ph[wv][0][0] + pb);
      #pragma unroll
      for (int ct=0; ct<8; ++ct) {
        int c = ct*16 + l15;
        int byt = c*128 + ((ki*64 + lhi*16) ^ ((c&7)<<4));
        bf16x8 vb = *(const bf16x8*)((const char*)vsh + byt);
        bf16x8 vbl = *(const bf16x8*)((const char*)vsl + byt);
        oacc[ct] = __builtin_amdgcn_mfma_f32_16x16x32_bf16(pa, vb, oacc[ct], 0,0,0);
        oacc[ct] = __builtin_amdgcn_mfma_f32_16x16x32_bf16(pa, vbl, oacc[ct], 0,0,0);
      }
    }
  }
  #pragma unroll
  for (int ct=0; ct<8; ++ct) {
    #pragma unroll
    for (int r=0;r<4;++r) {
      float* dst = &out0[((size_t)b*CC + ct*16 + l15)*MM + s0 + wv*16 + lhi*4 + r];
      __hip_atomic_fetch_add(dst, oacc[ct][r], __ATOMIC_RELAXED, __HIP_MEMORY_SCOPE_AGENT);
    }
  }
}

// ---------------------------------------------------------------
extern "C" void kernel_launch(void* const* d_in, const int* in_sizes, int n_in,
                              void* d_out, int out_size, void* d_ws, size_t ws_size,
                              hipStream_t stream) {
  const float* x  = (const float*)d_in[0];
  const float* Wq = (const float*)d_in[1];
  const float* Wk = (const float*)d_in[2];
  const float* Wv = (const float*)d_in[3];
  const float* bt = (const float*)d_in[4];
  float* out = (float*)d_out;
  char* ws = (char*)d_ws;

  u16* QH = (u16*)(ws + oQH);
  u16* QL = (u16*)(ws + oQL);
  u16* KH = (u16*)(ws + oKH);
  u16* KL = (u16*)(ws + oKL);
  u16* VH = (u16*)(ws + oVH);
  u16* VL = (u16*)(ws + oVL);
  float* rsumP = (float*)(ws + oRS0);   // 2 halves contiguous
  float* ebins = (float*)(ws + oEB);
  float* scoreP= (float*)(ws + oSC0);   // 2 halves contiguous
  float* score = (float*)(ws + oSCORE);
  int* binof = (int*)(ws + oBIN);
  int* kbins = (int*)(ws + oKB);
  int* flags = (int*)(ws + oFL);
  int* idxl  = (int*)(ws + oIDX);

  float* out0   = out;                        // (B,C,M)
  float* outIdx = out + (size_t)BB*CC*MM;     // (B,1,M) as float

  (void)hipMemsetAsync(flags, 0, (size_t)BB*NN*sizeof(int), stream);
  (void)hipMemsetAsync(out0, 0, (size_t)BB*CC*MM*sizeof(float), stream);

  hipLaunchKernelGGL(proj_q_kernel,  dim3(256),  dim3(256), 0, stream, x, Wq, QH, QL);
  hipLaunchKernelGGL(proj_kv_kernel, dim3(272),  dim3(256), 0, stream, x, Wk, Wv, bt, KH, KL, VH, VL);
  hipLaunchKernelGGL(statsA_kernel,  dim3(1024), dim3(256), 0, stream, QH, QL, KH, KL, rsumP, ebins);
  hipLaunchKernelGGL(scoreB_kernel,  dim3(1024), dim3(256), 0, stream, QH, QL, KH, KL, rsumP, scoreP);
  hipLaunchKernelGGL(bin_kernel,     dim3(16),   dim3(256), 0, stream, scoreP, ebins, score, binof, kbins);
  hipLaunchKernelGGL(topk_kernel,    dim3(64),   dim3(256), 0, stream, score, binof, kbins, flags);
  hipLaunchKernelGGL(scan_kernel,    dim3(16),   dim3(256), 0, stream, flags, idxl, outIdx);
  hipLaunchKernelGGL(outC_kernel,    dim3(512),  dim3(256), 0, stream, QH, QL, KH, KL, VH, VL, rsumP, idxl, out0);
}

// Round 6
// 428.590 us; speedup vs baseline: 4.1763x; 1.1663x over previous
//
#include <hip/hip_runtime.h>

#define BB 16
#define CC 128
#define NN 2048
#define MM2 2052
#define VST 2056   // padded V row stride
#define XTR 2056   // xt rows allocated per batch
#define MM 1024

constexpr float RSQRT_C = 0.08838834764831845f; // 1/sqrt(128)

typedef unsigned short u16;
typedef __attribute__((ext_vector_type(8))) short bf16x8;
typedef __attribute__((ext_vector_type(4))) float f32x4;

__device__ inline u16 f2b_rn(float f) {
  unsigned u = __float_as_uint(f);
  unsigned r = u + 0x7fffu + ((u >> 16) & 1u);
  return (u16)(r >> 16);
}
__device__ inline float b2f(u16 h) { return __uint_as_float(((unsigned)h) << 16); }

// ---- workspace layout (byte offsets) ----
constexpr size_t SZ_Q  = (size_t)BB*NN*CC*2;
constexpr size_t SZ_K  = (size_t)BB*MM2*CC*2;
constexpr size_t SZ_V  = (size_t)BB*CC*VST*2;
constexpr size_t oQH = 0;
constexpr size_t oQL = oQH + SZ_Q;
constexpr size_t oKH = oQL + SZ_Q;
constexpr size_t oKL = oKH + SZ_K;
constexpr size_t oVH = oKL + SZ_K;
constexpr size_t oVL = oVH + SZ_V;
constexpr size_t oRS0 = oVL + SZ_V;                    // 2*BB*NN f32 partial rowsums
constexpr size_t oEB  = oRS0 + (size_t)2*BB*NN*4;      // BB*NN*4 f32
constexpr size_t oSC0 = oEB  + (size_t)BB*NN*16;       // 2*BB*NN f32 partial scores
constexpr size_t oSCORE = oSC0 + (size_t)2*BB*NN*4;    // BB*NN f32 merged
constexpr size_t oBIN = oSCORE + (size_t)BB*NN*4;      // int
constexpr size_t oKB  = oBIN + (size_t)BB*NN*4;        // BB*4 int
constexpr size_t oFL  = oKB  + 256;                    // BB*NN int
constexpr size_t oIDX = oFL  + (size_t)BB*NN*4;        // BB*MM int
constexpr size_t oXH  = oIDX + (size_t)BB*MM*4;        // BB*XTR*CC u16
constexpr size_t oXL  = oXH  + (size_t)BB*XTR*CC*2;
constexpr size_t oWH  = oXL  + (size_t)BB*XTR*CC*2;    // 3*128*128 u16
constexpr size_t oWL  = oWH  + (size_t)3*CC*CC*2;

// ---------------------------------------------------------------
// splitX: xt[b][m][c] hi/lo bf16 from x (transpose) + bin-token rows
// ---------------------------------------------------------------
__global__ __launch_bounds__(256) void splitX_kernel(
    const float* __restrict__ x, const float* __restrict__ bt,
    u16* __restrict__ XH, u16* __restrict__ XL)
{
  const int t = threadIdx.x;
  const int b  = blockIdx.x / 33;
  const int nt = blockIdx.x % 33;
  if (nt == 32) {
    for (int i = t; i < 4*128; i += 256) {
      int j = i >> 7, c = i & 127;
      float v = bt[c*4 + j];
      u16 hb = f2b_rn(v);
      size_t oi = ((size_t)b*XTR + NN + j)*CC + c;
      XH[oi] = hb; XL[oi] = f2b_rn(v - b2f(hb));
    }
    return;
  }
  __shared__ float xs[128][65];
  const int n0 = nt*64;
  for (int i = t; i < 128*64; i += 256) {
    int c = i >> 6, n = i & 63;
    xs[c][n] = x[((size_t)b*CC + c)*NN + n0 + n];
  }
  __syncthreads();
  for (int i = t; i < 64*128; i += 256) {
    int m = i >> 7, c = i & 127;
    float v = xs[c][m];
    u16 hb = f2b_rn(v);
    size_t oi = ((size_t)b*XTR + n0 + m)*CC + c;
    XH[oi] = hb; XL[oi] = f2b_rn(v - b2f(hb));
  }
}

// ---------------------------------------------------------------
// splitW: W hi/lo bf16, packed [w][o][c], w in {q,k,v}
// ---------------------------------------------------------------
__global__ __launch_bounds__(256) void splitW_kernel(
    const float* __restrict__ Wq, const float* __restrict__ Wk, const float* __restrict__ Wv,
    u16* __restrict__ WH, u16* __restrict__ WL)
{
  int i = blockIdx.x*256 + threadIdx.x;   // grid 192 -> 49152 exact
  int w = i >> 14, rest = i & 16383;
  const float* W = (w == 0) ? Wq : (w == 1) ? Wk : Wv;
  float v = W[rest];
  u16 hb = f2b_rn(v);
  WH[i] = hb; WL[i] = f2b_rn(v - b2f(hb));
}

// ---------------------------------------------------------------
// projM: fused Q/K/V projection via bf16x3 MFMA.
// Q[b][n][o] (scaled), K[b][m][o], V[b][o][m] all hi/lo.
// ---------------------------------------------------------------
__global__ __launch_bounds__(256) void projM_kernel(
    const u16* __restrict__ XH, const u16* __restrict__ XL,
    const u16* __restrict__ WHs, const u16* __restrict__ WLs,
    u16* __restrict__ QH, u16* __restrict__ QL,
    u16* __restrict__ KH, u16* __restrict__ KL,
    u16* __restrict__ VH, u16* __restrict__ VL)
{
  __shared__ u16 xsh[64*128], xsl[64*128];
  const int t = threadIdx.x;
  const int b  = blockIdx.x / 33;
  const int mt = blockIdx.x % 33;
  const int m0 = mt*64;
  const int wv = t >> 6, lane = t & 63;
  const int l15 = lane & 15, lhi = lane >> 4;

  {
    const int row0 = t >> 4, chunk = t & 15;
    #pragma unroll
    for (int ii=0; ii<4; ++ii) {
      int r = row0 + ii*16; int gm = m0 + r;
      int dst = r*256 + ((chunk*16) ^ ((r&7)<<4));
      uint4 vh = make_uint4(0,0,0,0), vl = make_uint4(0,0,0,0);
      if (gm < MM2) {
        size_t g = ((size_t)b*XTR + gm)*CC + chunk*8;
        vh = *(const uint4*)(XH + g);
        vl = *(const uint4*)(XL + g);
      }
      *(uint4*)((char*)xsh + dst) = vh;
      *(uint4*)((char*)xsl + dst) = vl;
    }
  }
  __syncthreads();

  // q (w=0), k (w=1): A = x rows (m), B = W rows (o) -> D[m][o]
  for (int w = (m0 >= NN) ? 1 : 0; w < 2; ++w) {
    const u16* whp = WHs + (size_t)w*CC*CC;
    const u16* wlp = WLs + (size_t)w*CC*CC;
    u16* OH = w ? KH : QH;
    u16* OL = w ? KL : QL;
    const float scl = w ? 1.0f : RSQRT_C;
    const int mlim = w ? MM2 : NN;
    for (int osub = 0; osub < 2; ++osub) {
      const int ocol = wv*32 + osub*16;
      bf16x8 wbh[4], wbl[4];
      #pragma unroll
      for (int it=0; it<4; ++it) {
        size_t wi = (size_t)(ocol + l15)*CC + it*32 + lhi*8;
        wbh[it] = *(const bf16x8*)(whp + wi);
        wbl[it] = *(const bf16x8*)(wlp + wi);
      }
      for (int msub = 0; msub < 4; ++msub) {
        const int mrow = msub*16 + l15;
        f32x4 acc = {0.f,0.f,0.f,0.f};
        #pragma unroll
        for (int it=0; it<4; ++it) {
          int byt = mrow*256 + ((it*64 + lhi*16) ^ ((mrow&7)<<4));
          bf16x8 ah = *(const bf16x8*)((const char*)xsh + byt);
          bf16x8 al = *(const bf16x8*)((const char*)xsl + byt);
          acc = __builtin_amdgcn_mfma_f32_16x16x32_bf16(ah, wbh[it], acc, 0,0,0);
          acc = __builtin_amdgcn_mfma_f32_16x16x32_bf16(ah, wbl[it], acc, 0,0,0);
          acc = __builtin_amdgcn_mfma_f32_16x16x32_bf16(al, wbh[it], acc, 0,0,0);
        }
        #pragma unroll
        for (int r=0;r<4;++r) {
          int m = m0 + msub*16 + lhi*4 + r;
          if (m < mlim) {
            float vv = acc[r] * scl;
            u16 hb = f2b_rn(vv);
            size_t oi = w ? ((size_t)b*MM2 + m)*CC + ocol + l15
                          : ((size_t)b*NN  + m)*CC + ocol + l15;
            OH[oi] = hb;
            OL[oi] = f2b_rn(vv - b2f(hb));
          }
        }
      }
    }
  }

  // v: A = W rows (o), B = x rows (m) -> D[o][m]  (coalesced V[b][o][m])
  {
    const u16* whp = WHs + (size_t)2*CC*CC;
    const u16* wlp = WLs + (size_t)2*CC*CC;
    for (int osub = 0; osub < 2; ++osub) {
      const int ocol = wv*32 + osub*16;
      bf16x8 wbh[4], wbl[4];
      #pragma unroll
      for (int it=0; it<4; ++it) {
        size_t wi = (size_t)(ocol + l15)*CC + it*32 + lhi*8;
        wbh[it] = *(const bf16x8*)(whp + wi);
        wbl[it] = *(const bf16x8*)(wlp + wi);
      }
      for (int msub = 0; msub < 4; ++msub) {
        const int mrow = msub*16 + l15;
        f32x4 acc = {0.f,0.f,0.f,0.f};
        #pragma unroll
        for (int it=0; it<4; ++it) {
          int byt = mrow*256 + ((it*64 + lhi*16) ^ ((mrow&7)<<4));
          bf16x8 ah = *(const bf16x8*)((const char*)xsh + byt);
          bf16x8 al = *(const bf16x8*)((const char*)xsl + byt);
          acc = __builtin_amdgcn_mfma_f32_16x16x32_bf16(wbh[it], ah, acc, 0,0,0);
          acc = __builtin_amdgcn_mfma_f32_16x16x32_bf16(wbh[it], al, acc, 0,0,0);
          acc = __builtin_amdgcn_mfma_f32_16x16x32_bf16(wbl[it], ah, acc, 0,0,0);
        }
        #pragma unroll
        for (int r=0;r<4;++r) {
          int o = ocol + lhi*4 + r;
          int m = m0 + msub*16 + l15;
          if (m < VST) {
            float vv = acc[r];     // staging zeros rows >= MM2
            u16 hb = f2b_rn(vv);
            size_t oi = ((size_t)b*CC + o)*VST + m;
            VH[oi] = hb;
            VL[oi] = f2b_rn(vv - b2f(hb));
          }
        }
      }
    }
  }
}

// ---------------------------------------------------------------
// Pass A: partial rowsum of exp(e) + bin energies; kt half-split (grid 1024)
// ---------------------------------------------------------------
__global__ __launch_bounds__(256) void statsA_kernel(
    const u16* __restrict__ QH, const u16* __restrict__ QL,
    const u16* __restrict__ KH, const u16* __restrict__ KL,
    float* __restrict__ rsumP, float* __restrict__ ebins)
{
  __shared__ u16 kh[64*128], kl[64*128];
  const int t = threadIdx.x;
  const int half = blockIdx.x & 1;
  const int rest = blockIdx.x >> 1;
  const int b = rest >> 5;
  const int n0 = (rest & 31) * 64;
  const int wv = t >> 6, lane = t & 63;
  const int l15 = lane & 15, lhi = lane >> 4;
  const int nw = n0 + wv*16;
  const int ktBeg = half ? 17 : 0;
  const int ktEnd = half ? 33 : 17;

  bf16x8 qh[4], ql[4];
  {
    const size_t rb = ((size_t)b*NN + nw + l15)*CC + lhi*8;
    #pragma unroll
    for (int it=0; it<4; ++it) {
      qh[it] = *(const bf16x8*)(QH + rb + it*32);
      ql[it] = *(const bf16x8*)(QL + rb + it*32);
    }
  }
  float runsum[4] = {0.f, 0.f, 0.f, 0.f};

  for (int kt = ktBeg; kt < ktEnd; ++kt) {
    const int m0 = kt*64;
    __syncthreads();
    {
      const int row0 = t >> 4, chunk = t & 15;
      #pragma unroll
      for (int ii=0; ii<4; ++ii) {
        int r = row0 + ii*16; int gm = m0 + r;
        int dst = r*256 + ((chunk*16) ^ ((r&7)<<4));
        uint4 vh = make_uint4(0,0,0,0), vl = make_uint4(0,0,0,0);
        if (gm < MM2) {
          size_t g = ((size_t)b*MM2 + gm)*CC + chunk*8;
          vh = *(const uint4*)(KH + g);
          vl = *(const uint4*)(KL + g);
        }
        *(uint4*)((char*)kh + dst) = vh;
        *(uint4*)((char*)kl + dst) = vl;
      }
    }
    __syncthreads();
    const int mcEnd = (kt == 32) ? 1 : 4;
    for (int mc = 0; mc < mcEnd; ++mc) {
      f32x4 acc = {0.f,0.f,0.f,0.f};
      const int mrow = mc*16 + l15;
      #pragma unroll
      for (int it=0; it<4; ++it) {
        int byt = mrow*256 + ((it*64 + lhi*16) ^ ((mrow&7)<<4));
        bf16x8 bh = *(const bf16x8*)((const char*)kh + byt);
        bf16x8 bl = *(const bf16x8*)((const char*)kl + byt);
        acc = __builtin_amdgcn_mfma_f32_16x16x32_bf16(qh[it], bh, acc, 0,0,0);
        acc = __builtin_amdgcn_mfma_f32_16x16x32_bf16(qh[it], bl, acc, 0,0,0);
        acc = __builtin_amdgcn_mfma_f32_16x16x32_bf16(ql[it], bh, acc, 0,0,0);
      }
      const int m = m0 + mrow;
      if (kt == 32 && l15 < 4) {
        #pragma unroll
        for (int r=0;r<4;++r)
          ebins[((size_t)b*NN + nw + lhi*4 + r)*4 + l15] = acc[r];
      }
      const bool valid = (m < MM2);
      #pragma unroll
      for (int r=0;r<4;++r)
        runsum[r] += valid ? __expf(acc[r]) : 0.f;
    }
  }
  #pragma unroll
  for (int r=0;r<4;++r) {
    runsum[r] += __shfl_xor(runsum[r], 1);
    runsum[r] += __shfl_xor(runsum[r], 2);
    runsum[r] += __shfl_xor(runsum[r], 4);
    runsum[r] += __shfl_xor(runsum[r], 8);
  }
  if (l15 == 0) {
    float* rs = rsumP + (size_t)half*BB*NN;
    #pragma unroll
    for (int r=0;r<4;++r)
      rs[(size_t)b*NN + nw + lhi*4 + r] = runsum[r];
  }
}

// ---------------------------------------------------------------
// Pass B: partial score over an nt half-range (grid 1024)
// ---------------------------------------------------------------
__global__ __launch_bounds__(256) void scoreB_kernel(
    const u16* __restrict__ QH, const u16* __restrict__ QL,
    const u16* __restrict__ KH, const u16* __restrict__ KL,
    const float* __restrict__ rsumP, float* __restrict__ scoreP)
{
  __shared__ u16 qsh[64*128], qsl[64*128];
  __shared__ float sirs[64];
  const int t = threadIdx.x;
  const int half = blockIdx.x & 1;
  const int rest = blockIdx.x >> 1;
  const int b = rest >> 5;
  const int m0 = (rest & 31) * 64;
  const int wv = t >> 6, lane = t & 63;
  const int l15 = lane & 15, lhi = lane >> 4;
  const int mcol = m0 + wv*16 + l15;
  const int ntBeg = half ? 16 : 0;
  const int ntEnd = half ? 32 : 16;

  bf16x8 kbh[4], kbl[4];
  {
    const size_t rb = ((size_t)b*MM2 + mcol)*CC + lhi*8;
    #pragma unroll
    for (int it=0; it<4; ++it) {
      kbh[it] = *(const bf16x8*)(KH + rb + it*32);
      kbl[it] = *(const bf16x8*)(KL + rb + it*32);
    }
  }
  float sacc = 0.f;

  for (int nt = ntBeg; nt < ntEnd; ++nt) {
    const int n0 = nt*64;
    __syncthreads();
    {
      const int row0 = t >> 4, chunk = t & 15;
      #pragma unroll
      for (int ii=0; ii<4; ++ii) {
        int r = row0 + ii*16;
        int dst = r*256 + ((chunk*16) ^ ((r&7)<<4));
        size_t g = ((size_t)b*NN + n0 + r)*CC + chunk*8;
        *(uint4*)((char*)qsh + dst) = *(const uint4*)(QH + g);
        *(uint4*)((char*)qsl + dst) = *(const uint4*)(QL + g);
      }
      if (t < 64) {
        size_t ri = (size_t)b*NN + n0 + t;
        sirs[t] = 1.0f / (rsumP[ri] + rsumP[(size_t)BB*NN + ri]);
      }
    }
    __syncthreads();
    for (int sub = 0; sub < 4; ++sub) {
      f32x4 acc = {0.f,0.f,0.f,0.f};
      const int arow = sub*16 + l15;
      #pragma unroll
      for (int it=0; it<4; ++it) {
        int byt = arow*256 + ((it*64 + lhi*16) ^ ((arow&7)<<4));
        bf16x8 ah = *(const bf16x8*)((const char*)qsh + byt);
        bf16x8 al = *(const bf16x8*)((const char*)qsl + byt);
        acc = __builtin_amdgcn_mfma_f32_16x16x32_bf16(ah, kbh[it], acc, 0,0,0);
        acc = __builtin_amdgcn_mfma_f32_16x16x32_bf16(ah, kbl[it], acc, 0,0,0);
        acc = __builtin_amdgcn_mfma_f32_16x16x32_bf16(al, kbh[it], acc, 0,0,0);
      }
      #pragma unroll
      for (int r=0;r<4;++r) {
        int nl = sub*16 + lhi*4 + r;
        sacc += __expf(acc[r]) * sirs[nl];
      }
    }
  }
  sacc += __shfl_xor(sacc, 16);
  sacc += __shfl_xor(sacc, 32);
  if (lhi == 0) scoreP[(size_t)half*BB*NN + (size_t)b*NN + mcol] = sacc;
}

// ---------------------------------------------------------------
// bin: merge score halves, bin assignment + budget allocation
// ---------------------------------------------------------------
__global__ __launch_bounds__(256) void bin_kernel(
    const float* __restrict__ scoreP, const float* __restrict__ ebins,
    float* __restrict__ score, int* __restrict__ binof, int* __restrict__ kbins)
{
  const int b = blockIdx.x, t = threadIdx.x;
  float wsm[4] = {0.f,0.f,0.f,0.f};
  int   cnt[4] = {0,0,0,0};
  for (int n = t; n < NN; n += 256) {
    size_t si = (size_t)b*NN + n;
    float s = scoreP[si] + scoreP[(size_t)BB*NN + si];
    score[si] = s;
    int j = (s >= 1.2f) ? 0 : (s >= 1.0f) ? 1 : (s >= 0.8f) ? 2 : 3;
    binof[si] = j;
    wsm[j] += ebins[si*4 + j];
    cnt[j] += 1;
  }
  #pragma unroll
  for (int j=0;j<4;j++){
    for (int off=1; off<64; off<<=1){
      wsm[j] += __shfl_xor(wsm[j], off);
      cnt[j] += __shfl_xor(cnt[j], off);
    }
  }
  __shared__ float wred[4][4];
  __shared__ int   cred[4][4];
  int wave = t >> 6, lane = t & 63;
  if (lane == 0) for (int j=0;j<4;j++){ wred[wave][j]=wsm[j]; cred[wave][j]=cnt[j]; }
  __syncthreads();
  if (t == 0) {
    float wsum[4]; int cs[4];
    for (int j=0;j<4;j++){
      wsum[j]=wred[0][j]+wred[1][j]+wred[2][j]+wred[3][j];
      cs[j]=cred[0][j]+cred[1][j]+cred[2][j]+cred[3][j];
    }
    float bw[4]; float sbw = 0.f;
    for (int j=0;j<4;j++){
      float wp = wsum[j] / ((float)cs[j] + 1e-8f);
      bw[j] = fmaxf(wp, 0.f); sbw += bw[j];
    }
    float den = fmaxf(sbw, 1e-8f);
    int k0[4]; int sk0 = 0;
    for (int j=0;j<4;j++){
      float p = bw[j] / den;
      int kk = (int)floorf(p * 1024.0f);
      if (kk > cs[j]) kk = cs[j];
      k0[j]=kk; sk0 += kk;
    }
    int deficit = 1024 - sk0;
    int cum = 0;
    for (int j=0;j<4;j++){
      int cap = cs[j] - k0[j];
      int ex = deficit - cum; if (ex < 0) ex = 0; if (ex > cap) ex = cap;
      kbins[b*4+j] = k0[j] + ex;
      cum += cap;
    }
  }
}

// ---------------------------------------------------------------
// topk: per-(batch,bin) top-k by (score desc, index asc) -> flags
// ---------------------------------------------------------------
__global__ __launch_bounds__(256) void topk_kernel(
    const float* __restrict__ score, const int* __restrict__ binof,
    const int* __restrict__ kbins, int* __restrict__ flags)
{
  __shared__ unsigned long long arr[2048];
  const int t = threadIdx.x;
  const int b = blockIdx.x >> 2;
  const int j = blockIdx.x & 3;
  for (int n = t; n < NN; n += 256) {
    unsigned long long comp = 0ull;
    if (binof[(size_t)b*NN+n] == j) {
      unsigned int bits = __float_as_uint(score[(size_t)b*NN+n]);
      bits = (bits & 0x80000000u) ? ~bits : (bits | 0x80000000u);
      comp = ((unsigned long long)bits << 32) |
             (unsigned long long)(0xFFFFFFFFu - (unsigned)n);
    }
    arr[n] = ~comp;
  }
  __syncthreads();
  for (int ksz = 2; ksz <= 2048; ksz <<= 1) {
    for (int jsz = ksz >> 1; jsz > 0; jsz >>= 1) {
      for (int i = t; i < 2048; i += 256) {
        int ixj = i ^ jsz;
        if (ixj > i) {
          unsigned long long a = arr[i], bv = arr[ixj];
          bool up = ((i & ksz) == 0);
          if ((a > bv) == up) { arr[i] = bv; arr[ixj] = a; }
        }
      }
      __syncthreads();
    }
  }
  const int kb = kbins[b*4+j];
  for (int i = t; i < kb; i += 256) {
    unsigned long long comp = ~arr[i];
    int n = (int)(0xFFFFFFFFu - (unsigned)(comp & 0xFFFFFFFFull));
    flags[(size_t)b*NN + n] = 1;
  }
}

// ---------------------------------------------------------------
// scan: prefix-scan of flags -> selected index list + index output
// ---------------------------------------------------------------
__global__ __launch_bounds__(256) void scan_kernel(
    const int* __restrict__ flags, int* __restrict__ idxl, float* __restrict__ outIdx)
{
  __shared__ int tsum[256];
  const int b = blockIdx.x, t = threadIdx.x;
  int f[8]; int c8 = 0;
  const int base = t * 8;
  #pragma unroll
  for (int i=0;i<8;i++){ f[i] = flags[(size_t)b*NN + base + i]; c8 += f[i]; }
  tsum[t] = c8;
  __syncthreads();
  for (int off=1; off<256; off<<=1) {
    int v = (t >= off) ? tsum[t-off] : 0;
    __syncthreads();
    tsum[t] += v;
    __syncthreads();
  }
  int pos = tsum[t] - c8;
  #pragma unroll
  for (int i=0;i<8;i++){
    if (f[i] && pos < MM) {
      idxl[(size_t)b*MM + pos] = base + i;
      outIdx[(size_t)b*MM + pos] = (float)(base + i);
      pos++;
    }
  }
}

// ---------------------------------------------------------------
// Pass C (slim): e = (qh+ql)*kh, P bf16, PV = P*Vh; kt 3-way split
// (grid 768 = 3 blocks/CU at 42 KB LDS); atomic add into zeroed out0.
// ---------------------------------------------------------------
__global__ __launch_bounds__(256) void outC_kernel(
    const u16* __restrict__ QH, const u16* __restrict__ QL,
    const u16* __restrict__ KH,
    const u16* __restrict__ VH,
    const float* __restrict__ rsumP,
    const int* __restrict__ idxl, float* __restrict__ out0)
{
  __shared__ u16 kh[64*128];
  __shared__ u16 vsh[128*64];
  __shared__ u16 ph[4][16][72];
  __shared__ float sirs[64];
  __shared__ int rid[64];
  const int t = threadIdx.x;
  const int third = blockIdx.x % 3;
  const int rest = blockIdx.x / 3;
  const int b = rest >> 4;
  const int s0 = (rest & 15) * 64;
  const int wv = t >> 6, lane = t & 63;
  const int l15 = lane & 15, lhi = lane >> 4;
  const int ktBeg = third * 11;
  const int ktEnd = ktBeg + 11;

  if (t < 64) {
    int n = idxl[(size_t)b*MM + s0 + t];
    rid[t] = n;
    size_t ri = (size_t)b*NN + n;
    sirs[t] = 1.0f / (rsumP[ri] + rsumP[(size_t)BB*NN + ri]);
  }
  __syncthreads();

  bf16x8 qh[4], ql[4];
  {
    int nq = rid[wv*16 + l15];
    const size_t rb = ((size_t)b*NN + nq)*CC + lhi*8;
    #pragma unroll
    for (int it=0; it<4; ++it) {
      qh[it] = *(const bf16x8*)(QH + rb + it*32);
      ql[it] = *(const bf16x8*)(QL + rb + it*32);
    }
  }
  f32x4 oacc[8];
  #pragma unroll
  for (int ct=0; ct<8; ++ct) oacc[ct] = (f32x4){0.f,0.f,0.f,0.f};

  for (int kt = ktBeg; kt < ktEnd; ++kt) {
    const int m0 = kt*64;
    __syncthreads();
    {
      // stage K tile [64 m][128 c] (hi only)
      const int row0 = t >> 4, chunk = t & 15;
      #pragma unroll
      for (int ii=0; ii<4; ++ii) {
        int r = row0 + ii*16; int gm = m0 + r;
        int dst = r*256 + ((chunk*16) ^ ((r&7)<<4));
        uint4 vh4 = make_uint4(0,0,0,0);
        if (gm < MM2) {
          size_t g = ((size_t)b*MM2 + gm)*CC + chunk*8;
          vh4 = *(const uint4*)(KH + g);
        }
        *(uint4*)((char*)kh + dst) = vh4;
      }
      // stage V tile [128 c][64 m] (hi only)
      const int c0 = t >> 3, mch = t & 7;
      #pragma unroll
      for (int ii=0; ii<4; ++ii) {
        int c = c0 + ii*32;
        int gm = m0 + mch*8;
        int dst = c*128 + ((mch*16) ^ ((c&7)<<4));
        uint4 vh4 = make_uint4(0,0,0,0);
        if (gm < VST) {
          size_t g = ((size_t)b*CC + c)*VST + gm;
          vh4 = *(const uint4*)(VH + g);
        }
        *(uint4*)((char*)vsh + dst) = vh4;
      }
    }
    __syncthreads();

    for (int mc = 0; mc < 4; ++mc) {
      f32x4 acc = {0.f,0.f,0.f,0.f};
      const int mrow = mc*16 + l15;
      #pragma unroll
      for (int it=0; it<4; ++it) {
        int byt = mrow*256 + ((it*64 + lhi*16) ^ ((mrow&7)<<4));
        bf16x8 bh = *(const bf16x8*)((const char*)kh + byt);
        acc = __builtin_amdgcn_mfma_f32_16x16x32_bf16(qh[it], bh, acc, 0,0,0);
        acc = __builtin_amdgcn_mfma_f32_16x16x32_bf16(ql[it], bh, acc, 0,0,0);
      }
      const int m = m0 + mrow;
      #pragma unroll
      for (int r=0;r<4;++r) {
        int rl = lhi*4 + r;
        float p = 0.f;
        if (m < MM2) p = __expf(acc[r]) * sirs[wv*16+rl];
        ph[wv][rl][mc*16 + l15] = f2b_rn(p);
      }
    }
    #pragma unroll
    for (int ki=0; ki<2; ++ki) {
      int pb = l15*144 + ki*64 + lhi*16;
      bf16x8 pa = *(const bf16x8*)((const char*)&ph[wv][0][0] + pb);
      #pragma unroll
      for (int ct=0; ct<8; ++ct) {
        int c = ct*16 + l15;
        int byt = c*128 + ((ki*64 + lhi*16) ^ ((c&7)<<4));
        bf16x8 vb = *(const bf16x8*)((const char*)vsh + byt);
        oacc[ct] = __builtin_amdgcn_mfma_f32_16x16x32_bf16(pa, vb, oacc[ct], 0,0,0);
      }
    }
  }
  #pragma unroll
  for (int ct=0; ct<8; ++ct) {
    #pragma unroll
    for (int r=0;r<4;++r) {
      float* dst = &out0[((size_t)b*CC + ct*16 + l15)*MM + s0 + wv*16 + lhi*4 + r];
      __hip_atomic_fetch_add(dst, oacc[ct][r], __ATOMIC_RELAXED, __HIP_MEMORY_SCOPE_AGENT);
    }
  }
}

// ---------------------------------------------------------------
extern "C" void kernel_launch(void* const* d_in, const int* in_sizes, int n_in,
                              void* d_out, int out_size, void* d_ws, size_t ws_size,
                              hipStream_t stream) {
  const float* x  = (const float*)d_in[0];
  const float* Wq = (const float*)d_in[1];
  const float* Wk = (const float*)d_in[2];
  const float* Wv = (const float*)d_in[3];
  const float* bt = (const float*)d_in[4];
  float* out = (float*)d_out;
  char* ws = (char*)d_ws;

  u16* QH = (u16*)(ws + oQH);
  u16* QL = (u16*)(ws + oQL);
  u16* KH = (u16*)(ws + oKH);
  u16* KL = (u16*)(ws + oKL);
  u16* VH = (u16*)(ws + oVH);
  u16* VL = (u16*)(ws + oVL);
  float* rsumP = (float*)(ws + oRS0);
  float* ebins = (float*)(ws + oEB);
  float* scoreP= (float*)(ws + oSC0);
  float* score = (float*)(ws + oSCORE);
  int* binof = (int*)(ws + oBIN);
  int* kbins = (int*)(ws + oKB);
  int* flags = (int*)(ws + oFL);
  int* idxl  = (int*)(ws + oIDX);
  u16* XH = (u16*)(ws + oXH);
  u16* XL = (u16*)(ws + oXL);
  u16* WHs = (u16*)(ws + oWH);
  u16* WLs = (u16*)(ws + oWL);

  float* out0   = out;                        // (B,C,M)
  float* outIdx = out + (size_t)BB*CC*MM;     // (B,1,M) as float

  (void)hipMemsetAsync(flags, 0, (size_t)BB*NN*sizeof(int), stream);
  (void)hipMemsetAsync(out0, 0, (size_t)BB*CC*MM*sizeof(float), stream);

  hipLaunchKernelGGL(splitX_kernel,  dim3(528),  dim3(256), 0, stream, x, bt, XH, XL);
  hipLaunchKernelGGL(splitW_kernel,  dim3(192),  dim3(256), 0, stream, Wq, Wk, Wv, WHs, WLs);
  hipLaunchKernelGGL(projM_kernel,   dim3(528),  dim3(256), 0, stream, XH, XL, WHs, WLs, QH, QL, KH, KL, VH, VL);
  hipLaunchKernelGGL(statsA_kernel,  dim3(1024), dim3(256), 0, stream, QH, QL, KH, KL, rsumP, ebins);
  hipLaunchKernelGGL(scoreB_kernel,  dim3(1024), dim3(256), 0, stream, QH, QL, KH, KL, rsumP, scoreP);
  hipLaunchKernelGGL(bin_kernel,     dim3(16),   dim3(256), 0, stream, scoreP, ebins, score, binof, kbins);
  hipLaunchKernelGGL(topk_kernel,    dim3(64),   dim3(256), 0, stream, score, binof, kbins, flags);
  hipLaunchKernelGGL(scan_kernel,    dim3(16),   dim3(256), 0, stream, flags, idxl, outIdx);
  hipLaunchKernelGGL(outC_kernel,    dim3(768),  dim3(256), 0, stream, QH, QL, KH, VH, rsumP, idxl, out0);
}

// Round 7
// 383.692 us; speedup vs baseline: 4.6650x; 1.1170x over previous
//
#include <hip/hip_runtime.h>

#define BB 16
#define CC 128
#define NN 2048
#define MM2 2052
#define VST 2056   // padded V / P row stride (fp16, 16B-aligned rows)
#define XTR 2056
#define MM 1024

constexpr float RSQRT_C = 0.08838834764831845f; // 1/sqrt(128)

typedef unsigned short u16;
typedef __attribute__((ext_vector_type(8))) short bf16x8;
typedef __attribute__((ext_vector_type(8))) _Float16 f16x8;
typedef __attribute__((ext_vector_type(4))) float f32x4;

__device__ inline u16 f2b_rn(float f) {
  unsigned u = __float_as_uint(f);
  unsigned r = u + 0x7fffu + ((u >> 16) & 1u);
  return (u16)(r >> 16);
}
__device__ inline float b2f(u16 h) { return __uint_as_float(((unsigned)h) << 16); }
__device__ inline u16 f2h(float f) {
  union { _Float16 h; u16 u; } cv; cv.h = (_Float16)f; return cv.u;
}

// ---- workspace layout (byte offsets) ----
constexpr size_t SZ_Q  = (size_t)BB*NN*CC*2;
constexpr size_t SZ_K  = (size_t)BB*MM2*CC*2;
constexpr size_t SZ_V  = (size_t)BB*CC*VST*2;
constexpr size_t oQH = 0;
constexpr size_t oQL = oQH + SZ_Q;
constexpr size_t oKH = oQL + SZ_Q;
constexpr size_t oKL = oKH + SZ_K;
constexpr size_t oVF = oKL + SZ_K;                     // fp16 V
constexpr size_t oRS0 = oVF + SZ_V;                    // 2*BB*NN f32 partial rowsums
constexpr size_t oEB  = oRS0 + (size_t)2*BB*NN*4;      // BB*NN*4 f32
constexpr size_t oSC0 = oEB  + (size_t)BB*NN*16;       // 2*BB*NN f32 partial scores
constexpr size_t oSCORE = oSC0 + (size_t)2*BB*NN*4;    // BB*NN f32 merged
constexpr size_t oBIN = oSCORE + (size_t)BB*NN*4;      // int
constexpr size_t oKB  = oBIN + (size_t)BB*NN*4;        // BB*4 int
constexpr size_t oFL  = oKB  + 256;                    // BB*NN int
constexpr size_t oIDX = oFL  + (size_t)BB*NN*4;        // BB*MM int
constexpr size_t oXH  = oIDX + (size_t)BB*MM*4;        // BB*XTR*CC u16
constexpr size_t oXL  = oXH  + (size_t)BB*XTR*CC*2;
constexpr size_t oWH  = oXL  + (size_t)BB*XTR*CC*2;    // 3*128*128 u16
constexpr size_t oWL  = oWH  + (size_t)3*CC*CC*2;
// PU (fp16 normalized attention, [b][n][VST]) aliases X/W region: X,W dead
// by the time passP writes it (rewritten fresh every launch).
constexpr size_t oPU  = oXH;
constexpr size_t SZ_PU = (size_t)BB*NN*VST*2;
constexpr size_t oOP  = oPU + SZ_PU;                   // 3 partial outputs f32
constexpr size_t SZ_OP1 = (size_t)BB*CC*MM*4;

// ---------------------------------------------------------------
// splitX: xt[b][m][c] hi/lo bf16 from x (transpose) + bin-token rows
// ---------------------------------------------------------------
__global__ __launch_bounds__(256) void splitX_kernel(
    const float* __restrict__ x, const float* __restrict__ bt,
    u16* __restrict__ XH, u16* __restrict__ XL)
{
  const int t = threadIdx.x;
  const int b  = blockIdx.x / 33;
  const int nt = blockIdx.x % 33;
  if (nt == 32) {
    for (int i = t; i < 4*128; i += 256) {
      int j = i >> 7, c = i & 127;
      float v = bt[c*4 + j];
      u16 hb = f2b_rn(v);
      size_t oi = ((size_t)b*XTR + NN + j)*CC + c;
      XH[oi] = hb; XL[oi] = f2b_rn(v - b2f(hb));
    }
    return;
  }
  __shared__ float xs[128][65];
  const int n0 = nt*64;
  for (int i = t; i < 128*64; i += 256) {
    int c = i >> 6, n = i & 63;
    xs[c][n] = x[((size_t)b*CC + c)*NN + n0 + n];
  }
  __syncthreads();
  for (int i = t; i < 64*128; i += 256) {
    int m = i >> 7, c = i & 127;
    float v = xs[c][m];
    u16 hb = f2b_rn(v);
    size_t oi = ((size_t)b*XTR + n0 + m)*CC + c;
    XH[oi] = hb; XL[oi] = f2b_rn(v - b2f(hb));
  }
}

// ---------------------------------------------------------------
// splitW: W hi/lo bf16, packed [w][o][c], w in {q,k,v}
// ---------------------------------------------------------------
__global__ __launch_bounds__(256) void splitW_kernel(
    const float* __restrict__ Wq, const float* __restrict__ Wk, const float* __restrict__ Wv,
    u16* __restrict__ WH, u16* __restrict__ WL)
{
  int i = blockIdx.x*256 + threadIdx.x;
  int w = i >> 14, rest = i & 16383;
  const float* W = (w == 0) ? Wq : (w == 1) ? Wk : Wv;
  float v = W[rest];
  u16 hb = f2b_rn(v);
  WH[i] = hb; WL[i] = f2b_rn(v - b2f(hb));
}

// ---------------------------------------------------------------
// projM: fused Q/K/V projection via bf16x3 MFMA.
// Q[b][n][o] (scaled) hi/lo, K[b][m][o] hi/lo, V[b][o][m] fp16.
// ---------------------------------------------------------------
__global__ __launch_bounds__(256) void projM_kernel(
    const u16* __restrict__ XH, const u16* __restrict__ XL,
    const u16* __restrict__ WHs, const u16* __restrict__ WLs,
    u16* __restrict__ QH, u16* __restrict__ QL,
    u16* __restrict__ KH, u16* __restrict__ KL,
    u16* __restrict__ VF)
{
  __shared__ u16 xsh[64*128], xsl[64*128];
  const int t = threadIdx.x;
  const int b  = blockIdx.x / 33;
  const int mt = blockIdx.x % 33;
  const int m0 = mt*64;
  const int wv = t >> 6, lane = t & 63;
  const int l15 = lane & 15, lhi = lane >> 4;

  {
    const int row0 = t >> 4, chunk = t & 15;
    #pragma unroll
    for (int ii=0; ii<4; ++ii) {
      int r = row0 + ii*16; int gm = m0 + r;
      int dst = r*256 + ((chunk*16) ^ ((r&7)<<4));
      uint4 vh = make_uint4(0,0,0,0), vl = make_uint4(0,0,0,0);
      if (gm < MM2) {
        size_t g = ((size_t)b*XTR + gm)*CC + chunk*8;
        vh = *(const uint4*)(XH + g);
        vl = *(const uint4*)(XL + g);
      }
      *(uint4*)((char*)xsh + dst) = vh;
      *(uint4*)((char*)xsl + dst) = vl;
    }
  }
  __syncthreads();

  for (int w = (m0 >= NN) ? 1 : 0; w < 2; ++w) {
    const u16* whp = WHs + (size_t)w*CC*CC;
    const u16* wlp = WLs + (size_t)w*CC*CC;
    u16* OH = w ? KH : QH;
    u16* OL = w ? KL : QL;
    const float scl = w ? 1.0f : RSQRT_C;
    const int mlim = w ? MM2 : NN;
    for (int osub = 0; osub < 2; ++osub) {
      const int ocol = wv*32 + osub*16;
      bf16x8 wbh[4], wbl[4];
      #pragma unroll
      for (int it=0; it<4; ++it) {
        size_t wi = (size_t)(ocol + l15)*CC + it*32 + lhi*8;
        wbh[it] = *(const bf16x8*)(whp + wi);
        wbl[it] = *(const bf16x8*)(wlp + wi);
      }
      for (int msub = 0; msub < 4; ++msub) {
        const int mrow = msub*16 + l15;
        f32x4 acc = {0.f,0.f,0.f,0.f};
        #pragma unroll
        for (int it=0; it<4; ++it) {
          int byt = mrow*256 + ((it*64 + lhi*16) ^ ((mrow&7)<<4));
          bf16x8 ah = *(const bf16x8*)((const char*)xsh + byt);
          bf16x8 al = *(const bf16x8*)((const char*)xsl + byt);
          acc = __builtin_amdgcn_mfma_f32_16x16x32_bf16(ah, wbh[it], acc, 0,0,0);
          acc = __builtin_amdgcn_mfma_f32_16x16x32_bf16(ah, wbl[it], acc, 0,0,0);
          acc = __builtin_amdgcn_mfma_f32_16x16x32_bf16(al, wbh[it], acc, 0,0,0);
        }
        #pragma unroll
        for (int r=0;r<4;++r) {
          int m = m0 + msub*16 + lhi*4 + r;
          if (m < mlim) {
            float vv = acc[r] * scl;
            u16 hb = f2b_rn(vv);
            size_t oi = w ? ((size_t)b*MM2 + m)*CC + ocol + l15
                          : ((size_t)b*NN  + m)*CC + ocol + l15;
            OH[oi] = hb;
            OL[oi] = f2b_rn(vv - b2f(hb));
          }
        }
      }
    }
  }

  // v: A = W rows (o), B = x rows (m) -> D[o][m], fp16 out
  {
    const u16* whp = WHs + (size_t)2*CC*CC;
    const u16* wlp = WLs + (size_t)2*CC*CC;
    for (int osub = 0; osub < 2; ++osub) {
      const int ocol = wv*32 + osub*16;
      bf16x8 wbh[4], wbl[4];
      #pragma unroll
      for (int it=0; it<4; ++it) {
        size_t wi = (size_t)(ocol + l15)*CC + it*32 + lhi*8;
        wbh[it] = *(const bf16x8*)(whp + wi);
        wbl[it] = *(const bf16x8*)(wlp + wi);
      }
      for (int msub = 0; msub < 4; ++msub) {
        const int mrow = msub*16 + l15;
        f32x4 acc = {0.f,0.f,0.f,0.f};
        #pragma unroll
        for (int it=0; it<4; ++it) {
          int byt = mrow*256 + ((it*64 + lhi*16) ^ ((mrow&7)<<4));
          bf16x8 ah = *(const bf16x8*)((const char*)xsh + byt);
          bf16x8 al = *(const bf16x8*)((const char*)xsl + byt);
          acc = __builtin_amdgcn_mfma_f32_16x16x32_bf16(wbh[it], ah, acc, 0,0,0);
          acc = __builtin_amdgcn_mfma_f32_16x16x32_bf16(wbh[it], al, acc, 0,0,0);
          acc = __builtin_amdgcn_mfma_f32_16x16x32_bf16(wbl[it], ah, acc, 0,0,0);
        }
        #pragma unroll
        for (int r=0;r<4;++r) {
          int o = ocol + lhi*4 + r;
          int m = m0 + msub*16 + l15;
          if (m < VST)
            VF[((size_t)b*CC + o)*VST + m] = f2h(acc[r]);  // staging zeroed >=MM2
        }
      }
    }
  }
}

// ---------------------------------------------------------------
// Pass A: partial rowsum of exp(e) + bin energies; kt half-split (grid 1024)
// ---------------------------------------------------------------
__global__ __launch_bounds__(256) void statsA_kernel(
    const u16* __restrict__ QH, const u16* __restrict__ QL,
    const u16* __restrict__ KH, const u16* __restrict__ KL,
    float* __restrict__ rsumP, float* __restrict__ ebins)
{
  __shared__ u16 kh[64*128], kl[64*128];
  const int t = threadIdx.x;
  const int half = blockIdx.x & 1;
  const int rest = blockIdx.x >> 1;
  const int b = rest >> 5;
  const int n0 = (rest & 31) * 64;
  const int wv = t >> 6, lane = t & 63;
  const int l15 = lane & 15, lhi = lane >> 4;
  const int nw = n0 + wv*16;
  const int ktBeg = half ? 17 : 0;
  const int ktEnd = half ? 33 : 17;

  bf16x8 qh[4], ql[4];
  {
    const size_t rb = ((size_t)b*NN + nw + l15)*CC + lhi*8;
    #pragma unroll
    for (int it=0; it<4; ++it) {
      qh[it] = *(const bf16x8*)(QH + rb + it*32);
      ql[it] = *(const bf16x8*)(QL + rb + it*32);
    }
  }
  float runsum[4] = {0.f, 0.f, 0.f, 0.f};

  for (int kt = ktBeg; kt < ktEnd; ++kt) {
    const int m0 = kt*64;
    __syncthreads();
    {
      const int row0 = t >> 4, chunk = t & 15;
      #pragma unroll
      for (int ii=0; ii<4; ++ii) {
        int r = row0 + ii*16; int gm = m0 + r;
        int dst = r*256 + ((chunk*16) ^ ((r&7)<<4));
        uint4 vh = make_uint4(0,0,0,0), vl = make_uint4(0,0,0,0);
        if (gm < MM2) {
          size_t g = ((size_t)b*MM2 + gm)*CC + chunk*8;
          vh = *(const uint4*)(KH + g);
          vl = *(const uint4*)(KL + g);
        }
        *(uint4*)((char*)kh + dst) = vh;
        *(uint4*)((char*)kl + dst) = vl;
      }
    }
    __syncthreads();
    const int mcEnd = (kt == 32) ? 1 : 4;
    for (int mc = 0; mc < mcEnd; ++mc) {
      f32x4 acc = {0.f,0.f,0.f,0.f};
      const int mrow = mc*16 + l15;
      #pragma unroll
      for (int it=0; it<4; ++it) {
        int byt = mrow*256 + ((it*64 + lhi*16) ^ ((mrow&7)<<4));
        bf16x8 bh = *(const bf16x8*)((const char*)kh + byt);
        bf16x8 bl = *(const bf16x8*)((const char*)kl + byt);
        acc = __builtin_amdgcn_mfma_f32_16x16x32_bf16(qh[it], bh, acc, 0,0,0);
        acc = __builtin_amdgcn_mfma_f32_16x16x32_bf16(qh[it], bl, acc, 0,0,0);
        acc = __builtin_amdgcn_mfma_f32_16x16x32_bf16(ql[it], bh, acc, 0,0,0);
      }
      const int m = m0 + mrow;
      if (kt == 32 && l15 < 4) {
        #pragma unroll
        for (int r=0;r<4;++r)
          ebins[((size_t)b*NN + nw + lhi*4 + r)*4 + l15] = acc[r];
      }
      const bool valid = (m < MM2);
      #pragma unroll
      for (int r=0;r<4;++r)
        runsum[r] += valid ? __expf(acc[r]) : 0.f;
    }
  }
  #pragma unroll
  for (int r=0;r<4;++r) {
    runsum[r] += __shfl_xor(runsum[r], 1);
    runsum[r] += __shfl_xor(runsum[r], 2);
    runsum[r] += __shfl_xor(runsum[r], 4);
    runsum[r] += __shfl_xor(runsum[r], 8);
  }
  if (l15 == 0) {
    float* rs = rsumP + (size_t)half*BB*NN;
    #pragma unroll
    for (int r=0;r<4;++r)
      rs[(size_t)b*NN + nw + lhi*4 + r] = runsum[r];
  }
}

// ---------------------------------------------------------------
// passP: partial score + store normalized attention P (fp16) for all
// m<2052 (33 m-tiles incl. bin-col stub). n half-split: grid 1056.
// ---------------------------------------------------------------
__global__ __launch_bounds__(256) void passP_kernel(
    const u16* __restrict__ QH, const u16* __restrict__ QL,
    const u16* __restrict__ KH, const u16* __restrict__ KL,
    const float* __restrict__ rsumP, float* __restrict__ scoreP,
    u16* __restrict__ PU)
{
  __shared__ u16 qsh[64*128], qsl[64*128];
  __shared__ float sirs[64];
  const int t = threadIdx.x;
  const int half = blockIdx.x & 1;
  const int rest = blockIdx.x >> 1;
  const int b = rest / 33;
  const int mt = rest % 33;
  const int m0 = mt * 64;
  const int wv = t >> 6, lane = t & 63;
  const int l15 = lane & 15, lhi = lane >> 4;
  const int mcol = m0 + wv*16 + l15;
  const int ntBeg = half ? 16 : 0;
  const int ntEnd = half ? 32 : 16;

  bf16x8 kbh[4], kbl[4];
  {
    const int krow = (mcol < MM2) ? mcol : (MM2-1);
    const size_t rb = ((size_t)b*MM2 + krow)*CC + lhi*8;
    #pragma unroll
    for (int it=0; it<4; ++it) {
      kbh[it] = *(const bf16x8*)(KH + rb + it*32);
      kbl[it] = *(const bf16x8*)(KL + rb + it*32);
    }
  }
  float sacc = 0.f;

  for (int nt = ntBeg; nt < ntEnd; ++nt) {
    const int n0 = nt*64;
    __syncthreads();
    {
      const int row0 = t >> 4, chunk = t & 15;
      #pragma unroll
      for (int ii=0; ii<4; ++ii) {
        int r = row0 + ii*16;
        int dst = r*256 + ((chunk*16) ^ ((r&7)<<4));
        size_t g = ((size_t)b*NN + n0 + r)*CC + chunk*8;
        *(uint4*)((char*)qsh + dst) = *(const uint4*)(QH + g);
        *(uint4*)((char*)qsl + dst) = *(const uint4*)(QL + g);
      }
      if (t < 64) {
        size_t ri = (size_t)b*NN + n0 + t;
        sirs[t] = 1.0f / (rsumP[ri] + rsumP[(size_t)BB*NN + ri]);
      }
    }
    __syncthreads();
    for (int sub = 0; sub < 4; ++sub) {
      f32x4 acc = {0.f,0.f,0.f,0.f};
      const int arow = sub*16 + l15;
      #pragma unroll
      for (int it=0; it<4; ++it) {
        int byt = arow*256 + ((it*64 + lhi*16) ^ ((arow&7)<<4));
        bf16x8 ah = *(const bf16x8*)((const char*)qsh + byt);
        bf16x8 al = *(const bf16x8*)((const char*)qsl + byt);
        acc = __builtin_amdgcn_mfma_f32_16x16x32_bf16(ah, kbh[it], acc, 0,0,0);
        acc = __builtin_amdgcn_mfma_f32_16x16x32_bf16(ah, kbl[it], acc, 0,0,0);
        acc = __builtin_amdgcn_mfma_f32_16x16x32_bf16(al, kbh[it], acc, 0,0,0);
      }
      #pragma unroll
      for (int r=0;r<4;++r) {
        int nl = sub*16 + lhi*4 + r;
        float p = __expf(acc[r]) * sirs[nl];
        if (mcol < VST)
          PU[((size_t)b*NN + n0 + nl)*VST + mcol] = f2h((mcol < MM2) ? p : 0.f);
        sacc += p;
      }
    }
  }
  sacc += __shfl_xor(sacc, 16);
  sacc += __shfl_xor(sacc, 32);
  if (lhi == 0 && mcol < NN)
    scoreP[(size_t)half*BB*NN + (size_t)b*NN + mcol] = sacc;
}

// ---------------------------------------------------------------
// bin: merge score halves, bin assignment + budget allocation
// ---------------------------------------------------------------
__global__ __launch_bounds__(256) void bin_kernel(
    const float* __restrict__ scoreP, const float* __restrict__ ebins,
    float* __restrict__ score, int* __restrict__ binof, int* __restrict__ kbins)
{
  const int b = blockIdx.x, t = threadIdx.x;
  float wsm[4] = {0.f,0.f,0.f,0.f};
  int   cnt[4] = {0,0,0,0};
  for (int n = t; n < NN; n += 256) {
    size_t si = (size_t)b*NN + n;
    float s = scoreP[si] + scoreP[(size_t)BB*NN + si];
    score[si] = s;
    int j = (s >= 1.2f) ? 0 : (s >= 1.0f) ? 1 : (s >= 0.8f) ? 2 : 3;
    binof[si] = j;
    wsm[j] += ebins[si*4 + j];
    cnt[j] += 1;
  }
  #pragma unroll
  for (int j=0;j<4;j++){
    for (int off=1; off<64; off<<=1){
      wsm[j] += __shfl_xor(wsm[j], off);
      cnt[j] += __shfl_xor(cnt[j], off);
    }
  }
  __shared__ float wred[4][4];
  __shared__ int   cred[4][4];
  int wave = t >> 6, lane = t & 63;
  if (lane == 0) for (int j=0;j<4;j++){ wred[wave][j]=wsm[j]; cred[wave][j]=cnt[j]; }
  __syncthreads();
  if (t == 0) {
    float wsum[4]; int cs[4];
    for (int j=0;j<4;j++){
      wsum[j]=wred[0][j]+wred[1][j]+wred[2][j]+wred[3][j];
      cs[j]=cred[0][j]+cred[1][j]+cred[2][j]+cred[3][j];
    }
    float bw[4]; float sbw = 0.f;
    for (int j=0;j<4;j++){
      float wp = wsum[j] / ((float)cs[j] + 1e-8f);
      bw[j] = fmaxf(wp, 0.f); sbw += bw[j];
    }
    float den = fmaxf(sbw, 1e-8f);
    int k0[4]; int sk0 = 0;
    for (int j=0;j<4;j++){
      float p = bw[j] / den;
      int kk = (int)floorf(p * 1024.0f);
      if (kk > cs[j]) kk = cs[j];
      k0[j]=kk; sk0 += kk;
    }
    int deficit = 1024 - sk0;
    int cum = 0;
    for (int j=0;j<4;j++){
      int cap = cs[j] - k0[j];
      int ex = deficit - cum; if (ex < 0) ex = 0; if (ex > cap) ex = cap;
      kbins[b*4+j] = k0[j] + ex;
      cum += cap;
    }
  }
}

// ---------------------------------------------------------------
// topk: per-(batch,bin) top-k by (score desc, index asc) -> flags
// ---------------------------------------------------------------
__global__ __launch_bounds__(256) void topk_kernel(
    const float* __restrict__ score, const int* __restrict__ binof,
    const int* __restrict__ kbins, int* __restrict__ flags)
{
  __shared__ unsigned long long arr[2048];
  const int t = threadIdx.x;
  const int b = blockIdx.x >> 2;
  const int j = blockIdx.x & 3;
  for (int n = t; n < NN; n += 256) {
    unsigned long long comp = 0ull;
    if (binof[(size_t)b*NN+n] == j) {
      unsigned int bits = __float_as_uint(score[(size_t)b*NN+n]);
      bits = (bits & 0x80000000u) ? ~bits : (bits | 0x80000000u);
      comp = ((unsigned long long)bits << 32) |
             (unsigned long long)(0xFFFFFFFFu - (unsigned)n);
    }
    arr[n] = ~comp;
  }
  __syncthreads();
  for (int ksz = 2; ksz <= 2048; ksz <<= 1) {
    for (int jsz = ksz >> 1; jsz > 0; jsz >>= 1) {
      for (int i = t; i < 2048; i += 256) {
        int ixj = i ^ jsz;
        if (ixj > i) {
          unsigned long long a = arr[i], bv = arr[ixj];
          bool up = ((i & ksz) == 0);
          if ((a > bv) == up) { arr[i] = bv; arr[ixj] = a; }
        }
      }
      __syncthreads();
    }
  }
  const int kb = kbins[b*4+j];
  for (int i = t; i < kb; i += 256) {
    unsigned long long comp = ~arr[i];
    int n = (int)(0xFFFFFFFFu - (unsigned)(comp & 0xFFFFFFFFull));
    flags[(size_t)b*NN + n] = 1;
  }
}

// ---------------------------------------------------------------
// scan: prefix-scan of flags -> selected index list + index output
// ---------------------------------------------------------------
__global__ __launch_bounds__(256) void scan_kernel(
    const int* __restrict__ flags, int* __restrict__ idxl, float* __restrict__ outIdx)
{
  __shared__ int tsum[256];
  const int b = blockIdx.x, t = threadIdx.x;
  int f[8]; int c8 = 0;
  const int base = t * 8;
  #pragma unroll
  for (int i=0;i<8;i++){ f[i] = flags[(size_t)b*NN + base + i]; c8 += f[i]; }
  tsum[t] = c8;
  __syncthreads();
  for (int off=1; off<256; off<<=1) {
    int v = (t >= off) ? tsum[t-off] : 0;
    __syncthreads();
    tsum[t] += v;
    __syncthreads();
  }
  int pos = tsum[t] - c8;
  #pragma unroll
  for (int i=0;i<8;i++){
    if (f[i] && pos < MM) {
      idxl[(size_t)b*MM + pos] = base + i;
      outIdx[(size_t)b*MM + pos] = (float)(base + i);
      pos++;
    }
  }
}

// ---------------------------------------------------------------
// outC: pure PV. Gather selected P rows (fp16, pre-normalized), stage
// V tile, f16 MFMA. kt 3-way split into 3 partial buffers (grid 768).
// ---------------------------------------------------------------
__global__ __launch_bounds__(256) void outC_kernel(
    const u16* __restrict__ PU, const u16* __restrict__ VF,
    const int* __restrict__ idxl, float* __restrict__ oPart)
{
  __shared__ u16 psh[64*64];    // [selrow][m] fp16 (swizzled)
  __shared__ u16 vsh[128*64];   // [c][m] fp16 (swizzled)
  __shared__ int rid[64];
  const int t = threadIdx.x;
  const int third = blockIdx.x % 3;
  const int rest  = blockIdx.x / 3;
  const int b  = rest >> 4;
  const int s0 = (rest & 15) * 64;
  const int wv = t >> 6, lane = t & 63;
  const int l15 = lane & 15, lhi = lane >> 4;
  const int ktBeg = third * 11, ktEnd = ktBeg + 11;

  if (t < 64) rid[t] = idxl[(size_t)b*MM + s0 + t];

  f32x4 oacc[8];
  #pragma unroll
  for (int ct=0; ct<8; ++ct) oacc[ct] = (f32x4){0.f,0.f,0.f,0.f};

  for (int kt = ktBeg; kt < ktEnd; ++kt) {
    const int m0 = kt*64;
    __syncthreads();
    // stage P: 64 rows x 8 chunks (8 fp16 each)
    #pragma unroll
    for (int ii=0; ii<2; ++ii) {
      int item = t + 256*ii;
      int row = item >> 3, ch = item & 7;
      int gm = m0 + ch*8;
      uint4 v = make_uint4(0,0,0,0);
      if (gm < VST) v = *(const uint4*)(PU + ((size_t)b*NN + rid[row])*VST + gm);
      *(uint4*)((char*)psh + row*128 + ((ch*16) ^ ((row&7)<<4))) = v;
    }
    // stage V: 128 c x 8 chunks
    #pragma unroll
    for (int ii=0; ii<4; ++ii) {
      int item = t + 256*ii;
      int c = item >> 3, ch = item & 7;
      int gm = m0 + ch*8;
      uint4 v = make_uint4(0,0,0,0);
      if (gm < VST) v = *(const uint4*)(VF + ((size_t)b*CC + c)*VST + gm);
      *(uint4*)((char*)vsh + c*128 + ((ch*16) ^ ((c&7)<<4))) = v;
    }
    __syncthreads();
    #pragma unroll
    for (int ki=0; ki<2; ++ki) {
      const int prow = wv*16 + l15;
      f16x8 pa = *(const f16x8*)((const char*)psh + prow*128 + ((ki*64 + lhi*16) ^ ((prow&7)<<4)));
      #pragma unroll
      for (int ct=0; ct<8; ++ct) {
        int c = ct*16 + l15;
        f16x8 vb = *(const f16x8*)((const char*)vsh + c*128 + ((ki*64 + lhi*16) ^ ((c&7)<<4)));
        oacc[ct] = __builtin_amdgcn_mfma_f32_16x16x32_f16(pa, vb, oacc[ct], 0,0,0);
      }
    }
  }
  float* op = oPart + (size_t)third*BB*CC*MM;
  #pragma unroll
  for (int ct=0; ct<8; ++ct) {
    #pragma unroll
    for (int r=0;r<4;++r) {
      op[((size_t)b*CC + ct*16 + l15)*MM + s0 + wv*16 + lhi*4 + r] = oacc[ct][r];
    }
  }
}

// ---------------------------------------------------------------
// merge: out0 = sum of 3 partials (deterministic order)
// ---------------------------------------------------------------
__global__ __launch_bounds__(256) void merge_kernel(
    const float* __restrict__ oPart, float* __restrict__ out0)
{
  const size_t i = ((size_t)blockIdx.x*256 + threadIdx.x)*4;
  const float4 a = *(const float4*)(oPart + i);
  const float4 b = *(const float4*)(oPart + (size_t)BB*CC*MM + i);
  const float4 c = *(const float4*)(oPart + (size_t)2*BB*CC*MM + i);
  float4 o;
  o.x = a.x + b.x + c.x;
  o.y = a.y + b.y + c.y;
  o.z = a.z + b.z + c.z;
  o.w = a.w + b.w + c.w;
  *(float4*)(out0 + i) = o;
}

// ---------------------------------------------------------------
extern "C" void kernel_launch(void* const* d_in, const int* in_sizes, int n_in,
                              void* d_out, int out_size, void* d_ws, size_t ws_size,
                              hipStream_t stream) {
  const float* x  = (const float*)d_in[0];
  const float* Wq = (const float*)d_in[1];
  const float* Wk = (const float*)d_in[2];
  const float* Wv = (const float*)d_in[3];
  const float* bt = (const float*)d_in[4];
  float* out = (float*)d_out;
  char* ws = (char*)d_ws;

  u16* QH = (u16*)(ws + oQH);
  u16* QL = (u16*)(ws + oQL);
  u16* KH = (u16*)(ws + oKH);
  u16* KL = (u16*)(ws + oKL);
  u16* VF = (u16*)(ws + oVF);
  float* rsumP = (float*)(ws + oRS0);
  float* ebins = (float*)(ws + oEB);
  float* scoreP= (float*)(ws + oSC0);
  float* score = (float*)(ws + oSCORE);
  int* binof = (int*)(ws + oBIN);
  int* kbins = (int*)(ws + oKB);
  int* flags = (int*)(ws + oFL);
  int* idxl  = (int*)(ws + oIDX);
  u16* XH = (u16*)(ws + oXH);
  u16* XL = (u16*)(ws + oXL);
  u16* WHs = (u16*)(ws + oWH);
  u16* WLs = (u16*)(ws + oWL);
  u16* PU  = (u16*)(ws + oPU);     // aliases X/W (dead by then)
  float* oPart = (float*)(ws + oOP);

  float* out0   = out;                        // (B,C,M)
  float* outIdx = out + (size_t)BB*CC*MM;     // (B,1,M) as float

  (void)hipMemsetAsync(flags, 0, (size_t)BB*NN*sizeof(int), stream);

  hipLaunchKernelGGL(splitX_kernel,  dim3(528),  dim3(256), 0, stream, x, bt, XH, XL);
  hipLaunchKernelGGL(splitW_kernel,  dim3(192),  dim3(256), 0, stream, Wq, Wk, Wv, WHs, WLs);
  hipLaunchKernelGGL(projM_kernel,   dim3(528),  dim3(256), 0, stream, XH, XL, WHs, WLs, QH, QL, KH, KL, VF);
  hipLaunchKernelGGL(statsA_kernel,  dim3(1024), dim3(256), 0, stream, QH, QL, KH, KL, rsumP, ebins);
  hipLaunchKernelGGL(passP_kernel,   dim3(1056), dim3(256), 0, stream, QH, QL, KH, KL, rsumP, scoreP, PU);
  hipLaunchKernelGGL(bin_kernel,     dim3(16),   dim3(256), 0, stream, scoreP, ebins, score, binof, kbins);
  hipLaunchKernelGGL(topk_kernel,    dim3(64),   dim3(256), 0, stream, score, binof, kbins, flags);
  hipLaunchKernelGGL(scan_kernel,    dim3(16),   dim3(256), 0, stream, flags, idxl, outIdx);
  hipLaunchKernelGGL(outC_kernel,    dim3(768),  dim3(256), 0, stream, PU, VF, idxl, oPart);
  hipLaunchKernelGGL(merge_kernel,   dim3(2048), dim3(256), 0, stream, oPart, out0);
}

// Round 9
// 325.151 us; speedup vs baseline: 5.5049x; 1.1800x over previous
//
#include <hip/hip_runtime.h>

#define BB 16
#define CC 128
#define NN 2048
#define MM2 2052
#define VST 2056   // padded V / P row stride (fp16, 16B-aligned rows)
#define XTR 2056
#define MM 1024

constexpr float RSQRT_C = 0.08838834764831845f; // 1/sqrt(128)

typedef unsigned short u16;
typedef __attribute__((ext_vector_type(8))) short bf16x8;
typedef __attribute__((ext_vector_type(8))) _Float16 f16x8;
typedef __attribute__((ext_vector_type(4))) float f32x4;

__device__ inline u16 f2b_rn(float f) {
  unsigned u = __float_as_uint(f);
  unsigned r = u + 0x7fffu + ((u >> 16) & 1u);
  return (u16)(r >> 16);
}
__device__ inline float b2f(u16 h) { return __uint_as_float(((unsigned)h) << 16); }
__device__ inline u16 f2h(float f) {
  union { _Float16 h; u16 u; } cv; cv.h = (_Float16)f; return cv.u;
}

// ---- workspace layout (byte offsets) ----
constexpr size_t SZ_Q  = (size_t)BB*NN*CC*2;
constexpr size_t SZ_K  = (size_t)BB*MM2*CC*2;
constexpr size_t SZ_V  = (size_t)BB*CC*VST*2;
constexpr size_t oQH = 0;
constexpr size_t oQL = oQH + SZ_Q;
constexpr size_t oKH = oQL + SZ_Q;
constexpr size_t oKL = oKH + SZ_K;
constexpr size_t oVF = oKL + SZ_K;                     // fp16 V
constexpr size_t oRS0 = oVF + SZ_V;                    // 2*BB*NN f32 partial rowsums
constexpr size_t oEB  = oRS0 + (size_t)2*BB*NN*4;      // BB*NN*4 f32
constexpr size_t oSC0 = oEB  + (size_t)BB*NN*16;       // 8*BB*NN f32 partial scores
constexpr size_t oSCORE = oSC0 + (size_t)8*BB*NN*4;    // BB*NN f32 merged
constexpr size_t oBIN = oSCORE + (size_t)BB*NN*4;      // int
constexpr size_t oKB  = oBIN + (size_t)BB*NN*4;        // BB*4 int
constexpr size_t oFL  = oKB  + 256;                    // BB*NN int
constexpr size_t oIDX = oFL  + (size_t)BB*NN*4;        // BB*MM int
constexpr size_t oXH  = oIDX + (size_t)BB*MM*4;        // BB*XTR*CC u16
constexpr size_t oXL  = oXH  + (size_t)BB*XTR*CC*2;
constexpr size_t oWH  = oXL  + (size_t)BB*XTR*CC*2;    // 3*128*128 u16
constexpr size_t oWL  = oWH  + (size_t)3*CC*CC*2;
// PU (fp16 UNNORMALIZED exp(e), [b][n][VST]) aliases X/W region (dead by then).
constexpr size_t oPU  = oXH;
constexpr size_t SZ_PU = (size_t)BB*NN*VST*2;
constexpr size_t oOP  = oPU + SZ_PU;                   // 3 partial outputs f32

// ---------------------------------------------------------------
// splitX: xt[b][m][c] hi/lo bf16 from x (transpose) + bin-token rows
// ---------------------------------------------------------------
__global__ __launch_bounds__(256) void splitX_kernel(
    const float* __restrict__ x, const float* __restrict__ bt,
    u16* __restrict__ XH, u16* __restrict__ XL)
{
  const int t = threadIdx.x;
  const int b  = blockIdx.x / 33;
  const int nt = blockIdx.x % 33;
  if (nt == 32) {
    for (int i = t; i < 4*128; i += 256) {
      int j = i >> 7, c = i & 127;
      float v = bt[c*4 + j];
      u16 hb = f2b_rn(v);
      size_t oi = ((size_t)b*XTR + NN + j)*CC + c;
      XH[oi] = hb; XL[oi] = f2b_rn(v - b2f(hb));
    }
    return;
  }
  __shared__ float xs[128][65];
  const int n0 = nt*64;
  for (int i = t; i < 128*64; i += 256) {
    int c = i >> 6, n = i & 63;
    xs[c][n] = x[((size_t)b*CC + c)*NN + n0 + n];
  }
  __syncthreads();
  for (int i = t; i < 64*128; i += 256) {
    int m = i >> 7, c = i & 127;
    float v = xs[c][m];
    u16 hb = f2b_rn(v);
    size_t oi = ((size_t)b*XTR + n0 + m)*CC + c;
    XH[oi] = hb; XL[oi] = f2b_rn(v - b2f(hb));
  }
}

// ---------------------------------------------------------------
// splitW: W hi/lo bf16, packed [w][o][c], w in {q,k,v}
// ---------------------------------------------------------------
__global__ __launch_bounds__(256) void splitW_kernel(
    const float* __restrict__ Wq, const float* __restrict__ Wk, const float* __restrict__ Wv,
    u16* __restrict__ WH, u16* __restrict__ WL)
{
  int i = blockIdx.x*256 + threadIdx.x;
  int w = i >> 14, rest = i & 16383;
  const float* W = (w == 0) ? Wq : (w == 1) ? Wk : Wv;
  float v = W[rest];
  u16 hb = f2b_rn(v);
  WH[i] = hb; WL[i] = f2b_rn(v - b2f(hb));
}

// ---------------------------------------------------------------
// projM: fused Q/K/V projection via bf16x3 MFMA.
// Q[b][n][o] (scaled) hi/lo, K[b][m][o] hi/lo, V[b][o][m] fp16.
// ---------------------------------------------------------------
__global__ __launch_bounds__(256) void projM_kernel(
    const u16* __restrict__ XH, const u16* __restrict__ XL,
    const u16* __restrict__ WHs, const u16* __restrict__ WLs,
    u16* __restrict__ QH, u16* __restrict__ QL,
    u16* __restrict__ KH, u16* __restrict__ KL,
    u16* __restrict__ VF)
{
  __shared__ u16 xsh[64*128], xsl[64*128];
  const int t = threadIdx.x;
  const int b  = blockIdx.x / 33;
  const int mt = blockIdx.x % 33;
  const int m0 = mt*64;
  const int wv = t >> 6, lane = t & 63;
  const int l15 = lane & 15, lhi = lane >> 4;

  {
    const int row0 = t >> 4, chunk = t & 15;
    #pragma unroll
    for (int ii=0; ii<4; ++ii) {
      int r = row0 + ii*16; int gm = m0 + r;
      int dst = r*256 + ((chunk*16) ^ ((r&7)<<4));
      uint4 vh = make_uint4(0,0,0,0), vl = make_uint4(0,0,0,0);
      if (gm < MM2) {
        size_t g = ((size_t)b*XTR + gm)*CC + chunk*8;
        vh = *(const uint4*)(XH + g);
        vl = *(const uint4*)(XL + g);
      }
      *(uint4*)((char*)xsh + dst) = vh;
      *(uint4*)((char*)xsl + dst) = vl;
    }
  }
  __syncthreads();

  for (int w = (m0 >= NN) ? 1 : 0; w < 2; ++w) {
    const u16* whp = WHs + (size_t)w*CC*CC;
    const u16* wlp = WLs + (size_t)w*CC*CC;
    u16* OH = w ? KH : QH;
    u16* OL = w ? KL : QL;
    const float scl = w ? 1.0f : RSQRT_C;
    const int mlim = w ? MM2 : NN;
    for (int osub = 0; osub < 2; ++osub) {
      const int ocol = wv*32 + osub*16;
      bf16x8 wbh[4], wbl[4];
      #pragma unroll
      for (int it=0; it<4; ++it) {
        size_t wi = (size_t)(ocol + l15)*CC + it*32 + lhi*8;
        wbh[it] = *(const bf16x8*)(whp + wi);
        wbl[it] = *(const bf16x8*)(wlp + wi);
      }
      for (int msub = 0; msub < 4; ++msub) {
        const int mrow = msub*16 + l15;
        f32x4 acc = {0.f,0.f,0.f,0.f};
        #pragma unroll
        for (int it=0; it<4; ++it) {
          int byt = mrow*256 + ((it*64 + lhi*16) ^ ((mrow&7)<<4));
          bf16x8 ah = *(const bf16x8*)((const char*)xsh + byt);
          bf16x8 al = *(const bf16x8*)((const char*)xsl + byt);
          acc = __builtin_amdgcn_mfma_f32_16x16x32_bf16(ah, wbh[it], acc, 0,0,0);
          acc = __builtin_amdgcn_mfma_f32_16x16x32_bf16(ah, wbl[it], acc, 0,0,0);
          acc = __builtin_amdgcn_mfma_f32_16x16x32_bf16(al, wbh[it], acc, 0,0,0);
        }
        #pragma unroll
        for (int r=0;r<4;++r) {
          int m = m0 + msub*16 + lhi*4 + r;
          if (m < mlim) {
            float vv = acc[r] * scl;
            u16 hb = f2b_rn(vv);
            size_t oi = w ? ((size_t)b*MM2 + m)*CC + ocol + l15
                          : ((size_t)b*NN  + m)*CC + ocol + l15;
            OH[oi] = hb;
            OL[oi] = f2b_rn(vv - b2f(hb));
          }
        }
      }
    }
  }

  // v: A = W rows (o), B = x rows (m) -> D[o][m], fp16 out
  {
    const u16* whp = WHs + (size_t)2*CC*CC;
    const u16* wlp = WLs + (size_t)2*CC*CC;
    for (int osub = 0; osub < 2; ++osub) {
      const int ocol = wv*32 + osub*16;
      bf16x8 wbh[4], wbl[4];
      #pragma unroll
      for (int it=0; it<4; ++it) {
        size_t wi = (size_t)(ocol + l15)*CC + it*32 + lhi*8;
        wbh[it] = *(const bf16x8*)(whp + wi);
        wbl[it] = *(const bf16x8*)(wlp + wi);
      }
      for (int msub = 0; msub < 4; ++msub) {
        const int mrow = msub*16 + l15;
        f32x4 acc = {0.f,0.f,0.f,0.f};
        #pragma unroll
        for (int it=0; it<4; ++it) {
          int byt = mrow*256 + ((it*64 + lhi*16) ^ ((mrow&7)<<4));
          bf16x8 ah = *(const bf16x8*)((const char*)xsh + byt);
          bf16x8 al = *(const bf16x8*)((const char*)xsl + byt);
          acc = __builtin_amdgcn_mfma_f32_16x16x32_bf16(wbh[it], ah, acc, 0,0,0);
          acc = __builtin_amdgcn_mfma_f32_16x16x32_bf16(wbh[it], al, acc, 0,0,0);
          acc = __builtin_amdgcn_mfma_f32_16x16x32_bf16(wbl[it], ah, acc, 0,0,0);
        }
        #pragma unroll
        for (int r=0;r<4;++r) {
          int o = ocol + lhi*4 + r;
          int m = m0 + msub*16 + l15;
          if (m < VST)
            VF[((size_t)b*CC + o)*VST + m] = f2h(acc[r]);  // zeroed >= MM2
        }
      }
    }
  }
}

// ---------------------------------------------------------------
// fusedE: ONE QK^T pass -> partial rowsum of exp(e), bin energies,
// and PU = fp16 unnormalized exp(e) [b][n][VST]. kt half-split (grid 1024).
// ---------------------------------------------------------------
__global__ __launch_bounds__(256) void fusedE_kernel(
    const u16* __restrict__ QH, const u16* __restrict__ QL,
    const u16* __restrict__ KH, const u16* __restrict__ KL,
    float* __restrict__ rsumP, float* __restrict__ ebins, u16* __restrict__ PU)
{
  __shared__ u16 kh[64*128], kl[64*128];
  const int t = threadIdx.x;
  const int half = blockIdx.x & 1;
  const int rest = blockIdx.x >> 1;
  const int b = rest >> 5;
  const int n0 = (rest & 31) * 64;
  const int wv = t >> 6, lane = t & 63;
  const int l15 = lane & 15, lhi = lane >> 4;
  const int nw = n0 + wv*16;
  const int ktBeg = half ? 17 : 0;
  const int ktEnd = half ? 33 : 17;

  bf16x8 qh[4], ql[4];
  {
    const size_t rb = ((size_t)b*NN + nw + l15)*CC + lhi*8;
    #pragma unroll
    for (int it=0; it<4; ++it) {
      qh[it] = *(const bf16x8*)(QH + rb + it*32);
      ql[it] = *(const bf16x8*)(QL + rb + it*32);
    }
  }
  float runsum[4] = {0.f, 0.f, 0.f, 0.f};

  for (int kt = ktBeg; kt < ktEnd; ++kt) {
    const int m0 = kt*64;
    __syncthreads();
    {
      const int row0 = t >> 4, chunk = t & 15;
      #pragma unroll
      for (int ii=0; ii<4; ++ii) {
        int r = row0 + ii*16; int gm = m0 + r;
        int dst = r*256 + ((chunk*16) ^ ((r&7)<<4));
        uint4 vh = make_uint4(0,0,0,0), vl = make_uint4(0,0,0,0);
        if (gm < MM2) {
          size_t g = ((size_t)b*MM2 + gm)*CC + chunk*8;
          vh = *(const uint4*)(KH + g);
          vl = *(const uint4*)(KL + g);
        }
        *(uint4*)((char*)kh + dst) = vh;
        *(uint4*)((char*)kl + dst) = vl;
      }
    }
    __syncthreads();
    const int mcEnd = (kt == 32) ? 1 : 4;
    for (int mc = 0; mc < mcEnd; ++mc) {
      f32x4 acc = {0.f,0.f,0.f,0.f};
      const int mrow = mc*16 + l15;
      #pragma unroll
      for (int it=0; it<4; ++it) {
        int byt = mrow*256 + ((it*64 + lhi*16) ^ ((mrow&7)<<4));
        bf16x8 bh = *(const bf16x8*)((const char*)kh + byt);
        bf16x8 bl = *(const bf16x8*)((const char*)kl + byt);
        acc = __builtin_amdgcn_mfma_f32_16x16x32_bf16(qh[it], bh, acc, 0,0,0);
        acc = __builtin_amdgcn_mfma_f32_16x16x32_bf16(qh[it], bl, acc, 0,0,0);
        acc = __builtin_amdgcn_mfma_f32_16x16x32_bf16(ql[it], bh, acc, 0,0,0);
      }
      const int m = m0 + mrow;
      if (kt == 32 && l15 < 4) {
        #pragma unroll
        for (int r=0;r<4;++r)
          ebins[((size_t)b*NN + nw + lhi*4 + r)*4 + l15] = acc[r];
      }
      const bool valid = (m < MM2);
      #pragma unroll
      for (int r=0;r<4;++r) {
        float ex = valid ? __expf(acc[r]) : 0.f;
        if (m < VST)
          PU[((size_t)b*NN + nw + lhi*4 + r)*VST + m] = f2h(ex);
        runsum[r] += ex;
      }
    }
  }
  #pragma unroll
  for (int r=0;r<4;++r) {
    runsum[r] += __shfl_xor(runsum[r], 1);
    runsum[r] += __shfl_xor(runsum[r], 2);
    runsum[r] += __shfl_xor(runsum[r], 4);
    runsum[r] += __shfl_xor(runsum[r], 8);
  }
  if (l15 == 0) {
    float* rs = rsumP + (size_t)half*BB*NN;
    #pragma unroll
    for (int r=0;r<4;++r)
      rs[(size_t)b*NN + nw + lhi*4 + r] = runsum[r];
  }
}

// ---------------------------------------------------------------
// colsum: score partials. score[b][m] = sum_n PU[b][n][m]*sirs[n].
// grid 512 = 16b x 4 mtiles(512) x 8 nchunks(256). Streaming read-bound.
// ---------------------------------------------------------------
__global__ __launch_bounds__(256) void colsum_kernel(
    const u16* __restrict__ PU, const float* __restrict__ rsumP,
    float* __restrict__ scoreP)
{
  __shared__ float sirs[256];
  const int t = threadIdx.x;
  const int blk = blockIdx.x;
  const int ns = blk & 7;
  const int mt = (blk >> 3) & 3;
  const int b  = blk >> 5;
  const int n0 = ns*256;
  const int m0 = mt*512;
  {
    size_t ri = (size_t)b*NN + n0 + t;
    sirs[t] = 1.0f / (rsumP[ri] + rsumP[(size_t)BB*NN + ri]);
  }
  __syncthreads();
  float s0a = 0.f, s1a = 0.f;
  const u16* base = PU + ((size_t)b*NN + n0)*VST + m0 + 2*t;
  #pragma unroll 4
  for (int n = 0; n < 256; ++n) {
    unsigned pv = *(const unsigned*)(base + (size_t)n*VST);
    union { unsigned u; _Float16 h[2]; } cv; cv.u = pv;
    float w = sirs[n];
    s0a = fmaf((float)cv.h[0], w, s0a);
    s1a = fmaf((float)cv.h[1], w, s1a);
  }
  float2 o; o.x = s0a; o.y = s1a;
  *(float2*)(scoreP + (size_t)ns*BB*NN + (size_t)b*NN + m0 + 2*t) = o;
}

// ---------------------------------------------------------------
// bin: merge 8 score partials, bin assignment + budget allocation
// ---------------------------------------------------------------
__global__ __launch_bounds__(256) void bin_kernel(
    const float* __restrict__ scoreP, const float* __restrict__ ebins,
    float* __restrict__ score, int* __restrict__ binof, int* __restrict__ kbins)
{
  const int b = blockIdx.x, t = threadIdx.x;
  float wsm[4] = {0.f,0.f,0.f,0.f};
  int   cnt[4] = {0,0,0,0};
  for (int n = t; n < NN; n += 256) {
    size_t si = (size_t)b*NN + n;
    float s = 0.f;
    #pragma unroll
    for (int h = 0; h < 8; ++h) s += scoreP[(size_t)h*BB*NN + si];
    score[si] = s;
    int j = (s >= 1.2f) ? 0 : (s >= 1.0f) ? 1 : (s >= 0.8f) ? 2 : 3;
    binof[si] = j;
    wsm[j] += ebins[si*4 + j];
    cnt[j] += 1;
  }
  #pragma unroll
  for (int j=0;j<4;j++){
    for (int off=1; off<64; off<<=1){
      wsm[j] += __shfl_xor(wsm[j], off);
      cnt[j] += __shfl_xor(cnt[j], off);
    }
  }
  __shared__ float wred[4][4];
  __shared__ int   cred[4][4];
  int wave = t >> 6, lane = t & 63;
  if (lane == 0) for (int j=0;j<4;j++){ wred[wave][j]=wsm[j]; cred[wave][j]=cnt[j]; }
  __syncthreads();
  if (t == 0) {
    float wsum[4]; int cs[4];
    for (int j=0;j<4;j++){
      wsum[j]=wred[0][j]+wred[1][j]+wred[2][j]+wred[3][j];
      cs[j]=cred[0][j]+cred[1][j]+cred[2][j]+cred[3][j];
    }
    float bw[4]; float sbw = 0.f;
    for (int j=0;j<4;j++){
      float wp = wsum[j] / ((float)cs[j] + 1e-8f);
      bw[j] = fmaxf(wp, 0.f); sbw += bw[j];
    }
    float den = fmaxf(sbw, 1e-8f);
    int k0[4]; int sk0 = 0;
    for (int j=0;j<4;j++){
      float p = bw[j] / den;
      int kk = (int)floorf(p * 1024.0f);
      if (kk > cs[j]) kk = cs[j];
      k0[j]=kk; sk0 += kk;
    }
    int deficit = 1024 - sk0;
    int cum = 0;
    for (int j=0;j<4;j++){
      int cap = cs[j] - k0[j];
      int ex = deficit - cum; if (ex < 0) ex = 0; if (ex > cap) ex = cap;
      kbins[b*4+j] = k0[j] + ex;
      cum += cap;
    }
  }
}

// ---------------------------------------------------------------
// topk: per-(batch,bin) top-k by (score desc, index asc) -> flags
// ---------------------------------------------------------------
__global__ __launch_bounds__(256) void topk_kernel(
    const float* __restrict__ score, const int* __restrict__ binof,
    const int* __restrict__ kbins, int* __restrict__ flags)
{
  __shared__ unsigned long long arr[2048];
  const int t = threadIdx.x;
  const int b = blockIdx.x >> 2;
  const int j = blockIdx.x & 3;
  for (int n = t; n < NN; n += 256) {
    unsigned long long comp = 0ull;
    if (binof[(size_t)b*NN+n] == j) {
      unsigned int bits = __float_as_uint(score[(size_t)b*NN+n]);
      bits = (bits & 0x80000000u) ? ~bits : (bits | 0x80000000u);
      comp = ((unsigned long long)bits << 32) |
             (unsigned long long)(0xFFFFFFFFu - (unsigned)n);
    }
    arr[n] = ~comp;
  }
  __syncthreads();
  for (int ksz = 2; ksz <= 2048; ksz <<= 1) {
    for (int jsz = ksz >> 1; jsz > 0; jsz >>= 1) {
      for (int i = t; i < 2048; i += 256) {
        int ixj = i ^ jsz;
        if (ixj > i) {
          unsigned long long a = arr[i], bv = arr[ixj];
          bool up = ((i & ksz) == 0);
          if ((a > bv) == up) { arr[i] = bv; arr[ixj] = a; }
        }
      }
      __syncthreads();
    }
  }
  const int kb = kbins[b*4+j];
  for (int i = t; i < kb; i += 256) {
    unsigned long long comp = ~arr[i];
    int n = (int)(0xFFFFFFFFu - (unsigned)(comp & 0xFFFFFFFFull));
    flags[(size_t)b*NN + n] = 1;
  }
}

// ---------------------------------------------------------------
// scan: prefix-scan of flags -> selected index list + index output
// ---------------------------------------------------------------
__global__ __launch_bounds__(256) void scan_kernel(
    const int* __restrict__ flags, int* __restrict__ idxl, float* __restrict__ outIdx)
{
  __shared__ int tsum[256];
  const int b = blockIdx.x, t = threadIdx.x;
  int f[8]; int c8 = 0;
  const int base = t * 8;
  #pragma unroll
  for (int i=0;i<8;i++){ f[i] = flags[(size_t)b*NN + base + i]; c8 += f[i]; }
  tsum[t] = c8;
  __syncthreads();
  for (int off=1; off<256; off<<=1) {
    int v = (t >= off) ? tsum[t-off] : 0;
    __syncthreads();
    tsum[t] += v;
    __syncthreads();
  }
  int pos = tsum[t] - c8;
  #pragma unroll
  for (int i=0;i<8;i++){
    if (f[i] && pos < MM) {
      idxl[(size_t)b*MM + pos] = base + i;
      outIdx[(size_t)b*MM + pos] = (float)(base + i);
      pos++;
    }
  }
}

// ---------------------------------------------------------------
// outC: pure PV on unnormalized P; scale by sirs at epilogue.
// kt 3-way split into 3 partial buffers (grid 768).
// ---------------------------------------------------------------
__global__ __launch_bounds__(256) void outC_kernel(
    const u16* __restrict__ PU, const u16* __restrict__ VF,
    const float* __restrict__ rsumP,
    const int* __restrict__ idxl, float* __restrict__ oPart)
{
  __shared__ u16 psh[64*64];    // [selrow][m] fp16 (swizzled)
  __shared__ u16 vsh[128*64];   // [c][m] fp16 (swizzled)
  __shared__ int rid[64];
  __shared__ float ssel[64];
  const int t = threadIdx.x;
  const int third = blockIdx.x % 3;
  const int rest  = blockIdx.x / 3;
  const int b  = rest >> 4;
  const int s0 = (rest & 15) * 64;
  const int wv = t >> 6, lane = t & 63;
  const int l15 = lane & 15, lhi = lane >> 4;
  const int ktBeg = third * 11, ktEnd = ktBeg + 11;

  if (t < 64) {
    int n = idxl[(size_t)b*MM + s0 + t];
    rid[t] = n;
    size_t ri = (size_t)b*NN + n;
    ssel[t] = 1.0f / (rsumP[ri] + rsumP[(size_t)BB*NN + ri]);
  }

  f32x4 oacc[8];
  #pragma unroll
  for (int ct=0; ct<8; ++ct) oacc[ct] = (f32x4){0.f,0.f,0.f,0.f};

  for (int kt = ktBeg; kt < ktEnd; ++kt) {
    const int m0 = kt*64;
    __syncthreads();
    #pragma unroll
    for (int ii=0; ii<2; ++ii) {
      int item = t + 256*ii;
      int row = item >> 3, ch = item & 7;
      int gm = m0 + ch*8;
      uint4 v = make_uint4(0,0,0,0);
      if (gm < VST) v = *(const uint4*)(PU + ((size_t)b*NN + rid[row])*VST + gm);
      *(uint4*)((char*)psh + row*128 + ((ch*16) ^ ((row&7)<<4))) = v;
    }
    #pragma unroll
    for (int ii=0; ii<4; ++ii) {
      int item = t + 256*ii;
      int c = item >> 3, ch = item & 7;
      int gm = m0 + ch*8;
      uint4 v = make_uint4(0,0,0,0);
      if (gm < VST) v = *(const uint4*)(VF + ((size_t)b*CC + c)*VST + gm);
      *(uint4*)((char*)vsh + c*128 + ((ch*16) ^ ((c&7)<<4))) = v;
    }
    __syncthreads();
    #pragma unroll
    for (int ki=0; ki<2; ++ki) {
      const int prow = wv*16 + l15;
      f16x8 pa = *(const f16x8*)((const char*)psh + prow*128 + ((ki*64 + lhi*16) ^ ((prow&7)<<4)));
      #pragma unroll
      for (int ct=0; ct<8; ++ct) {
        int c = ct*16 + l15;
        f16x8 vb = *(const f16x8*)((const char*)vsh + c*128 + ((ki*64 + lhi*16) ^ ((c&7)<<4)));
        oacc[ct] = __builtin_amdgcn_mfma_f32_16x16x32_f16(pa, vb, oacc[ct], 0,0,0);
      }
    }
  }
  float* op = oPart + (size_t)third*BB*CC*MM;
  #pragma unroll
  for (int ct=0; ct<8; ++ct) {
    #pragma unroll
    for (int r=0;r<4;++r) {
      op[((size_t)b*CC + ct*16 + l15)*MM + s0 + wv*16 + lhi*4 + r] =
          oacc[ct][r] * ssel[wv*16 + lhi*4 + r];
    }
  }
}

// ---------------------------------------------------------------
// merge: out0 = sum of 3 partials (deterministic order)
// ---------------------------------------------------------------
__global__ __launch_bounds__(256) void merge_kernel(
    const float* __restrict__ oPart, float* __restrict__ out0)
{
  const size_t i = ((size_t)blockIdx.x*256 + threadIdx.x)*4;
  const float4 a = *(const float4*)(oPart + i);
  const float4 b = *(const float4*)(oPart + (size_t)BB*CC*MM + i);
  const float4 c = *(const float4*)(oPart + (size_t)2*BB*CC*MM + i);
  float4 o;
  o.x = a.x + b.x + c.x;
  o.y = a.y + b.y + c.y;
  o.z = a.z + b.z + c.z;
  o.w = a.w + b.w + c.w;
  *(float4*)(out0 + i) = o;
}

// ---------------------------------------------------------------
extern "C" void kernel_launch(void* const* d_in, const int* in_sizes, int n_in,
                              void* d_out, int out_size, void* d_ws, size_t ws_size,
                              hipStream_t stream) {
  const float* x  = (const float*)d_in[0];
  const float* Wq = (const float*)d_in[1];
  const float* Wk = (const float*)d_in[2];
  const float* Wv = (const float*)d_in[3];
  const float* bt = (const float*)d_in[4];
  float* out = (float*)d_out;
  char* ws = (char*)d_ws;

  u16* QH = (u16*)(ws + oQH);
  u16* QL = (u16*)(ws + oQL);
  u16* KH = (u16*)(ws + oKH);
  u16* KL = (u16*)(ws + oKL);
  u16* VF = (u16*)(ws + oVF);
  float* rsumP = (float*)(ws + oRS0);
  float* ebins = (float*)(ws + oEB);
  float* scoreP= (float*)(ws + oSC0);
  float* score = (float*)(ws + oSCORE);
  int* binof = (int*)(ws + oBIN);
  int* kbins = (int*)(ws + oKB);
  int* flags = (int*)(ws + oFL);
  int* idxl  = (int*)(ws + oIDX);
  u16* XH = (u16*)(ws + oXH);
  u16* XL = (u16*)(ws + oXL);
  u16* WHs = (u16*)(ws + oWH);
  u16* WLs = (u16*)(ws + oWL);
  u16* PU  = (u16*)(ws + oPU);     // aliases X/W (dead by then)
  float* oPart = (float*)(ws + oOP);

  float* out0   = out;                        // (B,C,M)
  float* outIdx = out + (size_t)BB*CC*MM;     // (B,1,M) as float

  (void)hipMemsetAsync(flags, 0, (size_t)BB*NN*sizeof(int), stream);

  hipLaunchKernelGGL(splitX_kernel,  dim3(528),  dim3(256), 0, stream, x, bt, XH, XL);
  hipLaunchKernelGGL(splitW_kernel,  dim3(192),  dim3(256), 0, stream, Wq, Wk, Wv, WHs, WLs);
  hipLaunchKernelGGL(projM_kernel,   dim3(528),  dim3(256), 0, stream, XH, XL, WHs, WLs, QH, QL, KH, KL, VF);
  hipLaunchKernelGGL(fusedE_kernel,  dim3(1024), dim3(256), 0, stream, QH, QL, KH, KL, rsumP, ebins, PU);
  hipLaunchKernelGGL(colsum_kernel,  dim3(512),  dim3(256), 0, stream, PU, rsumP, scoreP);
  hipLaunchKernelGGL(bin_kernel,     dim3(16),   dim3(256), 0, stream, scoreP, ebins, score, binof, kbins);
  hipLaunchKernelGGL(topk_kernel,    dim3(64),   dim3(256), 0, stream, score, binof, kbins, flags);
  hipLaunchKernelGGL(scan_kernel,    dim3(16),   dim3(256), 0, stream, flags, idxl, outIdx);
  hipLaunchKernelGGL(outC_kernel,    dim3(768),  dim3(256), 0, stream, PU, VF, rsumP, idxl, oPart);
  hipLaunchKernelGGL(merge_kernel,   dim3(2048), dim3(256), 0, stream, oPart, out0);
}

// Round 10
// 318.419 us; speedup vs baseline: 5.6213x; 1.0211x over previous
//
#include <hip/hip_runtime.h>

#define BB 16
#define CC 128
#define NN 2048
#define MM2 2052
#define VST 2056   // padded V / P row stride (fp16, 16B-aligned rows)
#define MM 1024

constexpr float RSQRT_C = 0.08838834764831845f; // 1/sqrt(128)

typedef unsigned short u16;
typedef __attribute__((ext_vector_type(8))) short bf16x8;
typedef __attribute__((ext_vector_type(8))) _Float16 f16x8;
typedef __attribute__((ext_vector_type(4))) float f32x4;

__device__ inline u16 f2b_rn(float f) {
  unsigned u = __float_as_uint(f);
  unsigned r = u + 0x7fffu + ((u >> 16) & 1u);
  return (u16)(r >> 16);
}
__device__ inline float b2f(u16 h) { return __uint_as_float(((unsigned)h) << 16); }
__device__ inline u16 f2h(float f) {
  union { _Float16 h; u16 u; } cv; cv.h = (_Float16)f; return cv.u;
}
__device__ inline void store8(u16* dst, const u16 h[8]) {
  uint4 v;
  v.x = (unsigned)h[0] | ((unsigned)h[1] << 16);
  v.y = (unsigned)h[2] | ((unsigned)h[3] << 16);
  v.z = (unsigned)h[4] | ((unsigned)h[5] << 16);
  v.w = (unsigned)h[6] | ((unsigned)h[7] << 16);
  *(uint4*)dst = v;
}

// ---- workspace layout (byte offsets) ----
constexpr size_t SZ_Q  = (size_t)BB*NN*CC*2;
constexpr size_t SZ_K  = (size_t)BB*MM2*CC*2;
constexpr size_t SZ_V  = (size_t)BB*CC*VST*2;
constexpr size_t oQH = 0;
constexpr size_t oQL = oQH + SZ_Q;
constexpr size_t oKH = oQL + SZ_Q;
constexpr size_t oKL = oKH + SZ_K;
constexpr size_t oVF = oKL + SZ_K;                     // fp16 V
constexpr size_t oRS0 = oVF + SZ_V;                    // 2*BB*NN f32 partial rowsums
constexpr size_t oEB  = oRS0 + (size_t)2*BB*NN*4;      // BB*NN*4 f32
constexpr size_t oSC0 = oEB  + (size_t)BB*NN*16;       // 8*BB*NN f32 partial scores
constexpr size_t oSCORE = oSC0 + (size_t)8*BB*NN*4;    // BB*NN f32 merged
constexpr size_t oBIN = oSCORE + (size_t)BB*NN*4;      // int
constexpr size_t oKB  = oBIN + (size_t)BB*NN*4;        // BB*4 int
constexpr size_t oFL  = oKB  + 256;                    // BB*NN int
constexpr size_t oIDX = oFL  + (size_t)BB*NN*4;        // BB*MM int
constexpr size_t oWH  = oIDX + (size_t)BB*MM*4;        // 3*128*128 u16
constexpr size_t oWL  = oWH  + (size_t)3*CC*CC*2;
constexpr size_t oPU  = oWL  + (size_t)3*CC*CC*2;      // fp16 unnormalized exp(e)
constexpr size_t SZ_PU = (size_t)BB*NN*VST*2;
constexpr size_t oOP  = oPU + SZ_PU;                   // 3 partial outputs f32

// ---------------------------------------------------------------
// splitW: W hi/lo bf16, packed [w][o][c], w in {q,k,v}
// ---------------------------------------------------------------
__global__ __launch_bounds__(256) void splitW_kernel(
    const float* __restrict__ Wq, const float* __restrict__ Wk, const float* __restrict__ Wv,
    u16* __restrict__ WH, u16* __restrict__ WL)
{
  int i = blockIdx.x*256 + threadIdx.x;
  int w = i >> 14, rest = i & 16383;
  const float* W = (w == 0) ? Wq : (w == 1) ? Wk : Wv;
  float v = W[rest];
  u16 hb = f2b_rn(v);
  WH[i] = hb; WL[i] = f2b_rn(v - b2f(hb));
}

// ---------------------------------------------------------------
// projM: fused transpose+split+Q/K/V projection via bf16x3 MFMA.
// Reads x directly (phase A fp32 transpose in LDS, phase B bf16 hi/lo
// split into swizzled operand buffers).
// Q[b][n][o] (scaled) hi/lo, K[b][m][o] hi/lo, V[b][o][m] fp16.
// ---------------------------------------------------------------
__global__ __launch_bounds__(256) void projM_kernel(
    const float* __restrict__ x, const float* __restrict__ bt,
    const u16* __restrict__ WHs, const u16* __restrict__ WLs,
    u16* __restrict__ QH, u16* __restrict__ QL,
    u16* __restrict__ KH, u16* __restrict__ KL,
    u16* __restrict__ VF)
{
  __shared__ float xs[64][130];
  __shared__ u16 xsh[64*128], xsl[64*128];
  const int t = threadIdx.x;
  const int b  = blockIdx.x / 33;
  const int mt = blockIdx.x % 33;
  const int m0 = mt*64;
  const int wv = t >> 6, lane = t & 63;
  const int l15 = lane & 15, lhi = lane >> 4;

  // phase A: stage x tile (fp32) transposed into xs[m][c]
  if (mt < 32) {
    for (int i = t; i < 128*64; i += 256) {
      int c = i >> 6, n = i & 63;
      xs[n][c] = x[((size_t)b*CC + c)*NN + m0 + n];
    }
  } else {
    for (int i = t; i < 64*128; i += 256) {
      int n = i >> 7, c = i & 127;
      xs[n][c] = (n < 4) ? bt[c*4 + n] : 0.f;
    }
  }
  __syncthreads();
  // phase B: bf16 hi/lo split into swizzled xsh/xsl
  {
    const int row0 = t >> 4, chunk = t & 15;
    #pragma unroll
    for (int ii=0; ii<4; ++ii) {
      int r = row0 + ii*16;
      const float* src = &xs[r][chunk*8];
      u16 hs[8], ls[8];
      #pragma unroll
      for (int j=0;j<8;++j) {
        float v = src[j];
        u16 hb = f2b_rn(v);
        hs[j] = hb; ls[j] = f2b_rn(v - b2f(hb));
      }
      int dst = r*256 + ((chunk*16) ^ ((r&7)<<4));
      store8((u16*)((char*)xsh + dst), hs);
      store8((u16*)((char*)xsl + dst), ls);
    }
  }
  __syncthreads();

  // q (w=0), k (w=1): A = x rows (m), B = W rows (o) -> D[m][o]
  for (int w = (m0 >= NN) ? 1 : 0; w < 2; ++w) {
    const u16* whp = WHs + (size_t)w*CC*CC;
    const u16* wlp = WLs + (size_t)w*CC*CC;
    u16* OH = w ? KH : QH;
    u16* OL = w ? KL : QL;
    const float scl = w ? 1.0f : RSQRT_C;
    const int mlim = w ? MM2 : NN;
    for (int osub = 0; osub < 2; ++osub) {
      const int ocol = wv*32 + osub*16;
      bf16x8 wbh[4], wbl[4];
      #pragma unroll
      for (int it=0; it<4; ++it) {
        size_t wi = (size_t)(ocol + l15)*CC + it*32 + lhi*8;
        wbh[it] = *(const bf16x8*)(WHs + (size_t)w*CC*CC + wi);
        wbl[it] = *(const bf16x8*)(WLs + (size_t)w*CC*CC + wi);
      }
      for (int msub = 0; msub < 4; ++msub) {
        const int mrow = msub*16 + l15;
        f32x4 acc = {0.f,0.f,0.f,0.f};
        #pragma unroll
        for (int it=0; it<4; ++it) {
          int byt = mrow*256 + ((it*64 + lhi*16) ^ ((mrow&7)<<4));
          bf16x8 ah = *(const bf16x8*)((const char*)xsh + byt);
          bf16x8 al = *(const bf16x8*)((const char*)xsl + byt);
          acc = __builtin_amdgcn_mfma_f32_16x16x32_bf16(ah, wbh[it], acc, 0,0,0);
          acc = __builtin_amdgcn_mfma_f32_16x16x32_bf16(ah, wbl[it], acc, 0,0,0);
          acc = __builtin_amdgcn_mfma_f32_16x16x32_bf16(al, wbh[it], acc, 0,0,0);
        }
        #pragma unroll
        for (int r=0;r<4;++r) {
          int m = m0 + msub*16 + lhi*4 + r;
          if (m < mlim) {
            float vv = acc[r] * scl;
            u16 hb = f2b_rn(vv);
            size_t oi = w ? ((size_t)b*MM2 + m)*CC + ocol + l15
                          : ((size_t)b*NN  + m)*CC + ocol + l15;
            OH[oi] = hb;
            OL[oi] = f2b_rn(vv - b2f(hb));
          }
        }
      }
    }
    (void)whp; (void)wlp;
  }

  // v: A = W rows (o), B = x rows (m) -> D[o][m], fp16 out
  {
    const u16* whp = WHs + (size_t)2*CC*CC;
    const u16* wlp = WLs + (size_t)2*CC*CC;
    for (int osub = 0; osub < 2; ++osub) {
      const int ocol = wv*32 + osub*16;
      bf16x8 wbh[4], wbl[4];
      #pragma unroll
      for (int it=0; it<4; ++it) {
        size_t wi = (size_t)(ocol + l15)*CC + it*32 + lhi*8;
        wbh[it] = *(const bf16x8*)(whp + wi);
        wbl[it] = *(const bf16x8*)(wlp + wi);
      }
      for (int msub = 0; msub < 4; ++msub) {
        const int mrow = msub*16 + l15;
        f32x4 acc = {0.f,0.f,0.f,0.f};
        #pragma unroll
        for (int it=0; it<4; ++it) {
          int byt = mrow*256 + ((it*64 + lhi*16) ^ ((mrow&7)<<4));
          bf16x8 ah = *(const bf16x8*)((const char*)xsh + byt);
          bf16x8 al = *(const bf16x8*)((const char*)xsl + byt);
          acc = __builtin_amdgcn_mfma_f32_16x16x32_bf16(wbh[it], ah, acc, 0,0,0);
          acc = __builtin_amdgcn_mfma_f32_16x16x32_bf16(wbh[it], al, acc, 0,0,0);
          acc = __builtin_amdgcn_mfma_f32_16x16x32_bf16(wbl[it], ah, acc, 0,0,0);
        }
        #pragma unroll
        for (int r=0;r<4;++r) {
          int o = ocol + lhi*4 + r;
          int m = m0 + msub*16 + l15;
          if (m < VST)
            VF[((size_t)b*CC + o)*VST + m] = f2h(acc[r]);  // zeroed >= MM2
        }
      }
    }
  }
}

// ---------------------------------------------------------------
// fusedE: ONE QK^T pass -> partial rowsum of exp(e), bin energies,
// and PU = fp16 unnormalized exp(e) [b][n][VST]. kt half-split (grid 1024).
// Fast path (kt<32) has no bounds checks; kt==32 tail (half 1) checked.
// ---------------------------------------------------------------
__global__ __launch_bounds__(256) void fusedE_kernel(
    const u16* __restrict__ QH, const u16* __restrict__ QL,
    const u16* __restrict__ KH, const u16* __restrict__ KL,
    float* __restrict__ rsumP, float* __restrict__ ebins, u16* __restrict__ PU)
{
  __shared__ u16 kh[64*128], kl[64*128];
  const int t = threadIdx.x;
  const int half = blockIdx.x & 1;
  const int rest = blockIdx.x >> 1;
  const int b = rest >> 5;
  const int n0 = (rest & 31) * 64;
  const int wv = t >> 6, lane = t & 63;
  const int l15 = lane & 15, lhi = lane >> 4;
  const int nw = n0 + wv*16;
  const int ktBeg = half ? 17 : 0;
  const int ktFastEnd = half ? 32 : 17;

  bf16x8 qh[4], ql[4];
  {
    const size_t rb = ((size_t)b*NN + nw + l15)*CC + lhi*8;
    #pragma unroll
    for (int it=0; it<4; ++it) {
      qh[it] = *(const bf16x8*)(QH + rb + it*32);
      ql[it] = *(const bf16x8*)(QL + rb + it*32);
    }
  }
  u16* puR[4];
  #pragma unroll
  for (int r=0;r<4;++r)
    puR[r] = PU + ((size_t)b*NN + nw + lhi*4 + r)*VST;

  float runsum[4] = {0.f, 0.f, 0.f, 0.f};

  for (int kt = ktBeg; kt < ktFastEnd; ++kt) {
    const int m0 = kt*64;
    __syncthreads();
    {
      const int row0 = t >> 4, chunk = t & 15;
      #pragma unroll
      for (int ii=0; ii<4; ++ii) {
        int r = row0 + ii*16;
        int dst = r*256 + ((chunk*16) ^ ((r&7)<<4));
        size_t g = ((size_t)b*MM2 + m0 + r)*CC + chunk*8;
        *(uint4*)((char*)kh + dst) = *(const uint4*)(KH + g);
        *(uint4*)((char*)kl + dst) = *(const uint4*)(KL + g);
      }
    }
    __syncthreads();
    for (int mc = 0; mc < 4; ++mc) {
      f32x4 acc = {0.f,0.f,0.f,0.f};
      const int mrow = mc*16 + l15;
      #pragma unroll
      for (int it=0; it<4; ++it) {
        int byt = mrow*256 + ((it*64 + lhi*16) ^ ((mrow&7)<<4));
        bf16x8 bh = *(const bf16x8*)((const char*)kh + byt);
        bf16x8 bl = *(const bf16x8*)((const char*)kl + byt);
        acc = __builtin_amdgcn_mfma_f32_16x16x32_bf16(qh[it], bh, acc, 0,0,0);
        acc = __builtin_amdgcn_mfma_f32_16x16x32_bf16(qh[it], bl, acc, 0,0,0);
        acc = __builtin_amdgcn_mfma_f32_16x16x32_bf16(ql[it], bh, acc, 0,0,0);
      }
      const int m = m0 + mrow;
      #pragma unroll
      for (int r=0;r<4;++r) {
        float ex = __expf(acc[r]);
        puR[r][m] = f2h(ex);
        runsum[r] += ex;
      }
    }
  }

  if (half) {   // kt == 32 tail (checked)
    const int m0 = 2048;
    __syncthreads();
    {
      const int row0 = t >> 4, chunk = t & 15;
      #pragma unroll
      for (int ii=0; ii<4; ++ii) {
        int r = row0 + ii*16; int gm = m0 + r;
        int dst = r*256 + ((chunk*16) ^ ((r&7)<<4));
        uint4 vh = make_uint4(0,0,0,0), vl = make_uint4(0,0,0,0);
        if (gm < MM2) {
          size_t g = ((size_t)b*MM2 + gm)*CC + chunk*8;
          vh = *(const uint4*)(KH + g);
          vl = *(const uint4*)(KL + g);
        }
        *(uint4*)((char*)kh + dst) = vh;
        *(uint4*)((char*)kl + dst) = vl;
      }
    }
    __syncthreads();
    {
      f32x4 acc = {0.f,0.f,0.f,0.f};
      const int mrow = l15;
      #pragma unroll
      for (int it=0; it<4; ++it) {
        int byt = mrow*256 + ((it*64 + lhi*16) ^ ((mrow&7)<<4));
        bf16x8 bh = *(const bf16x8*)((const char*)kh + byt);
        bf16x8 bl = *(const bf16x8*)((const char*)kl + byt);
        acc = __builtin_amdgcn_mfma_f32_16x16x32_bf16(qh[it], bh, acc, 0,0,0);
        acc = __builtin_amdgcn_mfma_f32_16x16x32_bf16(qh[it], bl, acc, 0,0,0);
        acc = __builtin_amdgcn_mfma_f32_16x16x32_bf16(ql[it], bh, acc, 0,0,0);
      }
      const int m = m0 + mrow;
      if (l15 < 4) {
        #pragma unroll
        for (int r=0;r<4;++r)
          ebins[((size_t)b*NN + nw + lhi*4 + r)*4 + l15] = acc[r];
      }
      const bool valid = (m < MM2);
      #pragma unroll
      for (int r=0;r<4;++r) {
        float ex = valid ? __expf(acc[r]) : 0.f;
        if (m < VST) puR[r][m] = f2h(ex);
        runsum[r] += ex;
      }
    }
  }

  #pragma unroll
  for (int r=0;r<4;++r) {
    runsum[r] += __shfl_xor(runsum[r], 1);
    runsum[r] += __shfl_xor(runsum[r], 2);
    runsum[r] += __shfl_xor(runsum[r], 4);
    runsum[r] += __shfl_xor(runsum[r], 8);
  }
  if (l15 == 0) {
    float* rs = rsumP + (size_t)half*BB*NN;
    #pragma unroll
    for (int r=0;r<4;++r)
      rs[(size_t)b*NN + nw + lhi*4 + r] = runsum[r];
  }
}

// ---------------------------------------------------------------
// colsum: score partials. score[b][m] = sum_n PU[b][n][m]*sirs[n].
// grid 512 = 16b x 4 mtiles(512) x 8 nchunks(256). Streaming read-bound.
// ---------------------------------------------------------------
__global__ __launch_bounds__(256) void colsum_kernel(
    const u16* __restrict__ PU, const float* __restrict__ rsumP,
    float* __restrict__ scoreP)
{
  __shared__ float sirs[256];
  const int t = threadIdx.x;
  const int blk = blockIdx.x;
  const int ns = blk & 7;
  const int mt = (blk >> 3) & 3;
  const int b  = blk >> 5;
  const int n0 = ns*256;
  const int m0 = mt*512;
  {
    size_t ri = (size_t)b*NN + n0 + t;
    sirs[t] = 1.0f / (rsumP[ri] + rsumP[(size_t)BB*NN + ri]);
  }
  __syncthreads();
  float s0a = 0.f, s1a = 0.f;
  const u16* base = PU + ((size_t)b*NN + n0)*VST + m0 + 2*t;
  #pragma unroll 4
  for (int n = 0; n < 256; ++n) {
    unsigned pv = *(const unsigned*)(base + (size_t)n*VST);
    union { unsigned u; _Float16 h[2]; } cv; cv.u = pv;
    float w = sirs[n];
    s0a = fmaf((float)cv.h[0], w, s0a);
    s1a = fmaf((float)cv.h[1], w, s1a);
  }
  float2 o; o.x = s0a; o.y = s1a;
  *(float2*)(scoreP + (size_t)ns*BB*NN + (size_t)b*NN + m0 + 2*t) = o;
}

// ---------------------------------------------------------------
// bin: merge 8 score partials, bin assignment + budget allocation
// ---------------------------------------------------------------
__global__ __launch_bounds__(256) void bin_kernel(
    const float* __restrict__ scoreP, const float* __restrict__ ebins,
    float* __restrict__ score, int* __restrict__ binof, int* __restrict__ kbins)
{
  const int b = blockIdx.x, t = threadIdx.x;
  float wsm[4] = {0.f,0.f,0.f,0.f};
  int   cnt[4] = {0,0,0,0};
  for (int n = t; n < NN; n += 256) {
    size_t si = (size_t)b*NN + n;
    float s = 0.f;
    #pragma unroll
    for (int h = 0; h < 8; ++h) s += scoreP[(size_t)h*BB*NN + si];
    score[si] = s;
    int j = (s >= 1.2f) ? 0 : (s >= 1.0f) ? 1 : (s >= 0.8f) ? 2 : 3;
    binof[si] = j;
    wsm[j] += ebins[si*4 + j];
    cnt[j] += 1;
  }
  #pragma unroll
  for (int j=0;j<4;j++){
    for (int off=1; off<64; off<<=1){
      wsm[j] += __shfl_xor(wsm[j], off);
      cnt[j] += __shfl_xor(cnt[j], off);
    }
  }
  __shared__ float wred[4][4];
  __shared__ int   cred[4][4];
  int wave = t >> 6, lane = t & 63;
  if (lane == 0) for (int j=0;j<4;j++){ wred[wave][j]=wsm[j]; cred[wave][j]=cnt[j]; }
  __syncthreads();
  if (t == 0) {
    float wsum[4]; int cs[4];
    for (int j=0;j<4;j++){
      wsum[j]=wred[0][j]+wred[1][j]+wred[2][j]+wred[3][j];
      cs[j]=cred[0][j]+cred[1][j]+cred[2][j]+cred[3][j];
    }
    float bw[4]; float sbw = 0.f;
    for (int j=0;j<4;j++){
      float wp = wsum[j] / ((float)cs[j] + 1e-8f);
      bw[j] = fmaxf(wp, 0.f); sbw += bw[j];
    }
    float den = fmaxf(sbw, 1e-8f);
    int k0[4]; int sk0 = 0;
    for (int j=0;j<4;j++){
      float p = bw[j] / den;
      int kk = (int)floorf(p * 1024.0f);
      if (kk > cs[j]) kk = cs[j];
      k0[j]=kk; sk0 += kk;
    }
    int deficit = 1024 - sk0;
    int cum = 0;
    for (int j=0;j<4;j++){
      int cap = cs[j] - k0[j];
      int ex = deficit - cum; if (ex < 0) ex = 0; if (ex > cap) ex = cap;
      kbins[b*4+j] = k0[j] + ex;
      cum += cap;
    }
  }
}

// ---------------------------------------------------------------
// topk: per-(batch,bin) top-k by (score desc, index asc) -> flags
// ---------------------------------------------------------------
__global__ __launch_bounds__(256) void topk_kernel(
    const float* __restrict__ score, const int* __restrict__ binof,
    const int* __restrict__ kbins, int* __restrict__ flags)
{
  __shared__ unsigned long long arr[2048];
  const int t = threadIdx.x;
  const int b = blockIdx.x >> 2;
  const int j = blockIdx.x & 3;
  for (int n = t; n < NN; n += 256) {
    unsigned long long comp = 0ull;
    if (binof[(size_t)b*NN+n] == j) {
      unsigned int bits = __float_as_uint(score[(size_t)b*NN+n]);
      bits = (bits & 0x80000000u) ? ~bits : (bits | 0x80000000u);
      comp = ((unsigned long long)bits << 32) |
             (unsigned long long)(0xFFFFFFFFu - (unsigned)n);
    }
    arr[n] = ~comp;
  }
  __syncthreads();
  for (int ksz = 2; ksz <= 2048; ksz <<= 1) {
    for (int jsz = ksz >> 1; jsz > 0; jsz >>= 1) {
      for (int i = t; i < 2048; i += 256) {
        int ixj = i ^ jsz;
        if (ixj > i) {
          unsigned long long a = arr[i], bv = arr[ixj];
          bool up = ((i & ksz) == 0);
          if ((a > bv) == up) { arr[i] = bv; arr[ixj] = a; }
        }
      }
      __syncthreads();
    }
  }
  const int kb = kbins[b*4+j];
  for (int i = t; i < kb; i += 256) {
    unsigned long long comp = ~arr[i];
    int n = (int)(0xFFFFFFFFu - (unsigned)(comp & 0xFFFFFFFFull));
    flags[(size_t)b*NN + n] = 1;
  }
}

// ---------------------------------------------------------------
// scan: prefix-scan of flags -> selected index list + index output
// ---------------------------------------------------------------
__global__ __launch_bounds__(256) void scan_kernel(
    const int* __restrict__ flags, int* __restrict__ idxl, float* __restrict__ outIdx)
{
  __shared__ int tsum[256];
  const int b = blockIdx.x, t = threadIdx.x;
  int f[8]; int c8 = 0;
  const int base = t * 8;
  #pragma unroll
  for (int i=0;i<8;i++){ f[i] = flags[(size_t)b*NN + base + i]; c8 += f[i]; }
  tsum[t] = c8;
  __syncthreads();
  for (int off=1; off<256; off<<=1) {
    int v = (t >= off) ? tsum[t-off] : 0;
    __syncthreads();
    tsum[t] += v;
    __syncthreads();
  }
  int pos = tsum[t] - c8;
  #pragma unroll
  for (int i=0;i<8;i++){
    if (f[i] && pos < MM) {
      idxl[(size_t)b*MM + pos] = base + i;
      outIdx[(size_t)b*MM + pos] = (float)(base + i);
      pos++;
    }
  }
}

// ---------------------------------------------------------------
// outC: pure PV on unnormalized P; scale by sirs at epilogue.
// kt 3-way split into 3 partial buffers (grid 768).
// ---------------------------------------------------------------
__global__ __launch_bounds__(256) void outC_kernel(
    const u16* __restrict__ PU, const u16* __restrict__ VF,
    const float* __restrict__ rsumP,
    const int* __restrict__ idxl, float* __restrict__ oPart)
{
  __shared__ u16 psh[64*64];    // [selrow][m] fp16 (swizzled)
  __shared__ u16 vsh[128*64];   // [c][m] fp16 (swizzled)
  __shared__ int rid[64];
  __shared__ float ssel[64];
  const int t = threadIdx.x;
  const int third = blockIdx.x % 3;
  const int rest  = blockIdx.x / 3;
  const int b  = rest >> 4;
  const int s0 = (rest & 15) * 64;
  const int wv = t >> 6, lane = t & 63;
  const int l15 = lane & 15, lhi = lane >> 4;
  const int ktBeg = third * 11, ktEnd = ktBeg + 11;

  if (t < 64) {
    int n = idxl[(size_t)b*MM + s0 + t];
    rid[t] = n;
    size_t ri = (size_t)b*NN + n;
    ssel[t] = 1.0f / (rsumP[ri] + rsumP[(size_t)BB*NN + ri]);
  }

  f32x4 oacc[8];
  #pragma unroll
  for (int ct=0; ct<8; ++ct) oacc[ct] = (f32x4){0.f,0.f,0.f,0.f};

  for (int kt = ktBeg; kt < ktEnd; ++kt) {
    const int m0 = kt*64;
    __syncthreads();
    #pragma unroll
    for (int ii=0; ii<2; ++ii) {
      int item = t + 256*ii;
      int row = item >> 3, ch = item & 7;
      int gm = m0 + ch*8;
      uint4 v = make_uint4(0,0,0,0);
      if (gm < VST) v = *(const uint4*)(PU + ((size_t)b*NN + rid[row])*VST + gm);
      *(uint4*)((char*)psh + row*128 + ((ch*16) ^ ((row&7)<<4))) = v;
    }
    #pragma unroll
    for (int ii=0; ii<4; ++ii) {
      int item = t + 256*ii;
      int c = item >> 3, ch = item & 7;
      int gm = m0 + ch*8;
      uint4 v = make_uint4(0,0,0,0);
      if (gm < VST) v = *(const uint4*)(VF + ((size_t)b*CC + c)*VST + gm);
      *(uint4*)((char*)vsh + c*128 + ((ch*16) ^ ((c&7)<<4))) = v;
    }
    __syncthreads();
    #pragma unroll
    for (int ki=0; ki<2; ++ki) {
      const int prow = wv*16 + l15;
      f16x8 pa = *(const f16x8*)((const char*)psh + prow*128 + ((ki*64 + lhi*16) ^ ((prow&7)<<4)));
      #pragma unroll
      for (int ct=0; ct<8; ++ct) {
        int c = ct*16 + l15;
        f16x8 vb = *(const f16x8*)((const char*)vsh + c*128 + ((ki*64 + lhi*16) ^ ((c&7)<<4)));
        oacc[ct] = __builtin_amdgcn_mfma_f32_16x16x32_f16(pa, vb, oacc[ct], 0,0,0);
      }
    }
  }
  float* op = oPart + (size_t)third*BB*CC*MM;
  #pragma unroll
  for (int ct=0; ct<8; ++ct) {
    #pragma unroll
    for (int r=0;r<4;++r) {
      op[((size_t)b*CC + ct*16 + l15)*MM + s0 + wv*16 + lhi*4 + r] =
          oacc[ct][r] * ssel[wv*16 + lhi*4 + r];
    }
  }
}

// ---------------------------------------------------------------
// merge: out0 = sum of 3 partials (deterministic order)
// ---------------------------------------------------------------
__global__ __launch_bounds__(256) void merge_kernel(
    const float* __restrict__ oPart, float* __restrict__ out0)
{
  const size_t i = ((size_t)blockIdx.x*256 + threadIdx.x)*4;
  const float4 a = *(const float4*)(oPart + i);
  const float4 b = *(const float4*)(oPart + (size_t)BB*CC*MM + i);
  const float4 c = *(const float4*)(oPart + (size_t)2*BB*CC*MM + i);
  float4 o;
  o.x = a.x + b.x + c.x;
  o.y = a.y + b.y + c.y;
  o.z = a.z + b.z + c.z;
  o.w = a.w + b.w + c.w;
  *(float4*)(out0 + i) = o;
}

// ---------------------------------------------------------------
extern "C" void kernel_launch(void* const* d_in, const int* in_sizes, int n_in,
                              void* d_out, int out_size, void* d_ws, size_t ws_size,
                              hipStream_t stream) {
  const float* x  = (const float*)d_in[0];
  const float* Wq = (const float*)d_in[1];
  const float* Wk = (const float*)d_in[2];
  const float* Wv = (const float*)d_in[3];
  const float* bt = (const float*)d_in[4];
  float* out = (float*)d_out;
  char* ws = (char*)d_ws;

  u16* QH = (u16*)(ws + oQH);
  u16* QL = (u16*)(ws + oQL);
  u16* KH = (u16*)(ws + oKH);
  u16* KL = (u16*)(ws + oKL);
  u16* VF = (u16*)(ws + oVF);
  float* rsumP = (float*)(ws + oRS0);
  float* ebins = (float*)(ws + oEB);
  float* scoreP= (float*)(ws + oSC0);
  float* score = (float*)(ws + oSCORE);
  int* binof = (int*)(ws + oBIN);
  int* kbins = (int*)(ws + oKB);
  int* flags = (int*)(ws + oFL);
  int* idxl  = (int*)(ws + oIDX);
  u16* WHs = (u16*)(ws + oWH);
  u16* WLs = (u16*)(ws + oWL);
  u16* PU  = (u16*)(ws + oPU);
  float* oPart = (float*)(ws + oOP);

  float* out0   = out;                        // (B,C,M)
  float* outIdx = out + (size_t)BB*CC*MM;     // (B,1,M) as float

  (void)hipMemsetAsync(flags, 0, (size_t)BB*NN*sizeof(int), stream);

  hipLaunchKernelGGL(splitW_kernel,  dim3(192),  dim3(256), 0, stream, Wq, Wk, Wv, WHs, WLs);
  hipLaunchKernelGGL(projM_kernel,   dim3(528),  dim3(256), 0, stream, x, bt, WHs, WLs, QH, QL, KH, KL, VF);
  hipLaunchKernelGGL(fusedE_kernel,  dim3(1024), dim3(256), 0, stream, QH, QL, KH, KL, rsumP, ebins, PU);
  hipLaunchKernelGGL(colsum_kernel,  dim3(512),  dim3(256), 0, stream, PU, rsumP, scoreP);
  hipLaunchKernelGGL(bin_kernel,     dim3(16),   dim3(256), 0, stream, scoreP, ebins, score, binof, kbins);
  hipLaunchKernelGGL(topk_kernel,    dim3(64),   dim3(256), 0, stream, score, binof, kbins, flags);
  hipLaunchKernelGGL(scan_kernel,    dim3(16),   dim3(256), 0, stream, flags, idxl, outIdx);
  hipLaunchKernelGGL(outC_kernel,    dim3(768),  dim3(256), 0, stream, PU, VF, rsumP, idxl, oPart);
  hipLaunchKernelGGL(merge_kernel,   dim3(2048), dim3(256), 0, stream, oPart, out0);
}

// Round 12
// 307.725 us; speedup vs baseline: 5.8167x; 1.0348x over previous
//
#include <hip/hip_runtime.h>

#define BB 16
#define CC 128
#define NN 2048
#define MM2 2052
#define VST 2056   // padded V / P row stride (fp16, 16B-aligned rows)
#define MM 1024

constexpr float RSQRT_C = 0.08838834764831845f; // 1/sqrt(128)

typedef unsigned short u16;
typedef __attribute__((ext_vector_type(8))) short bf16x8;
typedef __attribute__((ext_vector_type(8))) _Float16 f16x8;
typedef __attribute__((ext_vector_type(4))) float f32x4;

__device__ inline u16 f2b_rn(float f) {
  unsigned u = __float_as_uint(f);
  unsigned r = u + 0x7fffu + ((u >> 16) & 1u);
  return (u16)(r >> 16);
}
__device__ inline float b2f(u16 h) { return __uint_as_float(((unsigned)h) << 16); }
__device__ inline u16 f2h(float f) {
  union { _Float16 h; u16 u; } cv; cv.h = (_Float16)f; return cv.u;
}
__device__ inline void store8(u16* dst, const u16 h[8]) {
  uint4 v;
  v.x = (unsigned)h[0] | ((unsigned)h[1] << 16);
  v.y = (unsigned)h[2] | ((unsigned)h[3] << 16);
  v.z = (unsigned)h[4] | ((unsigned)h[5] << 16);
  v.w = (unsigned)h[6] | ((unsigned)h[7] << 16);
  *(uint4*)dst = v;
}

// ---- workspace layout (byte offsets) ----
constexpr size_t SZ_Q  = (size_t)BB*NN*CC*2;
constexpr size_t SZ_K  = (size_t)BB*MM2*CC*2;
constexpr size_t SZ_V  = (size_t)BB*CC*VST*2;
constexpr size_t oQH = 0;
constexpr size_t oQL = oQH + SZ_Q;
constexpr size_t oKH = oQL + SZ_Q;
constexpr size_t oKL = oKH + SZ_K;
constexpr size_t oVF = oKL + SZ_K;                     // fp16 V
constexpr size_t oRS0 = oVF + SZ_V;                    // 2*BB*NN f32 partial rowsums
constexpr size_t oEB  = oRS0 + (size_t)2*BB*NN*4;      // BB*NN*4 f32
constexpr size_t oSC0 = oEB  + (size_t)BB*NN*16;       // 8*BB*NN f32 partial scores
constexpr size_t oSCORE = oSC0 + (size_t)8*BB*NN*4;    // BB*NN f32 merged
constexpr size_t oBIN = oSCORE + (size_t)BB*NN*4;      // int
constexpr size_t oKB  = oBIN + (size_t)BB*NN*4;        // BB*4 int
constexpr size_t oFL  = oKB  + 256;                    // BB*NN int
constexpr size_t oIDX = oFL  + (size_t)BB*NN*4;        // BB*MM int
constexpr size_t oWH  = oIDX + (size_t)BB*MM*4;        // 3*128*128 u16
constexpr size_t oWL  = oWH  + (size_t)3*CC*CC*2;
constexpr size_t oPU  = oWL  + (size_t)3*CC*CC*2;      // fp16 unnormalized exp(e)
constexpr size_t SZ_PU = (size_t)BB*NN*VST*2;
constexpr size_t oOP  = oPU + SZ_PU;                   // 2 partial outputs f32

// ---------------------------------------------------------------
// splitW: W hi/lo bf16, packed [w][o][c], w in {q,k,v}
// ---------------------------------------------------------------
__global__ __launch_bounds__(256) void splitW_kernel(
    const float* __restrict__ Wq, const float* __restrict__ Wk, const float* __restrict__ Wv,
    u16* __restrict__ WH, u16* __restrict__ WL)
{
  int i = blockIdx.x*256 + threadIdx.x;
  int w = i >> 14, rest = i & 16383;
  const float* W = (w == 0) ? Wq : (w == 1) ? Wk : Wv;
  float v = W[rest];
  u16 hb = f2b_rn(v);
  WH[i] = hb; WL[i] = f2b_rn(v - b2f(hb));
}

// ---------------------------------------------------------------
// projM: fused transpose+split+Q/K/V projection via bf16x3 MFMA.
// Q[b][n][o] (scaled) hi/lo, K[b][m][o] hi/lo, V[b][o][m] fp16.
// ---------------------------------------------------------------
__global__ __launch_bounds__(256) void projM_kernel(
    const float* __restrict__ x, const float* __restrict__ bt,
    const u16* __restrict__ WHs, const u16* __restrict__ WLs,
    u16* __restrict__ QH, u16* __restrict__ QL,
    u16* __restrict__ KH, u16* __restrict__ KL,
    u16* __restrict__ VF)
{
  __shared__ float xs[64][130];
  __shared__ u16 xsh[64*128], xsl[64*128];
  const int t = threadIdx.x;
  const int b  = blockIdx.x / 33;
  const int mt = blockIdx.x % 33;
  const int m0 = mt*64;
  const int wv = t >> 6, lane = t & 63;
  const int l15 = lane & 15, lhi = lane >> 4;

  // phase A: stage x tile (fp32) transposed into xs[m][c]
  if (mt < 32) {
    for (int i = t; i < 128*64; i += 256) {
      int c = i >> 6, n = i & 63;
      xs[n][c] = x[((size_t)b*CC + c)*NN + m0 + n];
    }
  } else {
    for (int i = t; i < 64*128; i += 256) {
      int n = i >> 7, c = i & 127;
      xs[n][c] = (n < 4) ? bt[c*4 + n] : 0.f;
    }
  }
  __syncthreads();
  // phase B: bf16 hi/lo split into swizzled xsh/xsl
  {
    const int row0 = t >> 4, chunk = t & 15;
    #pragma unroll
    for (int ii=0; ii<4; ++ii) {
      int r = row0 + ii*16;
      const float* src = &xs[r][chunk*8];
      u16 hs[8], ls[8];
      #pragma unroll
      for (int j=0;j<8;++j) {
        float v = src[j];
        u16 hb = f2b_rn(v);
        hs[j] = hb; ls[j] = f2b_rn(v - b2f(hb));
      }
      int dst = r*256 + ((chunk*16) ^ ((r&7)<<4));
      store8((u16*)((char*)xsh + dst), hs);
      store8((u16*)((char*)xsl + dst), ls);
    }
  }
  __syncthreads();

  // q (w=0), k (w=1): A = x rows (m), B = W rows (o) -> D[m][o]
  for (int w = (m0 >= NN) ? 1 : 0; w < 2; ++w) {
    u16* OH = w ? KH : QH;
    u16* OL = w ? KL : QL;
    const float scl = w ? 1.0f : RSQRT_C;
    const int mlim = w ? MM2 : NN;
    for (int osub = 0; osub < 2; ++osub) {
      const int ocol = wv*32 + osub*16;
      bf16x8 wbh[4], wbl[4];
      #pragma unroll
      for (int it=0; it<4; ++it) {
        size_t wi = (size_t)(ocol + l15)*CC + it*32 + lhi*8;
        wbh[it] = *(const bf16x8*)(WHs + (size_t)w*CC*CC + wi);
        wbl[it] = *(const bf16x8*)(WLs + (size_t)w*CC*CC + wi);
      }
      for (int msub = 0; msub < 4; ++msub) {
        const int mrow = msub*16 + l15;
        f32x4 acc = {0.f,0.f,0.f,0.f};
        #pragma unroll
        for (int it=0; it<4; ++it) {
          int byt = mrow*256 + ((it*64 + lhi*16) ^ ((mrow&7)<<4));
          bf16x8 ah = *(const bf16x8*)((const char*)xsh + byt);
          bf16x8 al = *(const bf16x8*)((const char*)xsl + byt);
          acc = __builtin_amdgcn_mfma_f32_16x16x32_bf16(ah, wbh[it], acc, 0,0,0);
          acc = __builtin_amdgcn_mfma_f32_16x16x32_bf16(ah, wbl[it], acc, 0,0,0);
          acc = __builtin_amdgcn_mfma_f32_16x16x32_bf16(al, wbh[it], acc, 0,0,0);
        }
        #pragma unroll
        for (int r=0;r<4;++r) {
          int m = m0 + msub*16 + lhi*4 + r;
          if (m < mlim) {
            float vv = acc[r] * scl;
            u16 hb = f2b_rn(vv);
            size_t oi = w ? ((size_t)b*MM2 + m)*CC + ocol + l15
                          : ((size_t)b*NN  + m)*CC + ocol + l15;
            OH[oi] = hb;
            OL[oi] = f2b_rn(vv - b2f(hb));
          }
        }
      }
    }
  }

  // v: A = W rows (o), B = x rows (m) -> D[o][m], fp16 out
  {
    const u16* whp = WHs + (size_t)2*CC*CC;
    const u16* wlp = WLs + (size_t)2*CC*CC;
    for (int osub = 0; osub < 2; ++osub) {
      const int ocol = wv*32 + osub*16;
      bf16x8 wbh[4], wbl[4];
      #pragma unroll
      for (int it=0; it<4; ++it) {
        size_t wi = (size_t)(ocol + l15)*CC + it*32 + lhi*8;
        wbh[it] = *(const bf16x8*)(whp + wi);
        wbl[it] = *(const bf16x8*)(wlp + wi);
      }
      for (int msub = 0; msub < 4; ++msub) {
        const int mrow = msub*16 + l15;
        f32x4 acc = {0.f,0.f,0.f,0.f};
        #pragma unroll
        for (int it=0; it<4; ++it) {
          int byt = mrow*256 + ((it*64 + lhi*16) ^ ((mrow&7)<<4));
          bf16x8 ah = *(const bf16x8*)((const char*)xsh + byt);
          bf16x8 al = *(const bf16x8*)((const char*)xsl + byt);
          acc = __builtin_amdgcn_mfma_f32_16x16x32_bf16(wbh[it], ah, acc, 0,0,0);
          acc = __builtin_amdgcn_mfma_f32_16x16x32_bf16(wbh[it], al, acc, 0,0,0);
          acc = __builtin_amdgcn_mfma_f32_16x16x32_bf16(wbl[it], ah, acc, 0,0,0);
        }
        #pragma unroll
        for (int r=0;r<4;++r) {
          int o = ocol + lhi*4 + r;
          int m = m0 + msub*16 + l15;
          if (m < VST)
            VF[((size_t)b*CC + o)*VST + m] = f2h(acc[r]);  // zeroed >= MM2
        }
      }
    }
  }
}

// ---------------------------------------------------------------
// fusedE: ONE QK^T pass -> partial rowsum of exp(e), bin energies,
// and PU = fp16 unnormalized exp(e) [b][n][VST].
// 512 threads / 8 waves / 128 query rows per block; kt half-split
// (grid 512). Same 32KB K-stage now feeds 2x MFMA per barrier.
// ---------------------------------------------------------------
__global__ __launch_bounds__(512) void fusedE_kernel(
    const u16* __restrict__ QH, const u16* __restrict__ QL,
    const u16* __restrict__ KH, const u16* __restrict__ KL,
    float* __restrict__ rsumP, float* __restrict__ ebins, u16* __restrict__ PU)
{
  __shared__ u16 kh[64*128], kl[64*128];
  const int t = threadIdx.x;
  const int half = blockIdx.x & 1;
  const int rest = blockIdx.x >> 1;
  const int b = rest >> 4;
  const int n0 = (rest & 15) * 128;
  const int wv = t >> 6, lane = t & 63;
  const int l15 = lane & 15, lhi = lane >> 4;
  const int nw = n0 + wv*16;
  const int ktBeg = half ? 17 : 0;
  const int ktFastEnd = half ? 32 : 17;

  bf16x8 qh[4], ql[4];
  {
    const size_t rb = ((size_t)b*NN + nw + l15)*CC + lhi*8;
    #pragma unroll
    for (int it=0; it<4; ++it) {
      qh[it] = *(const bf16x8*)(QH + rb + it*32);
      ql[it] = *(const bf16x8*)(QL + rb + it*32);
    }
  }
  u16* puR[4];
  #pragma unroll
  for (int r=0;r<4;++r)
    puR[r] = PU + ((size_t)b*NN + nw + lhi*4 + r)*VST;

  float runsum[4] = {0.f, 0.f, 0.f, 0.f};

  for (int kt = ktBeg; kt < ktFastEnd; ++kt) {
    const int m0 = kt*64;
    __syncthreads();
    {
      const int row0 = t >> 4, chunk = t & 15;   // row0 0..31
      #pragma unroll
      for (int ii=0; ii<2; ++ii) {
        int r = row0 + ii*32;
        int dst = r*256 + ((chunk*16) ^ ((r&7)<<4));
        size_t g = ((size_t)b*MM2 + m0 + r)*CC + chunk*8;
        *(uint4*)((char*)kh + dst) = *(const uint4*)(KH + g);
        *(uint4*)((char*)kl + dst) = *(const uint4*)(KL + g);
      }
    }
    __syncthreads();
    for (int mc = 0; mc < 4; ++mc) {
      f32x4 acc = {0.f,0.f,0.f,0.f};
      const int mrow = mc*16 + l15;
      #pragma unroll
      for (int it=0; it<4; ++it) {
        int byt = mrow*256 + ((it*64 + lhi*16) ^ ((mrow&7)<<4));
        bf16x8 bh = *(const bf16x8*)((const char*)kh + byt);
        bf16x8 bl = *(const bf16x8*)((const char*)kl + byt);
        acc = __builtin_amdgcn_mfma_f32_16x16x32_bf16(qh[it], bh, acc, 0,0,0);
        acc = __builtin_amdgcn_mfma_f32_16x16x32_bf16(qh[it], bl, acc, 0,0,0);
        acc = __builtin_amdgcn_mfma_f32_16x16x32_bf16(ql[it], bh, acc, 0,0,0);
      }
      const int m = m0 + mrow;
      #pragma unroll
      for (int r=0;r<4;++r) {
        float ex = __expf(acc[r]);
        puR[r][m] = f2h(ex);
        runsum[r] += ex;
      }
    }
  }

  if (half) {   // kt == 32 tail (checked)
    const int m0 = 2048;
    __syncthreads();
    {
      const int row0 = t >> 4, chunk = t & 15;
      #pragma unroll
      for (int ii=0; ii<2; ++ii) {
        int r = row0 + ii*32; int gm = m0 + r;
        int dst = r*256 + ((chunk*16) ^ ((r&7)<<4));
        uint4 vh = make_uint4(0,0,0,0), vl = make_uint4(0,0,0,0);
        if (gm < MM2) {
          size_t g = ((size_t)b*MM2 + gm)*CC + chunk*8;
          vh = *(const uint4*)(KH + g);
          vl = *(const uint4*)(KL + g);
        }
        *(uint4*)((char*)kh + dst) = vh;
        *(uint4*)((char*)kl + dst) = vl;
      }
    }
    __syncthreads();
    {
      f32x4 acc = {0.f,0.f,0.f,0.f};
      const int mrow = l15;
      #pragma unroll
      for (int it=0; it<4; ++it) {
        int byt = mrow*256 + ((it*64 + lhi*16) ^ ((mrow&7)<<4));
        bf16x8 bh = *(const bf16x8*)((const char*)kh + byt);
        bf16x8 bl = *(const bf16x8*)((const char*)kl + byt);
        acc = __builtin_amdgcn_mfma_f32_16x16x32_bf16(qh[it], bh, acc, 0,0,0);
        acc = __builtin_amdgcn_mfma_f32_16x16x32_bf16(qh[it], bl, acc, 0,0,0);
        acc = __builtin_amdgcn_mfma_f32_16x16x32_bf16(ql[it], bh, acc, 0,0,0);
      }
      const int m = m0 + mrow;
      if (l15 < 4) {
        #pragma unroll
        for (int r=0;r<4;++r)
          ebins[((size_t)b*NN + nw + lhi*4 + r)*4 + l15] = acc[r];
      }
      const bool valid = (m < MM2);
      #pragma unroll
      for (int r=0;r<4;++r) {
        float ex = valid ? __expf(acc[r]) : 0.f;
        if (m < VST) puR[r][m] = f2h(ex);
        runsum[r] += ex;
      }
    }
  }

  #pragma unroll
  for (int r=0;r<4;++r) {
    runsum[r] += __shfl_xor(runsum[r], 1);
    runsum[r] += __shfl_xor(runsum[r], 2);
    runsum[r] += __shfl_xor(runsum[r], 4);
    runsum[r] += __shfl_xor(runsum[r], 8);
  }
  if (l15 == 0) {
    float* rs = rsumP + (size_t)half*BB*NN;
    #pragma unroll
    for (int r=0;r<4;++r)
      rs[(size_t)b*NN + nw + lhi*4 + r] = runsum[r];
  }
}

// ---------------------------------------------------------------
// colsum: score partials. score[b][m] = sum_n PU[b][n][m]*sirs[n].
// grid 512 = 16b x 4 mtiles(512) x 8 nchunks(256). Streaming read-bound.
// ---------------------------------------------------------------
__global__ __launch_bounds__(256) void colsum_kernel(
    const u16* __restrict__ PU, const float* __restrict__ rsumP,
    float* __restrict__ scoreP)
{
  __shared__ float sirs[256];
  const int t = threadIdx.x;
  const int blk = blockIdx.x;
  const int ns = blk & 7;
  const int mt = (blk >> 3) & 3;
  const int b  = blk >> 5;
  const int n0 = ns*256;
  const int m0 = mt*512;
  {
    size_t ri = (size_t)b*NN + n0 + t;
    sirs[t] = 1.0f / (rsumP[ri] + rsumP[(size_t)BB*NN + ri]);
  }
  __syncthreads();
  float s0a = 0.f, s1a = 0.f;
  const u16* base = PU + ((size_t)b*NN + n0)*VST + m0 + 2*t;
  #pragma unroll 4
  for (int n = 0; n < 256; ++n) {
    unsigned pv = *(const unsigned*)(base + (size_t)n*VST);
    union { unsigned u; _Float16 h[2]; } cv; cv.u = pv;
    float w = sirs[n];
    s0a = fmaf((float)cv.h[0], w, s0a);
    s1a = fmaf((float)cv.h[1], w, s1a);
  }
  float2 o; o.x = s0a; o.y = s1a;
  *(float2*)(scoreP + (size_t)ns*BB*NN + (size_t)b*NN + m0 + 2*t) = o;
}

// ---------------------------------------------------------------
// bin: merge 8 score partials, bin assignment + budget allocation
// ---------------------------------------------------------------
__global__ __launch_bounds__(256) void bin_kernel(
    const float* __restrict__ scoreP, const float* __restrict__ ebins,
    float* __restrict__ score, int* __restrict__ binof, int* __restrict__ kbins)
{
  const int b = blockIdx.x, t = threadIdx.x;
  float wsm[4] = {0.f,0.f,0.f,0.f};
  int   cnt[4] = {0,0,0,0};
  for (int n = t; n < NN; n += 256) {
    size_t si = (size_t)b*NN + n;
    float s = 0.f;
    #pragma unroll
    for (int h = 0; h < 8; ++h) s += scoreP[(size_t)h*BB*NN + si];
    score[si] = s;
    int j = (s >= 1.2f) ? 0 : (s >= 1.0f) ? 1 : (s >= 0.8f) ? 2 : 3;
    binof[si] = j;
    wsm[j] += ebins[si*4 + j];
    cnt[j] += 1;
  }
  #pragma unroll
  for (int j=0;j<4;j++){
    for (int off=1; off<64; off<<=1){
      wsm[j] += __shfl_xor(wsm[j], off);
      cnt[j] += __shfl_xor(cnt[j], off);
    }
  }
  __shared__ float wred[4][4];
  __shared__ int   cred[4][4];
  int wave = t >> 6, lane = t & 63;
  if (lane == 0) for (int j=0;j<4;j++){ wred[wave][j]=wsm[j]; cred[wave][j]=cnt[j]; }
  __syncthreads();
  if (t == 0) {
    float wsum[4]; int cs[4];
    for (int j=0;j<4;j++){
      wsum[j]=wred[0][j]+wred[1][j]+wred[2][j]+wred[3][j];
      cs[j]=cred[0][j]+cred[1][j]+cred[2][j]+cred[3][j];
    }
    float bw[4]; float sbw = 0.f;
    for (int j=0;j<4;j++){
      float wp = wsum[j] / ((float)cs[j] + 1e-8f);
      bw[j] = fmaxf(wp, 0.f); sbw += bw[j];
    }
    float den = fmaxf(sbw, 1e-8f);
    int k0[4]; int sk0 = 0;
    for (int j=0;j<4;j++){
      float p = bw[j] / den;
      int kk = (int)floorf(p * 1024.0f);
      if (kk > cs[j]) kk = cs[j];
      k0[j]=kk; sk0 += kk;
    }
    int deficit = 1024 - sk0;
    int cum = 0;
    for (int j=0;j<4;j++){
      int cap = cs[j] - k0[j];
      int ex = deficit - cum; if (ex < 0) ex = 0; if (ex > cap) ex = cap;
      kbins[b*4+j] = k0[j] + ex;
      cum += cap;
    }
  }
}

// ---------------------------------------------------------------
// topk: per-(batch,bin) top-k by (score desc, index asc) -> flags
// ---------------------------------------------------------------
__global__ __launch_bounds__(256) void topk_kernel(
    const float* __restrict__ score, const int* __restrict__ binof,
    const int* __restrict__ kbins, int* __restrict__ flags)
{
  __shared__ unsigned long long arr[2048];
  const int t = threadIdx.x;
  const int b = blockIdx.x >> 2;
  const int j = blockIdx.x & 3;
  for (int n = t; n < NN; n += 256) {
    unsigned long long comp = 0ull;
    if (binof[(size_t)b*NN+n] == j) {
      unsigned int bits = __float_as_uint(score[(size_t)b*NN+n]);
      bits = (bits & 0x80000000u) ? ~bits : (bits | 0x80000000u);
      comp = ((unsigned long long)bits << 32) |
             (unsigned long long)(0xFFFFFFFFu - (unsigned)n);
    }
    arr[n] = ~comp;
  }
  __syncthreads();
  for (int ksz = 2; ksz <= 2048; ksz <<= 1) {
    for (int jsz = ksz >> 1; jsz > 0; jsz >>= 1) {
      for (int i = t; i < 2048; i += 256) {
        int ixj = i ^ jsz;
        if (ixj > i) {
          unsigned long long a = arr[i], bv = arr[ixj];
          bool up = ((i & ksz) == 0);
          if ((a > bv) == up) { arr[i] = bv; arr[ixj] = a; }
        }
      }
      __syncthreads();
    }
  }
  const int kb = kbins[b*4+j];
  for (int i = t; i < kb; i += 256) {
    unsigned long long comp = ~arr[i];
    int n = (int)(0xFFFFFFFFu - (unsigned)(comp & 0xFFFFFFFFull));
    flags[(size_t)b*NN + n] = 1;
  }
}

// ---------------------------------------------------------------
// scan: prefix-scan of flags -> selected index list + index output
// ---------------------------------------------------------------
__global__ __launch_bounds__(256) void scan_kernel(
    const int* __restrict__ flags, int* __restrict__ idxl, float* __restrict__ outIdx)
{
  __shared__ int tsum[256];
  const int b = blockIdx.x, t = threadIdx.x;
  int f[8]; int c8 = 0;
  const int base = t * 8;
  #pragma unroll
  for (int i=0;i<8;i++){ f[i] = flags[(size_t)b*NN + base + i]; c8 += f[i]; }
  tsum[t] = c8;
  __syncthreads();
  for (int off=1; off<256; off<<=1) {
    int v = (t >= off) ? tsum[t-off] : 0;
    __syncthreads();
    tsum[t] += v;
    __syncthreads();
  }
  int pos = tsum[t] - c8;
  #pragma unroll
  for (int i=0;i<8;i++){
    if (f[i] && pos < MM) {
      idxl[(size_t)b*MM + pos] = base + i;
      outIdx[(size_t)b*MM + pos] = (float)(base + i);
      pos++;
    }
  }
}

// ---------------------------------------------------------------
// outC: pure PV on unnormalized P; scale by sirs at epilogue.
// kt 2-way split into 2 partial buffers (grid 512).
// ---------------------------------------------------------------
__global__ __launch_bounds__(256) void outC_kernel(
    const u16* __restrict__ PU, const u16* __restrict__ VF,
    const float* __restrict__ rsumP,
    const int* __restrict__ idxl, float* __restrict__ oPart)
{
  __shared__ u16 psh[64*64];    // [selrow][m] fp16 (swizzled)
  __shared__ u16 vsh[128*64];   // [c][m] fp16 (swizzled)
  __shared__ int rid[64];
  __shared__ float ssel[64];
  const int t = threadIdx.x;
  const int half = blockIdx.x & 1;
  const int rest  = blockIdx.x >> 1;
  const int b  = rest >> 4;
  const int s0 = (rest & 15) * 64;
  const int wv = t >> 6, lane = t & 63;
  const int l15 = lane & 15, lhi = lane >> 4;
  const int ktBeg = half ? 17 : 0, ktEnd = half ? 33 : 17;

  if (t < 64) {
    int n = idxl[(size_t)b*MM + s0 + t];
    rid[t] = n;
    size_t ri = (size_t)b*NN + n;
    ssel[t] = 1.0f / (rsumP[ri] + rsumP[(size_t)BB*NN + ri]);
  }

  f32x4 oacc[8];
  #pragma unroll
  for (int ct=0; ct<8; ++ct) oacc[ct] = (f32x4){0.f,0.f,0.f,0.f};

  for (int kt = ktBeg; kt < ktEnd; ++kt) {
    const int m0 = kt*64;
    __syncthreads();
    #pragma unroll
    for (int ii=0; ii<2; ++ii) {
      int item = t + 256*ii;
      int row = item >> 3, ch = item & 7;
      int gm = m0 + ch*8;
      uint4 v = make_uint4(0,0,0,0);
      if (gm < VST) v = *(const uint4*)(PU + ((size_t)b*NN + rid[row])*VST + gm);
      *(uint4*)((char*)psh + row*128 + ((ch*16) ^ ((row&7)<<4))) = v;
    }
    #pragma unroll
    for (int ii=0; ii<4; ++ii) {
      int item = t + 256*ii;
      int c = item >> 3, ch = item & 7;
      int gm = m0 + ch*8;
      uint4 v = make_uint4(0,0,0,0);
      if (gm < VST) v = *(const uint4*)(VF + ((size_t)b*CC + c)*VST + gm);
      *(uint4*)((char*)vsh + c*128 + ((ch*16) ^ ((c&7)<<4))) = v;
    }
    __syncthreads();
    #pragma unroll
    for (int ki=0; ki<2; ++ki) {
      const int prow = wv*16 + l15;
      f16x8 pa = *(const f16x8*)((const char*)psh + prow*128 + ((ki*64 + lhi*16) ^ ((prow&7)<<4)));
      #pragma unroll
      for (int ct=0; ct<8; ++ct) {
        int c = ct*16 + l15;
        f16x8 vb = *(const f16x8*)((const char*)vsh + c*128 + ((ki*64 + lhi*16) ^ ((c&7)<<4)));
        oacc[ct] = __builtin_amdgcn_mfma_f32_16x16x32_f16(pa, vb, oacc[ct], 0,0,0);
      }
    }
  }
  float* op = oPart + (size_t)half*BB*CC*MM;
  #pragma unroll
  for (int ct=0; ct<8; ++ct) {
    #pragma unroll
    for (int r=0;r<4;++r) {
      op[((size_t)b*CC + ct*16 + l15)*MM + s0 + wv*16 + lhi*4 + r] =
          oacc[ct][r] * ssel[wv*16 + lhi*4 + r];
    }
  }
}

// ---------------------------------------------------------------
// merge: out0 = sum of 2 partials (deterministic order)
// ---------------------------------------------------------------
__global__ __launch_bounds__(256) void merge_kernel(
    const float* __restrict__ oPart, float* __restrict__ out0)
{
  const size_t i = ((size_t)blockIdx.x*256 + threadIdx.x)*4;
  const float4 a = *(const float4*)(oPart + i);
  const float4 b = *(const float4*)(oPart + (size_t)BB*CC*MM + i);
  float4 o;
  o.x = a.x + b.x;
  o.y = a.y + b.y;
  o.z = a.z + b.z;
  o.w = a.w + b.w;
  *(float4*)(out0 + i) = o;
}

// ---------------------------------------------------------------
extern "C" void kernel_launch(void* const* d_in, const int* in_sizes, int n_in,
                              void* d_out, int out_size, void* d_ws, size_t ws_size,
                              hipStream_t stream) {
  const float* x  = (const float*)d_in[0];
  const float* Wq = (const float*)d_in[1];
  const float* Wk = (const float*)d_in[2];
  const float* Wv = (const float*)d_in[3];
  const float* bt = (const float*)d_in[4];
  float* out = (float*)d_out;
  char* ws = (char*)d_ws;

  u16* QH = (u16*)(ws + oQH);
  u16* QL = (u16*)(ws + oQL);
  u16* KH = (u16*)(ws + oKH);
  u16* KL = (u16*)(ws + oKL);
  u16* VF = (u16*)(ws + oVF);
  float* rsumP = (float*)(ws + oRS0);
  float* ebins = (float*)(ws + oEB);
  float* scoreP= (float*)(ws + oSC0);
  float* score = (float*)(ws + oSCORE);
  int* binof = (int*)(ws + oBIN);
  int* kbins = (int*)(ws + oKB);
  int* flags = (int*)(ws + oFL);
  int* idxl  = (int*)(ws + oIDX);
  u16* WHs = (u16*)(ws + oWH);
  u16* WLs = (u16*)(ws + oWL);
  u16* PU  = (u16*)(ws + oPU);
  float* oPart = (float*)(ws + oOP);

  float* out0   = out;                        // (B,C,M)
  float* outIdx = out + (size_t)BB*CC*MM;     // (B,1,M) as float

  (void)hipMemsetAsync(flags, 0, (size_t)BB*NN*sizeof(int), stream);

  hipLaunchKernelGGL(splitW_kernel,  dim3(192),  dim3(256), 0, stream, Wq, Wk, Wv, WHs, WLs);
  hipLaunchKernelGGL(projM_kernel,   dim3(528),  dim3(256), 0, stream, x, bt, WHs, WLs, QH, QL, KH, KL, VF);
  hipLaunchKernelGGL(fusedE_kernel,  dim3(512),  dim3(512), 0, stream, QH, QL, KH, KL, rsumP, ebins, PU);
  hipLaunchKernelGGL(colsum_kernel,  dim3(512),  dim3(256), 0, stream, PU, rsumP, scoreP);
  hipLaunchKernelGGL(bin_kernel,     dim3(16),   dim3(256), 0, stream, scoreP, ebins, score, binof, kbins);
  hipLaunchKernelGGL(topk_kernel,    dim3(64),   dim3(256), 0, stream, score, binof, kbins, flags);
  hipLaunchKernelGGL(scan_kernel,    dim3(16),   dim3(256), 0, stream, flags, idxl, outIdx);
  hipLaunchKernelGGL(outC_kernel,    dim3(512),  dim3(256), 0, stream, PU, VF, rsumP, idxl, oPart);
  hipLaunchKernelGGL(merge_kernel,   dim3(2048), dim3(256), 0, stream, oPart, out0);
}